// Round 9
// baseline (299.700 us; speedup 1.0000x reference)
//
#include <hip/hip_runtime.h>
#include <hip/hip_bf16.h>
#include <math.h>

#define N_NODES 50000
#define F_INK   256
#define HEADS   8
#define HID     64
#define HH      512     // HEADS*HID
#define NCLS    16
#define NEDGE   400000
#define NEG_SLOPE 0.2f

#define BCOLS 64
#define KPAD  264       // 256 + 8 bf16 pad -> optimal quad-bank spread
#define NBLK_SCAN ((N_NODES + 255) / 256)   // 196

typedef __attribute__((ext_vector_type(8))) short short8;
typedef __attribute__((ext_vector_type(4))) short sh4;
typedef __attribute__((ext_vector_type(4))) float float4v;

__device__ __forceinline__ float bf2f(unsigned short u){
    unsigned int x = ((unsigned int)u) << 16;
    float f; __builtin_memcpy(&f, &x, 4); return f;
}
__device__ __forceinline__ unsigned short f2bf(float f){
    unsigned int x; __builtin_memcpy(&x, &f, 4);
    unsigned int r = x + 0x7FFFu + ((x >> 16) & 1u);   // RNE
    return (unsigned short)(r >> 16);
}
__device__ __forceinline__ float lrelu(float a){ return a > 0.f ? a : NEG_SLOPE * a; }

// dword-level bf16x2 unpack + fma: 1 VALU unpack + 1 fma per element
__device__ __forceinline__ void fma8(float* acc, float w, short8 v){
    unsigned int u[4]; __builtin_memcpy(u, &v, 16);
#pragma unroll
    for (int j = 0; j < 4; j++){
        acc[2*j]   += w * __uint_as_float(u[j] << 16);
        acc[2*j+1] += w * __uint_as_float(u[j] & 0xffff0000u);
    }
}

// ---------------- conversions ----------------
__global__ void cvt_f32_bf16(const float* __restrict__ in, unsigned short* __restrict__ out, int n4){
    int i = blockIdx.x * blockDim.x + threadIdx.x;
    int stride = gridDim.x * blockDim.x;
    for (; i < n4; i += stride){
        float4v f = *(const float4v*)(in + (size_t)i * 4);
        sh4 o;
#pragma unroll
        for (int j = 0; j < 4; j++) o[j] = (short)f2bf(f[j]);
        *(sh4*)(out + (size_t)i * 4) = o;
    }
}

// W1 [256][512] fp32 -> W1T [512][256] bf16
__global__ void cvt_w1t(const float* __restrict__ W1, unsigned short* __restrict__ W1T){
    int i = blockIdx.x * blockDim.x + threadIdx.x;
    if (i >= F_INK * HH) return;
    int k = i / HH, c = i % HH;
    W1T[c * F_INK + k] = f2bf(W1[i]);
}

// W2 [512][16] fp32 -> W2T [16][512] bf16
__global__ void cvt_w2t(const float* __restrict__ W2, unsigned short* __restrict__ W2T){
    int i = blockIdx.x * blockDim.x + threadIdx.x;
    if (i >= HH * NCLS) return;
    int k = i / NCLS, c = i % NCLS;
    W2T[c * HH + k] = f2bf(W2[i]);
}

// ---------------- CSR build ----------------
__global__ void count_edges(const int* __restrict__ dst, int* __restrict__ counts){
    int e = blockIdx.x * blockDim.x + threadIdx.x;
    if (e < NEDGE) atomicAdd(&counts[dst[e]], 1);
}

__global__ __launch_bounds__(256) void scan_part(const int* __restrict__ counts,
                                                 int* __restrict__ blocksums){
    __shared__ int red[256];
    int i = blockIdx.x * 256 + threadIdx.x;
    int v = (i < N_NODES) ? counts[i] : 0;
    red[threadIdx.x] = v; __syncthreads();
    for (int off = 128; off > 0; off >>= 1){
        if (threadIdx.x < off) red[threadIdx.x] += red[threadIdx.x + off];
        __syncthreads();
    }
    if (threadIdx.x == 0) blocksums[blockIdx.x] = red[0];
}

__global__ __launch_bounds__(256) void scan_top(const int* __restrict__ blocksums,
                                                int* __restrict__ blockbase,
                                                int* __restrict__ offsets){
    __shared__ int s[256];
    int t = threadIdx.x;
    int v = (t < NBLK_SCAN) ? blocksums[t] : 0;
    s[t] = v; __syncthreads();
    int val = v;
    for (int off = 1; off < 256; off <<= 1){
        int o2 = (t >= off) ? s[t - off] : 0;
        __syncthreads();
        val += o2; s[t] = val;
        __syncthreads();
    }
    if (t < NBLK_SCAN) blockbase[t] = val - v;   // exclusive
    if (t == 255) offsets[N_NODES] = s[255];     // grand total
}

__global__ __launch_bounds__(256) void scan_write(const int* __restrict__ counts,
                                                  const int* __restrict__ blockbase,
                                                  int* __restrict__ offsets){
    __shared__ int s[256];
    int i = blockIdx.x * 256 + threadIdx.x;
    int t = threadIdx.x;
    int v = (i < N_NODES) ? counts[i] : 0;
    s[t] = v; __syncthreads();
    int val = v;
    for (int off = 1; off < 256; off <<= 1){
        int o2 = (t >= off) ? s[t - off] : 0;
        __syncthreads();
        val += o2; s[t] = val;
        __syncthreads();
    }
    if (i < N_NODES) offsets[i] = blockbase[blockIdx.x] + val - v;
}

__global__ void scatter_edges(const int* __restrict__ src, const int* __restrict__ dst,
                              const int* __restrict__ offsets, int* __restrict__ cursor,
                              int* __restrict__ esrc){
    int e = blockIdx.x * blockDim.x + threadIdx.x;
    if (e < NEDGE){
        int d = dst[e];
        int pos = offsets[d] + atomicAdd(&cursor[d], 1);
        esrc[pos] = src[e];
    }
}

// ---------------- GEMM1: h1 = bf16(x) @ bf16(W1), output bf16 [N][512] ----------------
__global__ __launch_bounds__(256) void gemm1(const unsigned short* __restrict__ xb,
                                             const unsigned short* __restrict__ w1t,
                                             unsigned short* __restrict__ h1b){
    __shared__ unsigned short bs[BCOLS * KPAD];   // 33 KB
    int cb  = blockIdx.x & 7;          // col panel: cols [cb*64, cb*64+64)
    int rg  = blockIdx.x >> 3;
    int nrg = gridDim.x >> 3;
    {   // stage B panel once
        int kc = threadIdx.x & 31;
        int c0 = threadIdx.x >> 5;
#pragma unroll
        for (int it = 0; it < 8; it++){
            int col = it * 8 + c0;
            short8 v = *(const short8*)(w1t + (size_t)(cb * BCOLS + col) * F_INK + kc * 8);
            *(short8*)(&bs[col * KPAD + kc * 8]) = v;
        }
    }
    __syncthreads();
    int w    = threadIdx.x >> 6;
    int lane = threadIdx.x & 63;
    int lr = lane & 15, lk = lane >> 4;
    const int nchunk = (N_NODES + 63) / 64;       // 782
    for (int ch = rg; ch < nchunk; ch += nrg){
        int rowbase = ch * 64 + w * 16;
        if (rowbase >= N_NODES) continue;
        short8 a[8];
#pragma unroll
        for (int ks = 0; ks < 8; ks++)
            a[ks] = *(const short8*)(xb + (size_t)(rowbase + lr) * F_INK + ks * 32 + lk * 8);
#pragma unroll
        for (int ct = 0; ct < 4; ct++){
            float4v acc = {0.f, 0.f, 0.f, 0.f};
#pragma unroll
            for (int ks = 0; ks < 8; ks++){
                short8 b = *(const short8*)(&bs[(ct * 16 + lr) * KPAD + ks * 32 + lk * 8]);
                acc = __builtin_amdgcn_mfma_f32_16x16x32_bf16(a[ks], b, acc, 0, 0, 0);
            }
#pragma unroll
            for (int r = 0; r < 4; r++)
                h1b[(size_t)(rowbase + lk * 4 + r) * HH + cb * BCOLS + ct * 16 + lr] = f2bf(acc[r]);
        }
    }
}

// ---------------- attention dots: al_src/al_dst [N][8] ----------------
__global__ __launch_bounds__(256) void attn1_dots(const unsigned short* __restrict__ h1b,
        const float* __restrict__ a_src, const float* __restrict__ a_dst,
        float* __restrict__ al_s, float* __restrict__ al_d){
    int n = blockIdx.x * 4 + (threadIdx.x >> 6);
    int lane = threadIdx.x & 63;
    if (n >= N_NODES) return;
    short8 v = *(const short8*)(h1b + (size_t)n * HH + lane * 8);
    int head = lane >> 3;
    int j0 = (lane & 7) * 8;
    float ps = 0.f, pd = 0.f;
#pragma unroll
    for (int j = 0; j < 8; j++){
        float hv = bf2f((unsigned short)v[j]);
        ps += hv * a_src[head * HID + j0 + j];
        pd += hv * a_dst[head * HID + j0 + j];
    }
#pragma unroll
    for (int off = 1; off < 8; off <<= 1){
        ps += __shfl_xor(ps, off);
        pd += __shfl_xor(pd, off);
    }
    if ((lane & 7) == 0){
        al_s[n * HEADS + head] = ps;
        al_d[n * HEADS + head] = pd;
    }
}

// ---------------- layer-1: fused softmax + aggregation + elu -> x2b ----------------
// one wave per dst; lane covers head g=lane>>3, cols (lane&7)*8..+8.
// pass1 max, pass2 denom (4B al_s gathers), pass3 row gather with recomputed exp.
__global__ __launch_bounds__(256) void agg1(const unsigned short* __restrict__ h1b,
        const float* __restrict__ al_s, const float* __restrict__ al_d,
        const int* __restrict__ offsets, const int* __restrict__ esrc,
        const float* __restrict__ b1, unsigned short* __restrict__ x2b){
    int d = blockIdx.x * 4 + (threadIdx.x >> 6);
    if (d >= N_NODES) return;
    int lane = threadIdx.x & 63;
    int g = lane >> 3;
    int cb = g * HID + (lane & 7) * 8;     // lane's column offset (loop-invariant)
    int off = offsets[d], deg = offsets[d + 1] - off;
    float ald = al_d[d * HEADS + g];
    float aself = lrelu(al_s[d * HEADS + g] + ald);
    float m = aself;
    for (int e = 0; e < deg; e++){
        int s = __builtin_amdgcn_readfirstlane(esrc[off + e]);
        m = fmaxf(m, lrelu(al_s[s * HEADS + g] + ald));
    }
    float wself = __expf(aself - m);
    float denom = wself;
    for (int e = 0; e < deg; e++){
        int s = __builtin_amdgcn_readfirstlane(esrc[off + e]);
        denom += __expf(lrelu(al_s[s * HEADS + g] + ald) - m);
    }
    float acc[8];
    {   // self edge
        short8 v = *(const short8*)(h1b + (size_t)d * HH + cb);
        unsigned int u[4]; __builtin_memcpy(u, &v, 16);
#pragma unroll
        for (int j = 0; j < 4; j++){
            acc[2*j]   = wself * __uint_as_float(u[j] << 16);
            acc[2*j+1] = wself * __uint_as_float(u[j] & 0xffff0000u);
        }
    }
    int e = 0;
    for (; e + 2 <= deg; e += 2){
        int s0 = __builtin_amdgcn_readfirstlane(esrc[off + e]);
        int s1 = __builtin_amdgcn_readfirstlane(esrc[off + e + 1]);
        float w0 = __expf(lrelu(al_s[s0 * HEADS + g] + ald) - m);
        float w1 = __expf(lrelu(al_s[s1 * HEADS + g] + ald) - m);
        short8 v0 = *(const short8*)(h1b + (size_t)s0 * HH + cb);
        short8 v1 = *(const short8*)(h1b + (size_t)s1 * HH + cb);
        fma8(acc, w0, v0); fma8(acc, w1, v1);
    }
    if (e < deg){
        int s0 = __builtin_amdgcn_readfirstlane(esrc[off + e]);
        float w0 = __expf(lrelu(al_s[s0 * HEADS + g] + ald) - m);
        short8 v0 = *(const short8*)(h1b + (size_t)s0 * HH + cb);
        fma8(acc, w0, v0);
    }
    float di = 1.f / denom;
    unsigned short o8[8];
#pragma unroll
    for (int j = 0; j < 8; j++){
        float v = acc[j] * di + b1[cb + j];
        v = v > 0.f ? v : __expf(v) - 1.f;   // elu
        o8[j] = f2bf(v);
    }
    short8 ov; __builtin_memcpy(&ov, o8, 16);
    *(short8*)(x2b + (size_t)d * HH + cb) = ov;
}

// ---------------- layer-2 GEMM via MFMA: h2 = x2b @ W2 (+ fused attention dots) --------
__global__ __launch_bounds__(256) void gemm2(const unsigned short* __restrict__ x2b,
        const unsigned short* __restrict__ w2t,
        const float* __restrict__ a_s2, const float* __restrict__ a_d2,
        float* __restrict__ h2, float* __restrict__ al2s, float* __restrict__ al2d){
    int wave = (blockIdx.x * blockDim.x + threadIdx.x) >> 6;
    int lane = threadIdx.x & 63;
    if (wave >= N_NODES / 16) return;
    int rowbase = wave * 16;
    int lr = lane & 15, lk = lane >> 4;
    float4v acc = {0.f, 0.f, 0.f, 0.f};
#pragma unroll
    for (int ks = 0; ks < 16; ks++){
        short8 a = *(const short8*)(x2b + (size_t)(rowbase + lr) * HH + ks * 32 + lk * 8);
        short8 b = *(const short8*)(w2t + (size_t)lr * HH + ks * 32 + lk * 8);
        acc = __builtin_amdgcn_mfma_f32_16x16x32_bf16(a, b, acc, 0, 0, 0);
    }
#pragma unroll
    for (int r = 0; r < 4; r++)
        h2[(size_t)(rowbase + lk * 4 + r) * NCLS + lr] = acc[r];
    float s_a = a_s2[lr], d_a = a_d2[lr];
#pragma unroll
    for (int r = 0; r < 4; r++){
        float ps = acc[r] * s_a, pd = acc[r] * d_a;
#pragma unroll
        for (int off = 1; off < 16; off <<= 1){
            ps += __shfl_xor(ps, off);
            pd += __shfl_xor(pd, off);
        }
        if (lr == 0){
            al2s[rowbase + lk * 4 + r] = ps;
            al2d[rowbase + lk * 4 + r] = pd;
        }
    }
}

// ---------------- layer-2: fused softmax + aggregation -> out [N][16] fp32 ----------------
// one wave per dst; 64-lane parallel max/denom passes, then 4x16 gather pass.
__global__ __launch_bounds__(256) void agg2(const float* __restrict__ h2,
        const float* __restrict__ al2s, const float* __restrict__ al2d,
        const int* __restrict__ offsets, const int* __restrict__ esrc,
        const float* __restrict__ b2, float* __restrict__ out){
    int d = blockIdx.x * 4 + (threadIdx.x >> 6);
    int lane = threadIdx.x & 63;
    if (d >= N_NODES) return;
    int off = offsets[d], deg = offsets[d + 1] - off;
    float ald = al2d[d];
    float a0 = lrelu(al2s[d] + ald);
    float m = a0;
    for (int base = 0; base < deg; base += 64){
        int e = base + lane;
        float a = (e < deg) ? lrelu(al2s[esrc[off + e]] + ald) : -1e30f;
#pragma unroll
        for (int o = 1; o < 64; o <<= 1) a = fmaxf(a, __shfl_xor(a, o));
        m = fmaxf(m, a);
    }
    float dsum = __expf(a0 - m);
    for (int base = 0; base < deg; base += 64){
        int e = base + lane;
        float w = (e < deg) ? __expf(lrelu(al2s[esrc[off + e]] + ald) - m) : 0.f;
#pragma unroll
        for (int o = 1; o < 64; o <<= 1) w += __shfl_xor(w, o);
        dsum += w;
    }
    int sg = lane >> 4, col = lane & 15;
    float acc = (sg == 0) ? __expf(a0 - m) * h2[(size_t)d * NCLS + col] : 0.f;
    for (int i = sg; i < deg; i += 4){
        int s = esrc[off + i];
        float w = __expf(lrelu(al2s[s] + ald) - m);
        acc += w * h2[(size_t)s * NCLS + col];
    }
    acc += __shfl_xor(acc, 16);
    acc += __shfl_xor(acc, 32);
    if (lane < NCLS) out[(size_t)d * NCLS + lane] = acc / dsum + b2[lane];
}

extern "C" void kernel_launch(void* const* d_in, const int* in_sizes, int n_in,
                              void* d_out, int out_size, void* d_ws, size_t ws_size,
                              hipStream_t stream){
    const float* x   = (const float*)d_in[0];
    const int*   ei  = (const int*)d_in[1];
    const int*   src = ei;
    const int*   dst = ei + NEDGE;
    const float* W1  = (const float*)d_in[2];
    const float* as1 = (const float*)d_in[3];
    const float* ad1 = (const float*)d_in[4];
    const float* b1  = (const float*)d_in[5];
    const float* W2  = (const float*)d_in[6];
    const float* as2 = (const float*)d_in[7];
    const float* ad2 = (const float*)d_in[8];
    const float* b2  = (const float*)d_in[9];
    float* out = (float*)d_out;

    char* p = (char*)d_ws;
    auto carve = [&](size_t bytes) -> char* {
        char* r = p; p += (bytes + 255) & ~(size_t)255; return r;
    };
    unsigned short* xb   = (unsigned short*)carve((size_t)N_NODES * F_INK * 2);
    unsigned short* w1t  = (unsigned short*)carve((size_t)HH * F_INK * 2);
    unsigned short* w2t  = (unsigned short*)carve((size_t)HH * NCLS * 2);
    unsigned short* h1b  = (unsigned short*)carve((size_t)N_NODES * HH * 2);
    float* al1s  = (float*)carve((size_t)N_NODES * HEADS * 4);
    float* al1d  = (float*)carve((size_t)N_NODES * HEADS * 4);
    int* counts  = (int*)carve((size_t)N_NODES * 4);
    int* cursor  = (int*)carve((size_t)N_NODES * 4);
    int* offsets = (int*)carve((size_t)(N_NODES + 1) * 4);
    int* blocksums = (int*)carve((size_t)NBLK_SCAN * 4);
    int* blockbase = (int*)carve((size_t)NBLK_SCAN * 4);
    int* esrc    = (int*)carve((size_t)NEDGE * 4);
    unsigned short* x2b = (unsigned short*)carve((size_t)N_NODES * HH * 2);
    float* h2    = (float*)carve((size_t)N_NODES * NCLS * 4);
    float* al2s  = (float*)carve((size_t)N_NODES * 4);
    float* al2d  = (float*)carve((size_t)N_NODES * 4);
    if ((size_t)(p - (char*)d_ws) > ws_size) return;  // workspace too small

    hipMemsetAsync(counts, 0, N_NODES * 4, stream);
    hipMemsetAsync(cursor, 0, N_NODES * 4, stream);

    cvt_f32_bf16<<<2048, 256, 0, stream>>>(x, xb, N_NODES * F_INK / 4);
    cvt_w1t<<<(F_INK * HH + 255) / 256, 256, 0, stream>>>(W1, w1t);
    cvt_w2t<<<(HH * NCLS + 255) / 256, 256, 0, stream>>>(W2, w2t);
    count_edges<<<(NEDGE + 255) / 256, 256, 0, stream>>>(dst, counts);
    scan_part<<<NBLK_SCAN, 256, 0, stream>>>(counts, blocksums);
    scan_top<<<1, 256, 0, stream>>>(blocksums, blockbase, offsets);
    scan_write<<<NBLK_SCAN, 256, 0, stream>>>(counts, blockbase, offsets);
    scatter_edges<<<(NEDGE + 255) / 256, 256, 0, stream>>>(src, dst, offsets, cursor, esrc);
    gemm1<<<8 * 128, 256, 0, stream>>>(xb, w1t, h1b);
    attn1_dots<<<(N_NODES + 3) / 4, 256, 0, stream>>>(h1b, as1, ad1, al1s, al1d);
    agg1<<<(N_NODES + 3) / 4, 256, 0, stream>>>(h1b, al1s, al1d, offsets, esrc, b1, x2b);
    gemm2<<<(N_NODES / 16 + 3) / 4, 256, 0, stream>>>(x2b, w2t, as2, ad2, h2, al2s, al2d);
    agg2<<<(N_NODES + 3) / 4, 256, 0, stream>>>(h2, al2s, al2d, offsets, esrc, b2, out);
}

// Round 10
// 267.448 us; speedup vs baseline: 1.1206x; 1.1206x over previous
//
#include <hip/hip_runtime.h>
#include <hip/hip_bf16.h>
#include <math.h>

#define N_NODES 50000
#define F_INK   256
#define HEADS   8
#define HID     64
#define HH      512     // HEADS*HID
#define NCLS    16
#define NEDGE   400000
#define NEG_SLOPE 0.2f

#define BCOLS 64
#define KPAD  264       // 256 + 8 bf16 pad -> optimal quad-bank spread
#define NBLK_SCAN ((N_NODES + 255) / 256)   // 196

typedef __attribute__((ext_vector_type(8))) short short8;
typedef __attribute__((ext_vector_type(4))) short sh4;
typedef __attribute__((ext_vector_type(4))) float float4v;

__device__ __forceinline__ float bf2f(unsigned short u){
    unsigned int x = ((unsigned int)u) << 16;
    float f; __builtin_memcpy(&f, &x, 4); return f;
}
__device__ __forceinline__ unsigned short f2bf(float f){
    unsigned int x; __builtin_memcpy(&x, &f, 4);
    unsigned int r = x + 0x7FFFu + ((x >> 16) & 1u);   // RNE
    return (unsigned short)(r >> 16);
}
__device__ __forceinline__ float lrelu(float a){ return a > 0.f ? a : NEG_SLOPE * a; }

// dword-level bf16x2 unpack + fma: 1 VALU unpack + 1 fma per element
__device__ __forceinline__ void fma8(float* acc, float w, short8 v){
    unsigned int u[4]; __builtin_memcpy(u, &v, 16);
#pragma unroll
    for (int j = 0; j < 4; j++){
        acc[2*j]   += w * __uint_as_float(u[j] << 16);
        acc[2*j+1] += w * __uint_as_float(u[j] & 0xffff0000u);
    }
}

// ---------------- conversions ----------------
__global__ void cvt_f32_bf16(const float* __restrict__ in, unsigned short* __restrict__ out, int n4){
    int i = blockIdx.x * blockDim.x + threadIdx.x;
    int stride = gridDim.x * blockDim.x;
    for (; i < n4; i += stride){
        float4v f = *(const float4v*)(in + (size_t)i * 4);
        sh4 o;
#pragma unroll
        for (int j = 0; j < 4; j++) o[j] = (short)f2bf(f[j]);
        *(sh4*)(out + (size_t)i * 4) = o;
    }
}

// W1 [256][512] -> W1T [512][256] bf16  AND  W2 [512][16] -> W2T [16][512] bf16
__global__ void cvt_weights(const float* __restrict__ W1, unsigned short* __restrict__ W1T,
                            const float* __restrict__ W2, unsigned short* __restrict__ W2T){
    int i = blockIdx.x * blockDim.x + threadIdx.x;
    if (i < F_INK * HH){
        int k = i / HH, c = i % HH;
        W1T[c * F_INK + k] = f2bf(W1[i]);
    }
    int j = i - F_INK * HH;
    if (j >= 0 && j < HH * NCLS){
        int k = j / NCLS, c = j % NCLS;
        W2T[c * HH + k] = f2bf(W2[j]);
    }
}

// ---------------- CSR build ----------------
__global__ void count_edges(const int* __restrict__ dst, int* __restrict__ counts){
    int e = blockIdx.x * blockDim.x + threadIdx.x;
    if (e < NEDGE) atomicAdd(&counts[dst[e]], 1);
}

__global__ __launch_bounds__(256) void scan_part(const int* __restrict__ counts,
                                                 int* __restrict__ blocksums){
    __shared__ int red[256];
    int i = blockIdx.x * 256 + threadIdx.x;
    int v = (i < N_NODES) ? counts[i] : 0;
    red[threadIdx.x] = v; __syncthreads();
    for (int off = 128; off > 0; off >>= 1){
        if (threadIdx.x < off) red[threadIdx.x] += red[threadIdx.x + off];
        __syncthreads();
    }
    if (threadIdx.x == 0) blocksums[blockIdx.x] = red[0];
}

__global__ __launch_bounds__(256) void scan_top(const int* __restrict__ blocksums,
                                                int* __restrict__ blockbase,
                                                int* __restrict__ offsets){
    __shared__ int s[256];
    int t = threadIdx.x;
    int v = (t < NBLK_SCAN) ? blocksums[t] : 0;
    s[t] = v; __syncthreads();
    int val = v;
    for (int off = 1; off < 256; off <<= 1){
        int o2 = (t >= off) ? s[t - off] : 0;
        __syncthreads();
        val += o2; s[t] = val;
        __syncthreads();
    }
    if (t < NBLK_SCAN) blockbase[t] = val - v;   // exclusive
    if (t == 255) offsets[N_NODES] = s[255];     // grand total
}

__global__ __launch_bounds__(256) void scan_write(const int* __restrict__ counts,
                                                  const int* __restrict__ blockbase,
                                                  int* __restrict__ offsets){
    __shared__ int s[256];
    int i = blockIdx.x * 256 + threadIdx.x;
    int t = threadIdx.x;
    int v = (i < N_NODES) ? counts[i] : 0;
    s[t] = v; __syncthreads();
    int val = v;
    for (int off = 1; off < 256; off <<= 1){
        int o2 = (t >= off) ? s[t - off] : 0;
        __syncthreads();
        val += o2; s[t] = val;
        __syncthreads();
    }
    if (i < N_NODES) offsets[i] = blockbase[blockIdx.x] + val - v;
}

__global__ void scatter_edges(const int* __restrict__ src, const int* __restrict__ dst,
                              const int* __restrict__ offsets, int* __restrict__ cursor,
                              int* __restrict__ esrc){
    int e = blockIdx.x * blockDim.x + threadIdx.x;
    if (e < NEDGE){
        int d = dst[e];
        int pos = offsets[d] + atomicAdd(&cursor[d], 1);
        esrc[pos] = src[e];
    }
}

// ---------------- GEMM1 + fused attention dots ----------------
// block owns 64-col panel cb == head cb; computes h1 tile AND al_s/al_d for head cb.
__global__ __launch_bounds__(256) void gemm1(const unsigned short* __restrict__ xb,
                                             const unsigned short* __restrict__ w1t,
                                             const float* __restrict__ a_src,
                                             const float* __restrict__ a_dst,
                                             unsigned short* __restrict__ h1b,
                                             float* __restrict__ al_s,
                                             float* __restrict__ al_d){
    __shared__ unsigned short bs[BCOLS * KPAD];   // 33 KB
    int cb  = blockIdx.x & 7;          // col panel == head
    int rg  = blockIdx.x >> 3;
    int nrg = gridDim.x >> 3;
    {   // stage B panel once
        int kc = threadIdx.x & 31;
        int c0 = threadIdx.x >> 5;
#pragma unroll
        for (int it = 0; it < 8; it++){
            int col = it * 8 + c0;
            short8 v = *(const short8*)(w1t + (size_t)(cb * BCOLS + col) * F_INK + kc * 8);
            *(short8*)(&bs[col * KPAD + kc * 8]) = v;
        }
    }
    __syncthreads();
    int w    = threadIdx.x >> 6;
    int lane = threadIdx.x & 63;
    int lr = lane & 15, lk = lane >> 4;
    // per-lane attention vector entries for this panel's 4 column sub-tiles
    float a_s[4], a_d[4];
#pragma unroll
    for (int ct = 0; ct < 4; ct++){
        a_s[ct] = a_src[cb * HID + ct * 16 + lr];
        a_d[ct] = a_dst[cb * HID + ct * 16 + lr];
    }
    const int nchunk = (N_NODES + 63) / 64;       // 782
    for (int ch = rg; ch < nchunk; ch += nrg){
        int rowbase = ch * 64 + w * 16;
        if (rowbase >= N_NODES) continue;
        short8 a[8];
#pragma unroll
        for (int ks = 0; ks < 8; ks++)
            a[ks] = *(const short8*)(xb + (size_t)(rowbase + lr) * F_INK + ks * 32 + lk * 8);
        float ds[4] = {0.f,0.f,0.f,0.f}, dd[4] = {0.f,0.f,0.f,0.f};
#pragma unroll
        for (int ct = 0; ct < 4; ct++){
            float4v acc = {0.f, 0.f, 0.f, 0.f};
#pragma unroll
            for (int ks = 0; ks < 8; ks++){
                short8 b = *(const short8*)(&bs[(ct * 16 + lr) * KPAD + ks * 32 + lk * 8]);
                acc = __builtin_amdgcn_mfma_f32_16x16x32_bf16(a[ks], b, acc, 0, 0, 0);
            }
#pragma unroll
            for (int r = 0; r < 4; r++){
                h1b[(size_t)(rowbase + lk * 4 + r) * HH + cb * BCOLS + ct * 16 + lr] = f2bf(acc[r]);
                ds[r] += acc[r] * a_s[ct];
                dd[r] += acc[r] * a_d[ct];
            }
        }
        // reduce over lr (16 lanes) and write dots for head cb
#pragma unroll
        for (int r = 0; r < 4; r++){
#pragma unroll
            for (int o = 1; o < 16; o <<= 1){
                ds[r] += __shfl_xor(ds[r], o);
                dd[r] += __shfl_xor(dd[r], o);
            }
        }
        if (lr == 0){
#pragma unroll
            for (int r = 0; r < 4; r++){
                al_s[(rowbase + lk * 4 + r) * HEADS + cb] = ds[r];
                al_d[(rowbase + lk * 4 + r) * HEADS + cb] = dd[r];
            }
        }
    }
}

// ---------------- layer-1 softmax: raw weights ew, wselfr, dinv ----------------
__global__ __launch_bounds__(256) void softmax1(
        const float* __restrict__ al_s, const float* __restrict__ al_d,
        const int* __restrict__ offsets, const int* __restrict__ esrc,
        float* __restrict__ ew, float* __restrict__ wselfr, float* __restrict__ dinv){
    int d = blockIdx.x * 4 + (threadIdx.x >> 6);
    int lane = threadIdx.x & 63;
    if (d >= N_NODES) return;
    int h = lane & 7, i = lane >> 3;
    int off = offsets[d], deg = offsets[d + 1] - off;
    float ald = al_d[d * HEADS + h];
    float aself = lrelu(al_s[d * HEADS + h] + ald);
    float m = aself;
    for (int base = 0; base < deg; base += 8){
        int e = base + i;
        float a = -1e30f;
        if (e < deg) a = lrelu(al_s[esrc[off + e] * HEADS + h] + ald);
        a = fmaxf(a, __shfl_xor(a, 8));
        a = fmaxf(a, __shfl_xor(a, 16));
        a = fmaxf(a, __shfl_xor(a, 32));
        m = fmaxf(m, a);
    }
    float denom = __expf(aself - m);
    for (int base = 0; base < deg; base += 8){
        int e = base + i;
        float w = 0.f;
        if (e < deg){
            w = __expf(lrelu(al_s[esrc[off + e] * HEADS + h] + ald) - m);
            ew[(size_t)(off + e) * HEADS + h] = w;    // unnormalized
        }
        float ws = w;
        ws += __shfl_xor(ws, 8);
        ws += __shfl_xor(ws, 16);
        ws += __shfl_xor(ws, 32);
        denom += ws;
    }
    if (i == 0){
        wselfr[d * HEADS + h] = __expf(aself - m);
        dinv[d * HEADS + h]   = 1.f / denom;
    }
}

// ---------------- layer-1 aggregation: one wave per dst, no LDS ----------------
__global__ __launch_bounds__(256) void agg1(const unsigned short* __restrict__ h1b,
        const float* __restrict__ ew, const float* __restrict__ wselfr,
        const float* __restrict__ dinv,
        const int* __restrict__ offsets, const int* __restrict__ esrc,
        const float* __restrict__ b1, unsigned short* __restrict__ x2b){
    int d = blockIdx.x * 4 + (threadIdx.x >> 6);
    if (d >= N_NODES) return;
    int lane = threadIdx.x & 63;
    int g = lane >> 3;
    int cb = g * HID + (lane & 7) * 8;     // lane's column offset (loop-invariant)
    int off = offsets[d], deg = offsets[d + 1] - off;
    float acc[8];
    {   // self edge
        float w0 = wselfr[d * HEADS + g];
        short8 v = *(const short8*)(h1b + (size_t)d * HH + cb);
        unsigned int u[4]; __builtin_memcpy(u, &v, 16);
#pragma unroll
        for (int j = 0; j < 4; j++){
            acc[2*j]   = w0 * __uint_as_float(u[j] << 16);
            acc[2*j+1] = w0 * __uint_as_float(u[j] & 0xffff0000u);
        }
    }
    int e = 0;
    for (; e + 4 <= deg; e += 4){
        int s0 = __builtin_amdgcn_readfirstlane(esrc[off + e]);
        int s1 = __builtin_amdgcn_readfirstlane(esrc[off + e + 1]);
        int s2 = __builtin_amdgcn_readfirstlane(esrc[off + e + 2]);
        int s3 = __builtin_amdgcn_readfirstlane(esrc[off + e + 3]);
        float w0 = ew[(size_t)(off + e)     * HEADS + g];
        float w1 = ew[(size_t)(off + e + 1) * HEADS + g];
        float w2 = ew[(size_t)(off + e + 2) * HEADS + g];
        float w3 = ew[(size_t)(off + e + 3) * HEADS + g];
        short8 v0 = *(const short8*)(h1b + (size_t)s0 * HH + cb);
        short8 v1 = *(const short8*)(h1b + (size_t)s1 * HH + cb);
        short8 v2 = *(const short8*)(h1b + (size_t)s2 * HH + cb);
        short8 v3 = *(const short8*)(h1b + (size_t)s3 * HH + cb);
        fma8(acc, w0, v0); fma8(acc, w1, v1);
        fma8(acc, w2, v2); fma8(acc, w3, v3);
    }
    for (; e < deg; e++){
        int s0 = __builtin_amdgcn_readfirstlane(esrc[off + e]);
        float w0 = ew[(size_t)(off + e) * HEADS + g];
        short8 v0 = *(const short8*)(h1b + (size_t)s0 * HH + cb);
        fma8(acc, w0, v0);
    }
    float di = dinv[d * HEADS + g];
    unsigned short o8[8];
#pragma unroll
    for (int j = 0; j < 8; j++){
        float v = acc[j] * di + b1[cb + j];
        v = v > 0.f ? v : __expf(v) - 1.f;   // elu
        o8[j] = f2bf(v);
    }
    short8 ov; __builtin_memcpy(&ov, o8, 16);
    *(short8*)(x2b + (size_t)d * HH + cb) = ov;
}

// ---------------- layer-2 GEMM via MFMA: h2 = x2b @ W2 (+ fused attention dots) --------
__global__ __launch_bounds__(256) void gemm2(const unsigned short* __restrict__ x2b,
        const unsigned short* __restrict__ w2t,
        const float* __restrict__ a_s2, const float* __restrict__ a_d2,
        float* __restrict__ h2, float* __restrict__ al2s, float* __restrict__ al2d){
    int wave = (blockIdx.x * blockDim.x + threadIdx.x) >> 6;
    int lane = threadIdx.x & 63;
    if (wave >= N_NODES / 16) return;
    int rowbase = wave * 16;
    int lr = lane & 15, lk = lane >> 4;
    float4v acc = {0.f, 0.f, 0.f, 0.f};
#pragma unroll
    for (int ks = 0; ks < 16; ks++){
        short8 a = *(const short8*)(x2b + (size_t)(rowbase + lr) * HH + ks * 32 + lk * 8);
        short8 b = *(const short8*)(w2t + (size_t)lr * HH + ks * 32 + lk * 8);
        acc = __builtin_amdgcn_mfma_f32_16x16x32_bf16(a, b, acc, 0, 0, 0);
    }
#pragma unroll
    for (int r = 0; r < 4; r++)
        h2[(size_t)(rowbase + lk * 4 + r) * NCLS + lr] = acc[r];
    float s_a = a_s2[lr], d_a = a_d2[lr];
#pragma unroll
    for (int r = 0; r < 4; r++){
        float ps = acc[r] * s_a, pd = acc[r] * d_a;
#pragma unroll
        for (int off = 1; off < 16; off <<= 1){
            ps += __shfl_xor(ps, off);
            pd += __shfl_xor(pd, off);
        }
        if (lr == 0){
            al2s[rowbase + lk * 4 + r] = ps;
            al2d[rowbase + lk * 4 + r] = pd;
        }
    }
}

// ---------------- layer-2 softmax weights ----------------
__global__ __launch_bounds__(256) void softmax2(
        const float* __restrict__ al2s, const float* __restrict__ al2d,
        const int* __restrict__ offsets, const int* __restrict__ esrc,
        float* __restrict__ ew2, float* __restrict__ wself2){
    int d = blockIdx.x * 4 + (threadIdx.x >> 6);
    int lane = threadIdx.x & 63;
    if (d >= N_NODES) return;
    int off = offsets[d], deg = offsets[d + 1] - off;
    float ald = al2d[d];
    float aself = lrelu(al2s[d] + ald);
    float m = aself;
    for (int base = 0; base < deg; base += 64){
        int e = base + lane;
        float a = (e < deg) ? lrelu(al2s[esrc[off + e]] + ald) : -1e30f;
#pragma unroll
        for (int o = 1; o < 64; o <<= 1) a = fmaxf(a, __shfl_xor(a, o));
        m = fmaxf(m, a);
    }
    float denom = __expf(aself - m);
    for (int base = 0; base < deg; base += 64){
        int e = base + lane;
        float w = 0.f;
        if (e < deg){
            w = __expf(lrelu(al2s[esrc[off + e]] + ald) - m);
            ew2[off + e] = w;
        }
#pragma unroll
        for (int o = 1; o < 64; o <<= 1) w += __shfl_xor(w, o);
        denom += w;
    }
    float inv = 1.f / denom;
    if (lane == 0) wself2[d] = __expf(aself - m) * inv;
    for (int base = 0; base < deg; base += 64){
        int e = base + lane;
        if (e < deg) ew2[off + e] *= inv;
    }
}

// ---------------- layer-2 aggregation -> out [N][16] fp32 ----------------
__global__ __launch_bounds__(256) void agg2(const float* __restrict__ h2,
        const float* __restrict__ ew2, const float* __restrict__ wself2,
        const int* __restrict__ offsets, const int* __restrict__ esrc,
        const float* __restrict__ b2, float* __restrict__ out){
    int d = blockIdx.x * 4 + (threadIdx.x >> 6);
    int lane = threadIdx.x & 63;
    if (d >= N_NODES) return;
    int off = offsets[d], deg = offsets[d + 1] - off;
    int sg = lane >> 4, col = lane & 15;
    float acc = (sg == 0) ? wself2[d] * h2[(size_t)d * NCLS + col] : 0.f;
    for (int i = sg; i < deg; i += 4){
        int s = esrc[off + i];
        acc += ew2[off + i] * h2[(size_t)s * NCLS + col];
    }
    acc += __shfl_xor(acc, 16);
    acc += __shfl_xor(acc, 32);
    if (lane < NCLS) out[(size_t)d * NCLS + lane] = acc + b2[lane];
}

extern "C" void kernel_launch(void* const* d_in, const int* in_sizes, int n_in,
                              void* d_out, int out_size, void* d_ws, size_t ws_size,
                              hipStream_t stream){
    const float* x   = (const float*)d_in[0];
    const int*   ei  = (const int*)d_in[1];
    const int*   src = ei;
    const int*   dst = ei + NEDGE;
    const float* W1  = (const float*)d_in[2];
    const float* as1 = (const float*)d_in[3];
    const float* ad1 = (const float*)d_in[4];
    const float* b1  = (const float*)d_in[5];
    const float* W2  = (const float*)d_in[6];
    const float* as2 = (const float*)d_in[7];
    const float* ad2 = (const float*)d_in[8];
    const float* b2  = (const float*)d_in[9];
    float* out = (float*)d_out;

    char* p = (char*)d_ws;
    auto carve = [&](size_t bytes) -> char* {
        char* r = p; p += (bytes + 255) & ~(size_t)255; return r;
    };
    unsigned short* xb   = (unsigned short*)carve((size_t)N_NODES * F_INK * 2);
    unsigned short* w1t  = (unsigned short*)carve((size_t)HH * F_INK * 2);
    unsigned short* w2t  = (unsigned short*)carve((size_t)HH * NCLS * 2);
    unsigned short* h1b  = (unsigned short*)carve((size_t)N_NODES * HH * 2);
    float* al1s  = (float*)carve((size_t)N_NODES * HEADS * 4);
    float* al1d  = (float*)carve((size_t)N_NODES * HEADS * 4);
    int* counts  = (int*)carve((size_t)N_NODES * 4);
    int* cursor  = (int*)carve((size_t)N_NODES * 4);
    int* offsets = (int*)carve((size_t)(N_NODES + 1) * 4);
    int* blocksums = (int*)carve((size_t)NBLK_SCAN * 4);
    int* blockbase = (int*)carve((size_t)NBLK_SCAN * 4);
    int* esrc    = (int*)carve((size_t)NEDGE * 4);
    float* ew    = (float*)carve((size_t)NEDGE * HEADS * 4);
    float* wselfr= (float*)carve((size_t)N_NODES * HEADS * 4);
    float* dinv  = (float*)carve((size_t)N_NODES * HEADS * 4);
    unsigned short* x2b = (unsigned short*)carve((size_t)N_NODES * HH * 2);
    float* h2    = (float*)carve((size_t)N_NODES * NCLS * 4);
    float* al2s  = (float*)carve((size_t)N_NODES * 4);
    float* al2d  = (float*)carve((size_t)N_NODES * 4);
    float* ew2   = (float*)carve((size_t)NEDGE * 4);
    float* wself2= (float*)carve((size_t)N_NODES * 4);
    if ((size_t)(p - (char*)d_ws) > ws_size) return;  // workspace too small

    hipMemsetAsync(counts, 0, N_NODES * 4, stream);
    hipMemsetAsync(cursor, 0, N_NODES * 4, stream);

    cvt_f32_bf16<<<2048, 256, 0, stream>>>(x, xb, N_NODES * F_INK / 4);
    cvt_weights<<<(F_INK * HH + HH * NCLS + 255) / 256, 256, 0, stream>>>(W1, w1t, W2, w2t);
    count_edges<<<(NEDGE + 255) / 256, 256, 0, stream>>>(dst, counts);
    scan_part<<<NBLK_SCAN, 256, 0, stream>>>(counts, blocksums);
    scan_top<<<1, 256, 0, stream>>>(blocksums, blockbase, offsets);
    scan_write<<<NBLK_SCAN, 256, 0, stream>>>(counts, blockbase, offsets);
    scatter_edges<<<(NEDGE + 255) / 256, 256, 0, stream>>>(src, dst, offsets, cursor, esrc);
    gemm1<<<8 * 128, 256, 0, stream>>>(xb, w1t, as1, ad1, h1b, al1s, al1d);
    softmax1<<<(N_NODES + 3) / 4, 256, 0, stream>>>(al1s, al1d, offsets, esrc, ew, wselfr, dinv);
    agg1<<<(N_NODES + 3) / 4, 256, 0, stream>>>(h1b, ew, wselfr, dinv, offsets, esrc, b1, x2b);
    gemm2<<<(N_NODES / 16 + 3) / 4, 256, 0, stream>>>(x2b, w2t, as2, ad2, h2, al2s, al2d);
    softmax2<<<(N_NODES + 3) / 4, 256, 0, stream>>>(al2s, al2d, offsets, esrc, ew2, wself2);
    agg2<<<(N_NODES + 3) / 4, 256, 0, stream>>>(h2, ew2, wself2, offsets, esrc, b2, out);
}

// Round 11
// 257.924 us; speedup vs baseline: 1.1620x; 1.0369x over previous
//
#include <hip/hip_runtime.h>
#include <hip/hip_bf16.h>
#include <math.h>

#define N_NODES 50000
#define F_INK   256
#define HEADS   8
#define HID     64
#define HH      512     // HEADS*HID
#define NCLS    16
#define NEDGE   400000
#define NEG_SLOPE 0.2f

#define BCOLS 64
#define KPAD  264       // 256 + 8 bf16 pad -> optimal quad-bank spread
#define NBLK_SCAN ((N_NODES + 255) / 256)   // 196

typedef __attribute__((ext_vector_type(8))) short short8;
typedef __attribute__((ext_vector_type(4))) short sh4;
typedef __attribute__((ext_vector_type(4))) float float4v;

__device__ __forceinline__ float bf2f(unsigned short u){
    unsigned int x = ((unsigned int)u) << 16;
    float f; __builtin_memcpy(&f, &x, 4); return f;
}
__device__ __forceinline__ unsigned short f2bf(float f){
    unsigned int x; __builtin_memcpy(&x, &f, 4);
    unsigned int r = x + 0x7FFFu + ((x >> 16) & 1u);   // RNE
    return (unsigned short)(r >> 16);
}
__device__ __forceinline__ float lrelu(float a){ return a > 0.f ? a : NEG_SLOPE * a; }

// dword-level bf16x2 unpack + fma: 1 VALU unpack + 1 fma per element
__device__ __forceinline__ void fma8(float* acc, float w, short8 v){
    unsigned int u[4]; __builtin_memcpy(u, &v, 16);
#pragma unroll
    for (int j = 0; j < 4; j++){
        acc[2*j]   += w * __uint_as_float(u[j] << 16);
        acc[2*j+1] += w * __uint_as_float(u[j] & 0xffff0000u);
    }
}

// ---------------- conversions ----------------
__global__ void cvt_f32_bf16(const float* __restrict__ in, unsigned short* __restrict__ out, int n4){
    int i = blockIdx.x * blockDim.x + threadIdx.x;
    int stride = gridDim.x * blockDim.x;
    for (; i < n4; i += stride){
        float4v f = *(const float4v*)(in + (size_t)i * 4);
        sh4 o;
#pragma unroll
        for (int j = 0; j < 4; j++) o[j] = (short)f2bf(f[j]);
        *(sh4*)(out + (size_t)i * 4) = o;
    }
}

// W1 [256][512] -> W1T [512][256] bf16  AND  W2 [512][16] -> W2T [16][512] bf16
__global__ void cvt_weights(const float* __restrict__ W1, unsigned short* __restrict__ W1T,
                            const float* __restrict__ W2, unsigned short* __restrict__ W2T){
    int i = blockIdx.x * blockDim.x + threadIdx.x;
    if (i < F_INK * HH){
        int k = i / HH, c = i % HH;
        W1T[c * F_INK + k] = f2bf(W1[i]);
    }
    int j = i - F_INK * HH;
    if (j >= 0 && j < HH * NCLS){
        int k = j / NCLS, c = j % NCLS;
        W2T[c * HH + k] = f2bf(W2[j]);
    }
}

// ---------------- CSR build ----------------
// counts + per-edge rank in one atomic pass
__global__ void count_edges(const int* __restrict__ dst, int* __restrict__ counts,
                            int* __restrict__ erank){
    int e = blockIdx.x * blockDim.x + threadIdx.x;
    if (e < NEDGE) erank[e] = atomicAdd(&counts[dst[e]], 1);
}

__global__ __launch_bounds__(256) void scan_part(const int* __restrict__ counts,
                                                 int* __restrict__ blocksums){
    __shared__ int red[256];
    int i = blockIdx.x * 256 + threadIdx.x;
    int v = (i < N_NODES) ? counts[i] : 0;
    red[threadIdx.x] = v; __syncthreads();
    for (int off = 128; off > 0; off >>= 1){
        if (threadIdx.x < off) red[threadIdx.x] += red[threadIdx.x + off];
        __syncthreads();
    }
    if (threadIdx.x == 0) blocksums[blockIdx.x] = red[0];
}

__global__ __launch_bounds__(256) void scan_top(const int* __restrict__ blocksums,
                                                int* __restrict__ blockbase,
                                                int* __restrict__ offsets){
    __shared__ int s[256];
    int t = threadIdx.x;
    int v = (t < NBLK_SCAN) ? blocksums[t] : 0;
    s[t] = v; __syncthreads();
    int val = v;
    for (int off = 1; off < 256; off <<= 1){
        int o2 = (t >= off) ? s[t - off] : 0;
        __syncthreads();
        val += o2; s[t] = val;
        __syncthreads();
    }
    if (t < NBLK_SCAN) blockbase[t] = val - v;   // exclusive
    if (t == 255) offsets[N_NODES] = s[255];     // grand total
}

__global__ __launch_bounds__(256) void scan_write(const int* __restrict__ counts,
                                                  const int* __restrict__ blockbase,
                                                  int* __restrict__ offsets){
    __shared__ int s[256];
    int i = blockIdx.x * 256 + threadIdx.x;
    int t = threadIdx.x;
    int v = (i < N_NODES) ? counts[i] : 0;
    s[t] = v; __syncthreads();
    int val = v;
    for (int off = 1; off < 256; off <<= 1){
        int o2 = (t >= off) ? s[t - off] : 0;
        __syncthreads();
        val += o2; s[t] = val;
        __syncthreads();
    }
    if (i < N_NODES) offsets[i] = blockbase[blockIdx.x] + val - v;
}

__global__ void scatter_edges(const int* __restrict__ src, const int* __restrict__ dst,
                              const int* __restrict__ offsets, const int* __restrict__ erank,
                              int* __restrict__ esrc){
    int e = blockIdx.x * blockDim.x + threadIdx.x;
    if (e < NEDGE) esrc[offsets[dst[e]] + erank[e]] = src[e];
}

// ---------------- GEMM1 + fused attention dots ----------------
// block owns 64-col panel cb == head cb; each wave does 32-row tiles -> 2 MFMA per ds_read.
__global__ __launch_bounds__(256) void gemm1(const unsigned short* __restrict__ xb,
                                             const unsigned short* __restrict__ w1t,
                                             const float* __restrict__ a_src,
                                             const float* __restrict__ a_dst,
                                             unsigned short* __restrict__ h1b,
                                             float* __restrict__ al_s,
                                             float* __restrict__ al_d){
    __shared__ unsigned short bs[BCOLS * KPAD];   // 33 KB
    int cb  = blockIdx.x & 7;          // col panel == head
    int rg  = blockIdx.x >> 3;
    int nrg = gridDim.x >> 3;
    {   // stage B panel once
        int kc = threadIdx.x & 31;
        int c0 = threadIdx.x >> 5;
#pragma unroll
        for (int it = 0; it < 8; it++){
            int col = it * 8 + c0;
            short8 v = *(const short8*)(w1t + (size_t)(cb * BCOLS + col) * F_INK + kc * 8);
            *(short8*)(&bs[col * KPAD + kc * 8]) = v;
        }
    }
    __syncthreads();
    int w    = threadIdx.x >> 6;
    int lane = threadIdx.x & 63;
    int lr = lane & 15, lk = lane >> 4;
    float a_s[4], a_d[4];
#pragma unroll
    for (int ct = 0; ct < 4; ct++){
        a_s[ct] = a_src[cb * HID + ct * 16 + lr];
        a_d[ct] = a_dst[cb * HID + ct * 16 + lr];
    }
    const int nchunk = (N_NODES + 127) / 128;     // 391
    for (int ch = rg; ch < nchunk; ch += nrg){
        int rb0 = ch * 128 + w * 32;              // tile0: rb0.., tile1: rb0+16..
        if (rb0 >= N_NODES) continue;
        bool t1 = (rb0 + 16 < N_NODES);           // 50000%16==0 -> tiles all-or-nothing
        short8 a0[8], a1[8];
#pragma unroll
        for (int ks = 0; ks < 8; ks++)
            a0[ks] = *(const short8*)(xb + (size_t)(rb0 + lr) * F_INK + ks * 32 + lk * 8);
        if (t1){
#pragma unroll
            for (int ks = 0; ks < 8; ks++)
                a1[ks] = *(const short8*)(xb + (size_t)(rb0 + 16 + lr) * F_INK + ks * 32 + lk * 8);
        }
        float ds0[4] = {0.f,0.f,0.f,0.f}, dd0[4] = {0.f,0.f,0.f,0.f};
        float ds1[4] = {0.f,0.f,0.f,0.f}, dd1[4] = {0.f,0.f,0.f,0.f};
#pragma unroll
        for (int ct = 0; ct < 4; ct++){
            float4v acc0 = {0.f, 0.f, 0.f, 0.f};
            float4v acc1 = {0.f, 0.f, 0.f, 0.f};
#pragma unroll
            for (int ks = 0; ks < 8; ks++){
                short8 b = *(const short8*)(&bs[(ct * 16 + lr) * KPAD + ks * 32 + lk * 8]);
                acc0 = __builtin_amdgcn_mfma_f32_16x16x32_bf16(a0[ks], b, acc0, 0, 0, 0);
                if (t1) acc1 = __builtin_amdgcn_mfma_f32_16x16x32_bf16(a1[ks], b, acc1, 0, 0, 0);
            }
#pragma unroll
            for (int r = 0; r < 4; r++){
                h1b[(size_t)(rb0 + lk * 4 + r) * HH + cb * BCOLS + ct * 16 + lr] = f2bf(acc0[r]);
                ds0[r] += acc0[r] * a_s[ct];
                dd0[r] += acc0[r] * a_d[ct];
            }
            if (t1){
#pragma unroll
                for (int r = 0; r < 4; r++){
                    h1b[(size_t)(rb0 + 16 + lk * 4 + r) * HH + cb * BCOLS + ct * 16 + lr] = f2bf(acc1[r]);
                    ds1[r] += acc1[r] * a_s[ct];
                    dd1[r] += acc1[r] * a_d[ct];
                }
            }
        }
#pragma unroll
        for (int r = 0; r < 4; r++){
#pragma unroll
            for (int o = 1; o < 16; o <<= 1){
                ds0[r] += __shfl_xor(ds0[r], o);
                dd0[r] += __shfl_xor(dd0[r], o);
                ds1[r] += __shfl_xor(ds1[r], o);
                dd1[r] += __shfl_xor(dd1[r], o);
            }
        }
        if (lr == 0){
#pragma unroll
            for (int r = 0; r < 4; r++){
                al_s[(rb0 + lk * 4 + r) * HEADS + cb] = ds0[r];
                al_d[(rb0 + lk * 4 + r) * HEADS + cb] = dd0[r];
            }
            if (t1){
#pragma unroll
                for (int r = 0; r < 4; r++){
                    al_s[(rb0 + 16 + lk * 4 + r) * HEADS + cb] = ds1[r];
                    al_d[(rb0 + 16 + lk * 4 + r) * HEADS + cb] = dd1[r];
                }
            }
        }
    }
}

// ---------------- layer-1 softmax: raw weights ew, wselfr, dinv ----------------
__global__ __launch_bounds__(256) void softmax1(
        const float* __restrict__ al_s, const float* __restrict__ al_d,
        const int* __restrict__ offsets, const int* __restrict__ esrc,
        float* __restrict__ ew, float* __restrict__ wselfr, float* __restrict__ dinv){
    int d = blockIdx.x * 4 + (threadIdx.x >> 6);
    int lane = threadIdx.x & 63;
    if (d >= N_NODES) return;
    int h = lane & 7, i = lane >> 3;
    int off = offsets[d], deg = offsets[d + 1] - off;
    float ald = al_d[d * HEADS + h];
    float aself = lrelu(al_s[d * HEADS + h] + ald);
    float m = aself;
    for (int base = 0; base < deg; base += 8){
        int e = base + i;
        float a = -1e30f;
        if (e < deg) a = lrelu(al_s[esrc[off + e] * HEADS + h] + ald);
        a = fmaxf(a, __shfl_xor(a, 8));
        a = fmaxf(a, __shfl_xor(a, 16));
        a = fmaxf(a, __shfl_xor(a, 32));
        m = fmaxf(m, a);
    }
    float denom = __expf(aself - m);
    for (int base = 0; base < deg; base += 8){
        int e = base + i;
        float w = 0.f;
        if (e < deg){
            w = __expf(lrelu(al_s[esrc[off + e] * HEADS + h] + ald) - m);
            ew[(size_t)(off + e) * HEADS + h] = w;    // unnormalized
        }
        float ws = w;
        ws += __shfl_xor(ws, 8);
        ws += __shfl_xor(ws, 16);
        ws += __shfl_xor(ws, 32);
        denom += ws;
    }
    if (i == 0){
        wselfr[d * HEADS + h] = __expf(aself - m);
        dinv[d * HEADS + h]   = 1.f / denom;
    }
}

// ---------------- layer-1 aggregation: one wave per dst, no LDS ----------------
__global__ __launch_bounds__(256) void agg1(const unsigned short* __restrict__ h1b,
        const float* __restrict__ ew, const float* __restrict__ wselfr,
        const float* __restrict__ dinv,
        const int* __restrict__ offsets, const int* __restrict__ esrc,
        const float* __restrict__ b1, unsigned short* __restrict__ x2b){
    int d = blockIdx.x * 4 + (threadIdx.x >> 6);
    if (d >= N_NODES) return;
    int lane = threadIdx.x & 63;
    int g = lane >> 3;
    int cb = g * HID + (lane & 7) * 8;     // lane's column offset (loop-invariant)
    int off = offsets[d], deg = offsets[d + 1] - off;
    float acc[8];
    {   // self edge
        float w0 = wselfr[d * HEADS + g];
        short8 v = *(const short8*)(h1b + (size_t)d * HH + cb);
        unsigned int u[4]; __builtin_memcpy(u, &v, 16);
#pragma unroll
        for (int j = 0; j < 4; j++){
            acc[2*j]   = w0 * __uint_as_float(u[j] << 16);
            acc[2*j+1] = w0 * __uint_as_float(u[j] & 0xffff0000u);
        }
    }
    int e = 0;
    for (; e + 4 <= deg; e += 4){
        int s0 = __builtin_amdgcn_readfirstlane(esrc[off + e]);
        int s1 = __builtin_amdgcn_readfirstlane(esrc[off + e + 1]);
        int s2 = __builtin_amdgcn_readfirstlane(esrc[off + e + 2]);
        int s3 = __builtin_amdgcn_readfirstlane(esrc[off + e + 3]);
        float w0 = ew[(size_t)(off + e)     * HEADS + g];
        float w1 = ew[(size_t)(off + e + 1) * HEADS + g];
        float w2 = ew[(size_t)(off + e + 2) * HEADS + g];
        float w3 = ew[(size_t)(off + e + 3) * HEADS + g];
        short8 v0 = *(const short8*)(h1b + (size_t)s0 * HH + cb);
        short8 v1 = *(const short8*)(h1b + (size_t)s1 * HH + cb);
        short8 v2 = *(const short8*)(h1b + (size_t)s2 * HH + cb);
        short8 v3 = *(const short8*)(h1b + (size_t)s3 * HH + cb);
        fma8(acc, w0, v0); fma8(acc, w1, v1);
        fma8(acc, w2, v2); fma8(acc, w3, v3);
    }
    for (; e < deg; e++){
        int s0 = __builtin_amdgcn_readfirstlane(esrc[off + e]);
        float w0 = ew[(size_t)(off + e) * HEADS + g];
        short8 v0 = *(const short8*)(h1b + (size_t)s0 * HH + cb);
        fma8(acc, w0, v0);
    }
    float di = dinv[d * HEADS + g];
    unsigned short o8[8];
#pragma unroll
    for (int j = 0; j < 8; j++){
        float v = acc[j] * di + b1[cb + j];
        v = v > 0.f ? v : __expf(v) - 1.f;   // elu
        o8[j] = f2bf(v);
    }
    short8 ov; __builtin_memcpy(&ov, o8, 16);
    *(short8*)(x2b + (size_t)d * HH + cb) = ov;
}

// ---------------- layer-2 GEMM via MFMA: h2 = x2b @ W2 (+ fused attention dots) --------
__global__ __launch_bounds__(256) void gemm2(const unsigned short* __restrict__ x2b,
        const unsigned short* __restrict__ w2t,
        const float* __restrict__ a_s2, const float* __restrict__ a_d2,
        float* __restrict__ h2, float* __restrict__ al2s, float* __restrict__ al2d){
    int wave = (blockIdx.x * blockDim.x + threadIdx.x) >> 6;
    int lane = threadIdx.x & 63;
    if (wave >= N_NODES / 16) return;
    int rowbase = wave * 16;
    int lr = lane & 15, lk = lane >> 4;
    float4v acc = {0.f, 0.f, 0.f, 0.f};
#pragma unroll
    for (int ks = 0; ks < 16; ks++){
        short8 a = *(const short8*)(x2b + (size_t)(rowbase + lr) * HH + ks * 32 + lk * 8);
        short8 b = *(const short8*)(w2t + (size_t)lr * HH + ks * 32 + lk * 8);
        acc = __builtin_amdgcn_mfma_f32_16x16x32_bf16(a, b, acc, 0, 0, 0);
    }
#pragma unroll
    for (int r = 0; r < 4; r++)
        h2[(size_t)(rowbase + lk * 4 + r) * NCLS + lr] = acc[r];
    float s_a = a_s2[lr], d_a = a_d2[lr];
#pragma unroll
    for (int r = 0; r < 4; r++){
        float ps = acc[r] * s_a, pd = acc[r] * d_a;
#pragma unroll
        for (int off = 1; off < 16; off <<= 1){
            ps += __shfl_xor(ps, off);
            pd += __shfl_xor(pd, off);
        }
        if (lr == 0){
            al2s[rowbase + lk * 4 + r] = ps;
            al2d[rowbase + lk * 4 + r] = pd;
        }
    }
}

// ---------------- layer-2 softmax weights ----------------
__global__ __launch_bounds__(256) void softmax2(
        const float* __restrict__ al2s, const float* __restrict__ al2d,
        const int* __restrict__ offsets, const int* __restrict__ esrc,
        float* __restrict__ ew2, float* __restrict__ wself2){
    int d = blockIdx.x * 4 + (threadIdx.x >> 6);
    int lane = threadIdx.x & 63;
    if (d >= N_NODES) return;
    int off = offsets[d], deg = offsets[d + 1] - off;
    float ald = al2d[d];
    float aself = lrelu(al2s[d] + ald);
    float m = aself;
    for (int base = 0; base < deg; base += 64){
        int e = base + lane;
        float a = (e < deg) ? lrelu(al2s[esrc[off + e]] + ald) : -1e30f;
#pragma unroll
        for (int o = 1; o < 64; o <<= 1) a = fmaxf(a, __shfl_xor(a, o));
        m = fmaxf(m, a);
    }
    float denom = __expf(aself - m);
    for (int base = 0; base < deg; base += 64){
        int e = base + lane;
        float w = 0.f;
        if (e < deg){
            w = __expf(lrelu(al2s[esrc[off + e]] + ald) - m);
            ew2[off + e] = w;
        }
#pragma unroll
        for (int o = 1; o < 64; o <<= 1) w += __shfl_xor(w, o);
        denom += w;
    }
    float inv = 1.f / denom;
    if (lane == 0) wself2[d] = __expf(aself - m) * inv;
    for (int base = 0; base < deg; base += 64){
        int e = base + lane;
        if (e < deg) ew2[off + e] *= inv;
    }
}

// ---------------- layer-2 aggregation -> out [N][16] fp32 ----------------
__global__ __launch_bounds__(256) void agg2(const float* __restrict__ h2,
        const float* __restrict__ ew2, const float* __restrict__ wself2,
        const int* __restrict__ offsets, const int* __restrict__ esrc,
        const float* __restrict__ b2, float* __restrict__ out){
    int d = blockIdx.x * 4 + (threadIdx.x >> 6);
    int lane = threadIdx.x & 63;
    if (d >= N_NODES) return;
    int off = offsets[d], deg = offsets[d + 1] - off;
    int sg = lane >> 4, col = lane & 15;
    float acc = (sg == 0) ? wself2[d] * h2[(size_t)d * NCLS + col] : 0.f;
    for (int i = sg; i < deg; i += 4){
        int s = esrc[off + i];
        acc += ew2[off + i] * h2[(size_t)s * NCLS + col];
    }
    acc += __shfl_xor(acc, 16);
    acc += __shfl_xor(acc, 32);
    if (lane < NCLS) out[(size_t)d * NCLS + lane] = acc + b2[lane];
}

extern "C" void kernel_launch(void* const* d_in, const int* in_sizes, int n_in,
                              void* d_out, int out_size, void* d_ws, size_t ws_size,
                              hipStream_t stream){
    const float* x   = (const float*)d_in[0];
    const int*   ei  = (const int*)d_in[1];
    const int*   src = ei;
    const int*   dst = ei + NEDGE;
    const float* W1  = (const float*)d_in[2];
    const float* as1 = (const float*)d_in[3];
    const float* ad1 = (const float*)d_in[4];
    const float* b1  = (const float*)d_in[5];
    const float* W2  = (const float*)d_in[6];
    const float* as2 = (const float*)d_in[7];
    const float* ad2 = (const float*)d_in[8];
    const float* b2  = (const float*)d_in[9];
    float* out = (float*)d_out;

    char* p = (char*)d_ws;
    auto carve = [&](size_t bytes) -> char* {
        char* r = p; p += (bytes + 255) & ~(size_t)255; return r;
    };
    unsigned short* xb   = (unsigned short*)carve((size_t)N_NODES * F_INK * 2);
    unsigned short* w1t  = (unsigned short*)carve((size_t)HH * F_INK * 2);
    unsigned short* w2t  = (unsigned short*)carve((size_t)HH * NCLS * 2);
    unsigned short* h1b  = (unsigned short*)carve((size_t)N_NODES * HH * 2);
    float* al1s  = (float*)carve((size_t)N_NODES * HEADS * 4);
    float* al1d  = (float*)carve((size_t)N_NODES * HEADS * 4);
    int* counts  = (int*)carve((size_t)N_NODES * 4);
    int* erank   = (int*)carve((size_t)NEDGE * 4);
    int* offsets = (int*)carve((size_t)(N_NODES + 1) * 4);
    int* blocksums = (int*)carve((size_t)NBLK_SCAN * 4);
    int* blockbase = (int*)carve((size_t)NBLK_SCAN * 4);
    int* esrc    = (int*)carve((size_t)NEDGE * 4);
    float* ew    = (float*)carve((size_t)NEDGE * HEADS * 4);
    float* wselfr= (float*)carve((size_t)N_NODES * HEADS * 4);
    float* dinv  = (float*)carve((size_t)N_NODES * HEADS * 4);
    unsigned short* x2b = (unsigned short*)carve((size_t)N_NODES * HH * 2);
    float* h2    = (float*)carve((size_t)N_NODES * NCLS * 4);
    float* al2s  = (float*)carve((size_t)N_NODES * 4);
    float* al2d  = (float*)carve((size_t)N_NODES * 4);
    float* ew2   = (float*)carve((size_t)NEDGE * 4);
    float* wself2= (float*)carve((size_t)N_NODES * 4);
    if ((size_t)(p - (char*)d_ws) > ws_size) return;  // workspace too small

    hipMemsetAsync(counts, 0, N_NODES * 4, stream);

    cvt_f32_bf16<<<2048, 256, 0, stream>>>(x, xb, N_NODES * F_INK / 4);
    cvt_weights<<<(F_INK * HH + HH * NCLS + 255) / 256, 256, 0, stream>>>(W1, w1t, W2, w2t);
    count_edges<<<(NEDGE + 255) / 256, 256, 0, stream>>>(dst, counts, erank);
    scan_part<<<NBLK_SCAN, 256, 0, stream>>>(counts, blocksums);
    scan_top<<<1, 256, 0, stream>>>(blocksums, blockbase, offsets);
    scan_write<<<NBLK_SCAN, 256, 0, stream>>>(counts, blockbase, offsets);
    scatter_edges<<<(NEDGE + 255) / 256, 256, 0, stream>>>(src, dst, offsets, erank, esrc);
    gemm1<<<8 * 128, 256, 0, stream>>>(xb, w1t, as1, ad1, h1b, al1s, al1d);
    softmax1<<<(N_NODES + 3) / 4, 256, 0, stream>>>(al1s, al1d, offsets, esrc, ew, wselfr, dinv);
    agg1<<<(N_NODES + 3) / 4, 256, 0, stream>>>(h1b, ew, wselfr, dinv, offsets, esrc, b1, x2b);
    gemm2<<<(N_NODES / 16 + 3) / 4, 256, 0, stream>>>(x2b, w2t, as2, ad2, h2, al2s, al2d);
    softmax2<<<(N_NODES + 3) / 4, 256, 0, stream>>>(al2s, al2d, offsets, esrc, ew2, wself2);
    agg2<<<(N_NODES + 3) / 4, 256, 0, stream>>>(h2, ew2, wself2, offsets, esrc, b2, out);
}

// Round 12
// 250.097 us; speedup vs baseline: 1.1983x; 1.0313x over previous
//
#include <hip/hip_runtime.h>
#include <hip/hip_bf16.h>
#include <math.h>

#define N_NODES 50000
#define F_INK   256
#define HEADS   8
#define HID     64
#define HH      512     // HEADS*HID
#define NCLS    16
#define NEDGE   400000
#define NEG_SLOPE 0.2f

#define BCOLS 64
#define KPAD  264       // 256 + 8 bf16 pad -> optimal quad-bank spread
#define NBLK_SCAN ((N_NODES + 255) / 256)   // 196

typedef __attribute__((ext_vector_type(8))) short short8;
typedef __attribute__((ext_vector_type(4))) short sh4;
typedef __attribute__((ext_vector_type(4))) float float4v;

__device__ __forceinline__ float bf2f(unsigned short u){
    unsigned int x = ((unsigned int)u) << 16;
    float f; __builtin_memcpy(&f, &x, 4); return f;
}
__device__ __forceinline__ unsigned short f2bf(float f){
    unsigned int x; __builtin_memcpy(&x, &f, 4);
    unsigned int r = x + 0x7FFFu + ((x >> 16) & 1u);   // RNE
    return (unsigned short)(r >> 16);
}
__device__ __forceinline__ float lrelu(float a){ return a > 0.f ? a : NEG_SLOPE * a; }

// dword-level bf16x2 unpack + fma: 1 VALU unpack + 1 fma per element
__device__ __forceinline__ void fma8(float* acc, float w, short8 v){
    unsigned int u[4]; __builtin_memcpy(u, &v, 16);
#pragma unroll
    for (int j = 0; j < 4; j++){
        acc[2*j]   += w * __uint_as_float(u[j] << 16);
        acc[2*j+1] += w * __uint_as_float(u[j] & 0xffff0000u);
    }
}

// ---------------- conversions ----------------
__global__ void cvt_f32_bf16(const float* __restrict__ in, unsigned short* __restrict__ out, int n4){
    int i = blockIdx.x * blockDim.x + threadIdx.x;
    int stride = gridDim.x * blockDim.x;
    for (; i < n4; i += stride){
        float4v f = *(const float4v*)(in + (size_t)i * 4);
        sh4 o;
#pragma unroll
        for (int j = 0; j < 4; j++) o[j] = (short)f2bf(f[j]);
        *(sh4*)(out + (size_t)i * 4) = o;
    }
}

// W1 [256][512] -> W1T [512][256] bf16  AND  W2 [512][16] -> W2T [16][512] bf16
__global__ void cvt_weights(const float* __restrict__ W1, unsigned short* __restrict__ W1T,
                            const float* __restrict__ W2, unsigned short* __restrict__ W2T){
    int i = blockIdx.x * blockDim.x + threadIdx.x;
    if (i < F_INK * HH){
        int k = i / HH, c = i % HH;
        W1T[c * F_INK + k] = f2bf(W1[i]);
    }
    int j = i - F_INK * HH;
    if (j >= 0 && j < HH * NCLS){
        int k = j / NCLS, c = j % NCLS;
        W2T[c * HH + k] = f2bf(W2[j]);
    }
}

// ---------------- CSR build ----------------
__global__ void count_edges(const int* __restrict__ dst, int* __restrict__ counts,
                            int* __restrict__ erank){
    int e = blockIdx.x * blockDim.x + threadIdx.x;
    if (e < NEDGE) erank[e] = atomicAdd(&counts[dst[e]], 1);
}

__global__ __launch_bounds__(256) void scan_part(const int* __restrict__ counts,
                                                 int* __restrict__ blocksums){
    __shared__ int red[256];
    int i = blockIdx.x * 256 + threadIdx.x;
    int v = (i < N_NODES) ? counts[i] : 0;
    red[threadIdx.x] = v; __syncthreads();
    for (int off = 128; off > 0; off >>= 1){
        if (threadIdx.x < off) red[threadIdx.x] += red[threadIdx.x + off];
        __syncthreads();
    }
    if (threadIdx.x == 0) blocksums[blockIdx.x] = red[0];
}

__global__ __launch_bounds__(256) void scan_top(const int* __restrict__ blocksums,
                                                int* __restrict__ blockbase,
                                                int* __restrict__ offsets){
    __shared__ int s[256];
    int t = threadIdx.x;
    int v = (t < NBLK_SCAN) ? blocksums[t] : 0;
    s[t] = v; __syncthreads();
    int val = v;
    for (int off = 1; off < 256; off <<= 1){
        int o2 = (t >= off) ? s[t - off] : 0;
        __syncthreads();
        val += o2; s[t] = val;
        __syncthreads();
    }
    if (t < NBLK_SCAN) blockbase[t] = val - v;   // exclusive
    if (t == 255) offsets[N_NODES] = s[255];     // grand total
}

__global__ __launch_bounds__(256) void scan_write(const int* __restrict__ counts,
                                                  const int* __restrict__ blockbase,
                                                  int* __restrict__ offsets){
    __shared__ int s[256];
    int i = blockIdx.x * 256 + threadIdx.x;
    int t = threadIdx.x;
    int v = (i < N_NODES) ? counts[i] : 0;
    s[t] = v; __syncthreads();
    int val = v;
    for (int off = 1; off < 256; off <<= 1){
        int o2 = (t >= off) ? s[t - off] : 0;
        __syncthreads();
        val += o2; s[t] = val;
        __syncthreads();
    }
    if (i < N_NODES) offsets[i] = blockbase[blockIdx.x] + val - v;
}

__global__ void scatter_edges(const int* __restrict__ src, const int* __restrict__ dst,
                              const int* __restrict__ offsets, const int* __restrict__ erank,
                              int* __restrict__ esrc){
    int e = blockIdx.x * blockDim.x + threadIdx.x;
    if (e < NEDGE) esrc[offsets[dst[e]] + erank[e]] = src[e];
}

// ---------------- GEMM1 + fused attention dots ----------------
__global__ __launch_bounds__(256) void gemm1(const unsigned short* __restrict__ xb,
                                             const unsigned short* __restrict__ w1t,
                                             const float* __restrict__ a_src,
                                             const float* __restrict__ a_dst,
                                             unsigned short* __restrict__ h1b,
                                             float* __restrict__ al_s,
                                             float* __restrict__ al_d){
    __shared__ unsigned short bs[BCOLS * KPAD];   // 33 KB
    int cb  = blockIdx.x & 7;          // col panel == head
    int rg  = blockIdx.x >> 3;
    int nrg = gridDim.x >> 3;
    {   // stage B panel once
        int kc = threadIdx.x & 31;
        int c0 = threadIdx.x >> 5;
#pragma unroll
        for (int it = 0; it < 8; it++){
            int col = it * 8 + c0;
            short8 v = *(const short8*)(w1t + (size_t)(cb * BCOLS + col) * F_INK + kc * 8);
            *(short8*)(&bs[col * KPAD + kc * 8]) = v;
        }
    }
    __syncthreads();
    int w    = threadIdx.x >> 6;
    int lane = threadIdx.x & 63;
    int lr = lane & 15, lk = lane >> 4;
    float a_s[4], a_d[4];
#pragma unroll
    for (int ct = 0; ct < 4; ct++){
        a_s[ct] = a_src[cb * HID + ct * 16 + lr];
        a_d[ct] = a_dst[cb * HID + ct * 16 + lr];
    }
    const int nchunk = (N_NODES + 127) / 128;     // 391
    for (int ch = rg; ch < nchunk; ch += nrg){
        int rb0 = ch * 128 + w * 32;
        if (rb0 >= N_NODES) continue;
        bool t1 = (rb0 + 16 < N_NODES);
        short8 a0[8], a1[8];
#pragma unroll
        for (int ks = 0; ks < 8; ks++)
            a0[ks] = *(const short8*)(xb + (size_t)(rb0 + lr) * F_INK + ks * 32 + lk * 8);
        if (t1){
#pragma unroll
            for (int ks = 0; ks < 8; ks++)
                a1[ks] = *(const short8*)(xb + (size_t)(rb0 + 16 + lr) * F_INK + ks * 32 + lk * 8);
        }
        float ds0[4] = {0.f,0.f,0.f,0.f}, dd0[4] = {0.f,0.f,0.f,0.f};
        float ds1[4] = {0.f,0.f,0.f,0.f}, dd1[4] = {0.f,0.f,0.f,0.f};
#pragma unroll
        for (int ct = 0; ct < 4; ct++){
            float4v acc0 = {0.f, 0.f, 0.f, 0.f};
            float4v acc1 = {0.f, 0.f, 0.f, 0.f};
#pragma unroll
            for (int ks = 0; ks < 8; ks++){
                short8 b = *(const short8*)(&bs[(ct * 16 + lr) * KPAD + ks * 32 + lk * 8]);
                acc0 = __builtin_amdgcn_mfma_f32_16x16x32_bf16(a0[ks], b, acc0, 0, 0, 0);
                if (t1) acc1 = __builtin_amdgcn_mfma_f32_16x16x32_bf16(a1[ks], b, acc1, 0, 0, 0);
            }
#pragma unroll
            for (int r = 0; r < 4; r++){
                h1b[(size_t)(rb0 + lk * 4 + r) * HH + cb * BCOLS + ct * 16 + lr] = f2bf(acc0[r]);
                ds0[r] += acc0[r] * a_s[ct];
                dd0[r] += acc0[r] * a_d[ct];
            }
            if (t1){
#pragma unroll
                for (int r = 0; r < 4; r++){
                    h1b[(size_t)(rb0 + 16 + lk * 4 + r) * HH + cb * BCOLS + ct * 16 + lr] = f2bf(acc1[r]);
                    ds1[r] += acc1[r] * a_s[ct];
                    dd1[r] += acc1[r] * a_d[ct];
                }
            }
        }
#pragma unroll
        for (int r = 0; r < 4; r++){
#pragma unroll
            for (int o = 1; o < 16; o <<= 1){
                ds0[r] += __shfl_xor(ds0[r], o);
                dd0[r] += __shfl_xor(dd0[r], o);
                ds1[r] += __shfl_xor(ds1[r], o);
                dd1[r] += __shfl_xor(dd1[r], o);
            }
        }
        if (lr == 0){
#pragma unroll
            for (int r = 0; r < 4; r++){
                al_s[(rb0 + lk * 4 + r) * HEADS + cb] = ds0[r];
                al_d[(rb0 + lk * 4 + r) * HEADS + cb] = dd0[r];
            }
            if (t1){
#pragma unroll
                for (int r = 0; r < 4; r++){
                    al_s[(rb0 + 16 + lk * 4 + r) * HEADS + cb] = ds1[r];
                    al_d[(rb0 + 16 + lk * 4 + r) * HEADS + cb] = dd1[r];
                }
            }
        }
    }
}

// ---------------- layer-1 softmax: raw weights ew, wselfr, dinv ----------------
__global__ __launch_bounds__(256) void softmax1(
        const float* __restrict__ al_s, const float* __restrict__ al_d,
        const int* __restrict__ offsets, const int* __restrict__ esrc,
        float* __restrict__ ew, float* __restrict__ wselfr, float* __restrict__ dinv){
    int d = blockIdx.x * 4 + (threadIdx.x >> 6);
    int lane = threadIdx.x & 63;
    if (d >= N_NODES) return;
    int h = lane & 7, i = lane >> 3;
    int off = offsets[d], deg = offsets[d + 1] - off;
    float ald = al_d[d * HEADS + h];
    float aself = lrelu(al_s[d * HEADS + h] + ald);
    float m = aself;
    for (int base = 0; base < deg; base += 8){
        int e = base + i;
        float a = -1e30f;
        if (e < deg) a = lrelu(al_s[esrc[off + e] * HEADS + h] + ald);
        a = fmaxf(a, __shfl_xor(a, 8));
        a = fmaxf(a, __shfl_xor(a, 16));
        a = fmaxf(a, __shfl_xor(a, 32));
        m = fmaxf(m, a);
    }
    float denom = __expf(aself - m);
    for (int base = 0; base < deg; base += 8){
        int e = base + i;
        float w = 0.f;
        if (e < deg){
            w = __expf(lrelu(al_s[esrc[off + e] * HEADS + h] + ald) - m);
            ew[(size_t)(off + e) * HEADS + h] = w;    // unnormalized
        }
        float ws = w;
        ws += __shfl_xor(ws, 8);
        ws += __shfl_xor(ws, 16);
        ws += __shfl_xor(ws, 32);
        denom += ws;
    }
    if (i == 0){
        wselfr[d * HEADS + h] = __expf(aself - m);
        dinv[d * HEADS + h]   = 1.f / denom;
    }
}

// ---------------- layer-1 aggregation: one wave per dst, no LDS ----------------
__global__ __launch_bounds__(256) void agg1(const unsigned short* __restrict__ h1b,
        const float* __restrict__ ew, const float* __restrict__ wselfr,
        const float* __restrict__ dinv,
        const int* __restrict__ offsets, const int* __restrict__ esrc,
        const float* __restrict__ b1, unsigned short* __restrict__ x2b){
    int d = blockIdx.x * 4 + (threadIdx.x >> 6);
    if (d >= N_NODES) return;
    int lane = threadIdx.x & 63;
    int g = lane >> 3;
    int cb = g * HID + (lane & 7) * 8;     // lane's column offset (loop-invariant)
    int off = offsets[d], deg = offsets[d + 1] - off;
    float acc[8];
    {   // self edge
        float w0 = wselfr[d * HEADS + g];
        short8 v = *(const short8*)(h1b + (size_t)d * HH + cb);
        unsigned int u[4]; __builtin_memcpy(u, &v, 16);
#pragma unroll
        for (int j = 0; j < 4; j++){
            acc[2*j]   = w0 * __uint_as_float(u[j] << 16);
            acc[2*j+1] = w0 * __uint_as_float(u[j] & 0xffff0000u);
        }
    }
    int e = 0;
    for (; e + 4 <= deg; e += 4){
        int s0 = __builtin_amdgcn_readfirstlane(esrc[off + e]);
        int s1 = __builtin_amdgcn_readfirstlane(esrc[off + e + 1]);
        int s2 = __builtin_amdgcn_readfirstlane(esrc[off + e + 2]);
        int s3 = __builtin_amdgcn_readfirstlane(esrc[off + e + 3]);
        float w0 = ew[(size_t)(off + e)     * HEADS + g];
        float w1 = ew[(size_t)(off + e + 1) * HEADS + g];
        float w2 = ew[(size_t)(off + e + 2) * HEADS + g];
        float w3 = ew[(size_t)(off + e + 3) * HEADS + g];
        short8 v0 = *(const short8*)(h1b + (size_t)s0 * HH + cb);
        short8 v1 = *(const short8*)(h1b + (size_t)s1 * HH + cb);
        short8 v2 = *(const short8*)(h1b + (size_t)s2 * HH + cb);
        short8 v3 = *(const short8*)(h1b + (size_t)s3 * HH + cb);
        fma8(acc, w0, v0); fma8(acc, w1, v1);
        fma8(acc, w2, v2); fma8(acc, w3, v3);
    }
    for (; e < deg; e++){
        int s0 = __builtin_amdgcn_readfirstlane(esrc[off + e]);
        float w0 = ew[(size_t)(off + e) * HEADS + g];
        short8 v0 = *(const short8*)(h1b + (size_t)s0 * HH + cb);
        fma8(acc, w0, v0);
    }
    float di = dinv[d * HEADS + g];
    unsigned short o8[8];
#pragma unroll
    for (int j = 0; j < 8; j++){
        float v = acc[j] * di + b1[cb + j];
        v = v > 0.f ? v : __expf(v) - 1.f;   // elu
        o8[j] = f2bf(v);
    }
    short8 ov; __builtin_memcpy(&ov, o8, 16);
    *(short8*)(x2b + (size_t)d * HH + cb) = ov;
}

// ---------------- layer-2 GEMM via MFMA: h2 = x2b @ W2 (+ fused attention dots) --------
__global__ __launch_bounds__(256) void gemm2(const unsigned short* __restrict__ x2b,
        const unsigned short* __restrict__ w2t,
        const float* __restrict__ a_s2, const float* __restrict__ a_d2,
        float* __restrict__ h2, float* __restrict__ al2s, float* __restrict__ al2d){
    int wave = (blockIdx.x * blockDim.x + threadIdx.x) >> 6;
    int lane = threadIdx.x & 63;
    if (wave >= N_NODES / 16) return;
    int rowbase = wave * 16;
    int lr = lane & 15, lk = lane >> 4;
    float4v acc = {0.f, 0.f, 0.f, 0.f};
#pragma unroll
    for (int ks = 0; ks < 16; ks++){
        short8 a = *(const short8*)(x2b + (size_t)(rowbase + lr) * HH + ks * 32 + lk * 8);
        short8 b = *(const short8*)(w2t + (size_t)lr * HH + ks * 32 + lk * 8);
        acc = __builtin_amdgcn_mfma_f32_16x16x32_bf16(a, b, acc, 0, 0, 0);
    }
#pragma unroll
    for (int r = 0; r < 4; r++)
        h2[(size_t)(rowbase + lk * 4 + r) * NCLS + lr] = acc[r];
    float s_a = a_s2[lr], d_a = a_d2[lr];
#pragma unroll
    for (int r = 0; r < 4; r++){
        float ps = acc[r] * s_a, pd = acc[r] * d_a;
#pragma unroll
        for (int off = 1; off < 16; off <<= 1){
            ps += __shfl_xor(ps, off);
            pd += __shfl_xor(pd, off);
        }
        if (lr == 0){
            al2s[rowbase + lk * 4 + r] = ps;
            al2d[rowbase + lk * 4 + r] = pd;
        }
    }
}

// ---------------- layer-2: fused softmax + aggregation -> out [N][16] fp32 ----------------
// one wave per dst; 64-lane parallel max/denom passes, then 4x16 gather pass.
__global__ __launch_bounds__(256) void agg2(const float* __restrict__ h2,
        const float* __restrict__ al2s, const float* __restrict__ al2d,
        const int* __restrict__ offsets, const int* __restrict__ esrc,
        const float* __restrict__ b2, float* __restrict__ out){
    int d = blockIdx.x * 4 + (threadIdx.x >> 6);
    int lane = threadIdx.x & 63;
    if (d >= N_NODES) return;
    int off = offsets[d], deg = offsets[d + 1] - off;
    float ald = al2d[d];
    float a0 = lrelu(al2s[d] + ald);
    float m = a0;
    for (int base = 0; base < deg; base += 64){
        int e = base + lane;
        float a = (e < deg) ? lrelu(al2s[esrc[off + e]] + ald) : -1e30f;
#pragma unroll
        for (int o = 1; o < 64; o <<= 1) a = fmaxf(a, __shfl_xor(a, o));
        m = fmaxf(m, a);
    }
    float dsum = __expf(a0 - m);
    for (int base = 0; base < deg; base += 64){
        int e = base + lane;
        float w = (e < deg) ? __expf(lrelu(al2s[esrc[off + e]] + ald) - m) : 0.f;
#pragma unroll
        for (int o = 1; o < 64; o <<= 1) w += __shfl_xor(w, o);
        dsum += w;
    }
    int sg = lane >> 4, col = lane & 15;
    float acc = (sg == 0) ? __expf(a0 - m) * h2[(size_t)d * NCLS + col] : 0.f;
    for (int i = sg; i < deg; i += 4){
        int s = esrc[off + i];
        float w = __expf(lrelu(al2s[s] + ald) - m);
        acc += w * h2[(size_t)s * NCLS + col];
    }
    acc += __shfl_xor(acc, 16);
    acc += __shfl_xor(acc, 32);
    if (lane < NCLS) out[(size_t)d * NCLS + lane] = acc / dsum + b2[lane];
}

extern "C" void kernel_launch(void* const* d_in, const int* in_sizes, int n_in,
                              void* d_out, int out_size, void* d_ws, size_t ws_size,
                              hipStream_t stream){
    const float* x   = (const float*)d_in[0];
    const int*   ei  = (const int*)d_in[1];
    const int*   src = ei;
    const int*   dst = ei + NEDGE;
    const float* W1  = (const float*)d_in[2];
    const float* as1 = (const float*)d_in[3];
    const float* ad1 = (const float*)d_in[4];
    const float* b1  = (const float*)d_in[5];
    const float* W2  = (const float*)d_in[6];
    const float* as2 = (const float*)d_in[7];
    const float* ad2 = (const float*)d_in[8];
    const float* b2  = (const float*)d_in[9];
    float* out = (float*)d_out;

    char* p = (char*)d_ws;
    auto carve = [&](size_t bytes) -> char* {
        char* r = p; p += (bytes + 255) & ~(size_t)255; return r;
    };
    unsigned short* xb   = (unsigned short*)carve((size_t)N_NODES * F_INK * 2);
    unsigned short* w1t  = (unsigned short*)carve((size_t)HH * F_INK * 2);
    unsigned short* w2t  = (unsigned short*)carve((size_t)HH * NCLS * 2);
    unsigned short* h1b  = (unsigned short*)carve((size_t)N_NODES * HH * 2);
    float* al1s  = (float*)carve((size_t)N_NODES * HEADS * 4);
    float* al1d  = (float*)carve((size_t)N_NODES * HEADS * 4);
    int* counts  = (int*)carve((size_t)N_NODES * 4);
    int* erank   = (int*)carve((size_t)NEDGE * 4);
    int* offsets = (int*)carve((size_t)(N_NODES + 1) * 4);
    int* blocksums = (int*)carve((size_t)NBLK_SCAN * 4);
    int* blockbase = (int*)carve((size_t)NBLK_SCAN * 4);
    int* esrc    = (int*)carve((size_t)NEDGE * 4);
    float* ew    = (float*)carve((size_t)NEDGE * HEADS * 4);
    float* wselfr= (float*)carve((size_t)N_NODES * HEADS * 4);
    float* dinv  = (float*)carve((size_t)N_NODES * HEADS * 4);
    unsigned short* x2b = (unsigned short*)carve((size_t)N_NODES * HH * 2);
    float* h2    = (float*)carve((size_t)N_NODES * NCLS * 4);
    float* al2s  = (float*)carve((size_t)N_NODES * 4);
    float* al2d  = (float*)carve((size_t)N_NODES * 4);
    if ((size_t)(p - (char*)d_ws) > ws_size) return;  // workspace too small

    hipMemsetAsync(counts, 0, N_NODES * 4, stream);

    cvt_f32_bf16<<<2048, 256, 0, stream>>>(x, xb, N_NODES * F_INK / 4);
    cvt_weights<<<(F_INK * HH + HH * NCLS + 255) / 256, 256, 0, stream>>>(W1, w1t, W2, w2t);
    count_edges<<<(NEDGE + 255) / 256, 256, 0, stream>>>(dst, counts, erank);
    scan_part<<<NBLK_SCAN, 256, 0, stream>>>(counts, blocksums);
    scan_top<<<1, 256, 0, stream>>>(blocksums, blockbase, offsets);
    scan_write<<<NBLK_SCAN, 256, 0, stream>>>(counts, blockbase, offsets);
    scatter_edges<<<(NEDGE + 255) / 256, 256, 0, stream>>>(src, dst, offsets, erank, esrc);
    gemm1<<<8 * 128, 256, 0, stream>>>(xb, w1t, as1, ad1, h1b, al1s, al1d);
    softmax1<<<(N_NODES + 3) / 4, 256, 0, stream>>>(al1s, al1d, offsets, esrc, ew, wselfr, dinv);
    agg1<<<(N_NODES + 3) / 4, 256, 0, stream>>>(h1b, ew, wselfr, dinv, offsets, esrc, b1, x2b);
    gemm2<<<(N_NODES / 16 + 3) / 4, 256, 0, stream>>>(x2b, w2t, as2, ad2, h2, al2s, al2d);
    agg2<<<(N_NODES + 3) / 4, 256, 0, stream>>>(h2, al2s, al2d, offsets, esrc, b2, out);
}

// Round 13
// 234.822 us; speedup vs baseline: 1.2763x; 1.0651x over previous
//
#include <hip/hip_runtime.h>
#include <hip/hip_bf16.h>
#include <math.h>

#define N_NODES 50000
#define F_INK   256
#define HEADS   8
#define HID     64
#define HH      512     // HEADS*HID
#define NCLS    16
#define NEDGE   400000
#define NEG_SLOPE 0.2f

#define BCOLS 64
#define KPAD  264       // 256 + 8 bf16 pad
#define NBLK_SCAN ((N_NODES + 255) / 256)   // 196
// LDS x2 tile: 16 rows; row = 8 g-blocks of (64 bf16 data + 8 pad) + 8 row-pad = 584 shorts
#define X2ROW 584
#define X2GB  72

typedef __attribute__((ext_vector_type(8))) short short8;
typedef __attribute__((ext_vector_type(4))) short sh4;
typedef __attribute__((ext_vector_type(4))) float float4v;

__device__ __forceinline__ float bf2f(unsigned short u){
    unsigned int x = ((unsigned int)u) << 16;
    float f; __builtin_memcpy(&f, &x, 4); return f;
}
__device__ __forceinline__ unsigned short f2bf(float f){
    unsigned int x; __builtin_memcpy(&x, &f, 4);
    unsigned int r = x + 0x7FFFu + ((x >> 16) & 1u);   // RNE
    return (unsigned short)(r >> 16);
}
__device__ __forceinline__ float lrelu(float a){ return a > 0.f ? a : NEG_SLOPE * a; }

__device__ __forceinline__ void fma8(float* acc, float w, short8 v){
    unsigned int u[4]; __builtin_memcpy(u, &v, 16);
#pragma unroll
    for (int j = 0; j < 4; j++){
        acc[2*j]   += w * __uint_as_float(u[j] << 16);
        acc[2*j+1] += w * __uint_as_float(u[j] & 0xffff0000u);
    }
}

// ---------------- conversions ----------------
__global__ void cvt_f32_bf16(const float* __restrict__ in, unsigned short* __restrict__ out, int n4){
    int i = blockIdx.x * blockDim.x + threadIdx.x;
    int stride = gridDim.x * blockDim.x;
    for (; i < n4; i += stride){
        float4v f = *(const float4v*)(in + (size_t)i * 4);
        sh4 o;
#pragma unroll
        for (int j = 0; j < 4; j++) o[j] = (short)f2bf(f[j]);
        *(sh4*)(out + (size_t)i * 4) = o;
    }
}

__global__ void cvt_weights(const float* __restrict__ W1, unsigned short* __restrict__ W1T,
                            const float* __restrict__ W2, unsigned short* __restrict__ W2T){
    int i = blockIdx.x * blockDim.x + threadIdx.x;
    if (i < F_INK * HH){
        int k = i / HH, c = i % HH;
        W1T[c * F_INK + k] = f2bf(W1[i]);
    }
    int j = i - F_INK * HH;
    if (j >= 0 && j < HH * NCLS){
        int k = j / NCLS, c = j % NCLS;
        W2T[c * HH + k] = f2bf(W2[j]);
    }
}

// ---------------- CSR build ----------------
__global__ void count_edges(const int* __restrict__ dst, int* __restrict__ counts,
                            int* __restrict__ erank){
    int e = blockIdx.x * blockDim.x + threadIdx.x;
    if (e < NEDGE) erank[e] = atomicAdd(&counts[dst[e]], 1);
}

__global__ __launch_bounds__(256) void scan_part(const int* __restrict__ counts,
                                                 int* __restrict__ blocksums){
    __shared__ int red[256];
    int i = blockIdx.x * 256 + threadIdx.x;
    int v = (i < N_NODES) ? counts[i] : 0;
    red[threadIdx.x] = v; __syncthreads();
    for (int off = 128; off > 0; off >>= 1){
        if (threadIdx.x < off) red[threadIdx.x] += red[threadIdx.x + off];
        __syncthreads();
    }
    if (threadIdx.x == 0) blocksums[blockIdx.x] = red[0];
}

__global__ __launch_bounds__(256) void scan_top(const int* __restrict__ blocksums,
                                                int* __restrict__ blockbase,
                                                int* __restrict__ offsets){
    __shared__ int s[256];
    int t = threadIdx.x;
    int v = (t < NBLK_SCAN) ? blocksums[t] : 0;
    s[t] = v; __syncthreads();
    int val = v;
    for (int off = 1; off < 256; off <<= 1){
        int o2 = (t >= off) ? s[t - off] : 0;
        __syncthreads();
        val += o2; s[t] = val;
        __syncthreads();
    }
    if (t < NBLK_SCAN) blockbase[t] = val - v;   // exclusive
    if (t == 255) offsets[N_NODES] = s[255];     // grand total
}

__global__ __launch_bounds__(256) void scan_write(const int* __restrict__ counts,
                                                  const int* __restrict__ blockbase,
                                                  int* __restrict__ offsets){
    __shared__ int s[256];
    int i = blockIdx.x * 256 + threadIdx.x;
    int t = threadIdx.x;
    int v = (i < N_NODES) ? counts[i] : 0;
    s[t] = v; __syncthreads();
    int val = v;
    for (int off = 1; off < 256; off <<= 1){
        int o2 = (t >= off) ? s[t - off] : 0;
        __syncthreads();
        val += o2; s[t] = val;
        __syncthreads();
    }
    if (i < N_NODES) offsets[i] = blockbase[blockIdx.x] + val - v;
}

__global__ void scatter_edges(const int* __restrict__ src, const int* __restrict__ dst,
                              const int* __restrict__ offsets, const int* __restrict__ erank,
                              int* __restrict__ esrc){
    int e = blockIdx.x * blockDim.x + threadIdx.x;
    if (e < NEDGE) esrc[offsets[dst[e]] + erank[e]] = src[e];
}

// ---------------- GEMM1 + fused attention dots ----------------
__global__ __launch_bounds__(256) void gemm1(const unsigned short* __restrict__ xb,
                                             const unsigned short* __restrict__ w1t,
                                             const float* __restrict__ a_src,
                                             const float* __restrict__ a_dst,
                                             unsigned short* __restrict__ h1b,
                                             float* __restrict__ al_s,
                                             float* __restrict__ al_d){
    __shared__ unsigned short bs[BCOLS * KPAD];   // 33 KB
    int cb  = blockIdx.x & 7;          // col panel == head
    int rg  = blockIdx.x >> 3;
    int nrg = gridDim.x >> 3;
    {   // stage B panel once
        int kc = threadIdx.x & 31;
        int c0 = threadIdx.x >> 5;
#pragma unroll
        for (int it = 0; it < 8; it++){
            int col = it * 8 + c0;
            short8 v = *(const short8*)(w1t + (size_t)(cb * BCOLS + col) * F_INK + kc * 8);
            *(short8*)(&bs[col * KPAD + kc * 8]) = v;
        }
    }
    __syncthreads();
    int w    = threadIdx.x >> 6;
    int lane = threadIdx.x & 63;
    int lr = lane & 15, lk = lane >> 4;
    float a_s[4], a_d[4];
#pragma unroll
    for (int ct = 0; ct < 4; ct++){
        a_s[ct] = a_src[cb * HID + ct * 16 + lr];
        a_d[ct] = a_dst[cb * HID + ct * 16 + lr];
    }
    const int nchunk = (N_NODES + 127) / 128;     // 391
    for (int ch = rg; ch < nchunk; ch += nrg){
        int rb0 = ch * 128 + w * 32;
        if (rb0 >= N_NODES) continue;
        bool t1 = (rb0 + 16 < N_NODES);
        short8 a0[8], a1[8];
#pragma unroll
        for (int ks = 0; ks < 8; ks++)
            a0[ks] = *(const short8*)(xb + (size_t)(rb0 + lr) * F_INK + ks * 32 + lk * 8);
        if (t1){
#pragma unroll
            for (int ks = 0; ks < 8; ks++)
                a1[ks] = *(const short8*)(xb + (size_t)(rb0 + 16 + lr) * F_INK + ks * 32 + lk * 8);
        }
        float ds0[4] = {0.f,0.f,0.f,0.f}, dd0[4] = {0.f,0.f,0.f,0.f};
        float ds1[4] = {0.f,0.f,0.f,0.f}, dd1[4] = {0.f,0.f,0.f,0.f};
#pragma unroll
        for (int ct = 0; ct < 4; ct++){
            float4v acc0 = {0.f, 0.f, 0.f, 0.f};
            float4v acc1 = {0.f, 0.f, 0.f, 0.f};
#pragma unroll
            for (int ks = 0; ks < 8; ks++){
                short8 b = *(const short8*)(&bs[(ct * 16 + lr) * KPAD + ks * 32 + lk * 8]);
                acc0 = __builtin_amdgcn_mfma_f32_16x16x32_bf16(a0[ks], b, acc0, 0, 0, 0);
                if (t1) acc1 = __builtin_amdgcn_mfma_f32_16x16x32_bf16(a1[ks], b, acc1, 0, 0, 0);
            }
#pragma unroll
            for (int r = 0; r < 4; r++){
                h1b[(size_t)(rb0 + lk * 4 + r) * HH + cb * BCOLS + ct * 16 + lr] = f2bf(acc0[r]);
                ds0[r] += acc0[r] * a_s[ct];
                dd0[r] += acc0[r] * a_d[ct];
            }
            if (t1){
#pragma unroll
                for (int r = 0; r < 4; r++){
                    h1b[(size_t)(rb0 + 16 + lk * 4 + r) * HH + cb * BCOLS + ct * 16 + lr] = f2bf(acc1[r]);
                    ds1[r] += acc1[r] * a_s[ct];
                    dd1[r] += acc1[r] * a_d[ct];
                }
            }
        }
#pragma unroll
        for (int r = 0; r < 4; r++){
#pragma unroll
            for (int o = 1; o < 16; o <<= 1){
                ds0[r] += __shfl_xor(ds0[r], o);
                dd0[r] += __shfl_xor(dd0[r], o);
                ds1[r] += __shfl_xor(ds1[r], o);
                dd1[r] += __shfl_xor(dd1[r], o);
            }
        }
        if (lr == 0){
#pragma unroll
            for (int r = 0; r < 4; r++){
                al_s[(rb0 + lk * 4 + r) * HEADS + cb] = ds0[r];
                al_d[(rb0 + lk * 4 + r) * HEADS + cb] = dd0[r];
            }
            if (t1){
#pragma unroll
                for (int r = 0; r < 4; r++){
                    al_s[(rb0 + 16 + lk * 4 + r) * HEADS + cb] = ds1[r];
                    al_d[(rb0 + 16 + lk * 4 + r) * HEADS + cb] = dd1[r];
                }
            }
        }
    }
}

// ---------------- layer-1 softmax: raw weights ew, wselfr, dinv ----------------
__global__ __launch_bounds__(256) void softmax1(
        const float* __restrict__ al_s, const float* __restrict__ al_d,
        const int* __restrict__ offsets, const int* __restrict__ esrc,
        float* __restrict__ ew, float* __restrict__ wselfr, float* __restrict__ dinv){
    int d = blockIdx.x * 4 + (threadIdx.x >> 6);
    int lane = threadIdx.x & 63;
    if (d >= N_NODES) return;
    int h = lane & 7, i = lane >> 3;
    int off = offsets[d], deg = offsets[d + 1] - off;
    float ald = al_d[d * HEADS + h];
    float aself = lrelu(al_s[d * HEADS + h] + ald);
    float m = aself;
    for (int base = 0; base < deg; base += 8){
        int e = base + i;
        float a = -1e30f;
        if (e < deg) a = lrelu(al_s[esrc[off + e] * HEADS + h] + ald);
        a = fmaxf(a, __shfl_xor(a, 8));
        a = fmaxf(a, __shfl_xor(a, 16));
        a = fmaxf(a, __shfl_xor(a, 32));
        m = fmaxf(m, a);
    }
    float denom = __expf(aself - m);
    for (int base = 0; base < deg; base += 8){
        int e = base + i;
        float w = 0.f;
        if (e < deg){
            w = __expf(lrelu(al_s[esrc[off + e] * HEADS + h] + ald) - m);
            ew[(size_t)(off + e) * HEADS + h] = w;    // unnormalized
        }
        float ws = w;
        ws += __shfl_xor(ws, 8);
        ws += __shfl_xor(ws, 16);
        ws += __shfl_xor(ws, 32);
        denom += ws;
    }
    if (i == 0){
        wselfr[d * HEADS + h] = __expf(aself - m);
        dinv[d * HEADS + h]   = 1.f / denom;
    }
}

// ---------------- layer-1 aggregation + fused layer-2 GEMM ----------------
// block = 16 dsts (4 waves x 4 sequential dsts). Gathered x2 rows (post-ELU, bf16)
// staged in padded LDS; wave 0 runs the 16-row MFMA mini-gemm (h2 + al2 dots).
__global__ __launch_bounds__(256) void agg1f(const unsigned short* __restrict__ h1b,
        const float* __restrict__ ew, const float* __restrict__ wselfr,
        const float* __restrict__ dinv,
        const int* __restrict__ offsets, const int* __restrict__ esrc,
        const float* __restrict__ b1,
        const unsigned short* __restrict__ w2t,
        const float* __restrict__ a_s2, const float* __restrict__ a_d2,
        float* __restrict__ h2, float* __restrict__ al2s, float* __restrict__ al2d){
    __shared__ unsigned short x2l[16 * X2ROW];    // 18.7 KB
    int w = threadIdx.x >> 6;
    int lane = threadIdx.x & 63;
    int g = lane >> 3, i = lane & 7;
    int cb = g * HID + i * 8;
#pragma unroll
    for (int q = 0; q < 4; q++){
        int row = w * 4 + q;
        int d = blockIdx.x * 16 + row;
        int off = offsets[d], deg = offsets[d + 1] - off;
        float acc[8];
        {   // self edge
            float w0 = wselfr[d * HEADS + g];
            short8 v = *(const short8*)(h1b + (size_t)d * HH + cb);
            unsigned int u[4]; __builtin_memcpy(u, &v, 16);
#pragma unroll
            for (int j = 0; j < 4; j++){
                acc[2*j]   = w0 * __uint_as_float(u[j] << 16);
                acc[2*j+1] = w0 * __uint_as_float(u[j] & 0xffff0000u);
            }
        }
        int e = 0;
        for (; e + 4 <= deg; e += 4){
            int s0 = __builtin_amdgcn_readfirstlane(esrc[off + e]);
            int s1 = __builtin_amdgcn_readfirstlane(esrc[off + e + 1]);
            int s2 = __builtin_amdgcn_readfirstlane(esrc[off + e + 2]);
            int s3 = __builtin_amdgcn_readfirstlane(esrc[off + e + 3]);
            float w0 = ew[(size_t)(off + e)     * HEADS + g];
            float w1 = ew[(size_t)(off + e + 1) * HEADS + g];
            float w2 = ew[(size_t)(off + e + 2) * HEADS + g];
            float w3 = ew[(size_t)(off + e + 3) * HEADS + g];
            short8 v0 = *(const short8*)(h1b + (size_t)s0 * HH + cb);
            short8 v1 = *(const short8*)(h1b + (size_t)s1 * HH + cb);
            short8 v2 = *(const short8*)(h1b + (size_t)s2 * HH + cb);
            short8 v3 = *(const short8*)(h1b + (size_t)s3 * HH + cb);
            fma8(acc, w0, v0); fma8(acc, w1, v1);
            fma8(acc, w2, v2); fma8(acc, w3, v3);
        }
        for (; e < deg; e++){
            int s0 = __builtin_amdgcn_readfirstlane(esrc[off + e]);
            float w0 = ew[(size_t)(off + e) * HEADS + g];
            short8 v0 = *(const short8*)(h1b + (size_t)s0 * HH + cb);
            fma8(acc, w0, v0);
        }
        float di = dinv[d * HEADS + g];
        unsigned short o8[8];
#pragma unroll
        for (int j = 0; j < 8; j++){
            float v = acc[j] * di + b1[cb + j];
            v = v > 0.f ? v : __expf(v) - 1.f;   // elu
            o8[j] = f2bf(v);
        }
        short8 ov; __builtin_memcpy(&ov, o8, 16);
        *(short8*)(&x2l[row * X2ROW + g * X2GB + i * 8]) = ov;
    }
    __syncthreads();
    if (w == 0){
        int rowbase = blockIdx.x * 16;
        int lr = lane & 15, lk = lane >> 4;
        float4v accv = {0.f, 0.f, 0.f, 0.f};
#pragma unroll
        for (int ks = 0; ks < 16; ks++){
            int c0 = ks * 32 + lk * 8;
            int gg = c0 >> 6, wc = c0 & 63;
            short8 a = *(const short8*)(&x2l[lr * X2ROW + gg * X2GB + wc]);
            short8 b = *(const short8*)(w2t + (size_t)lr * HH + ks * 32 + lk * 8);
            accv = __builtin_amdgcn_mfma_f32_16x16x32_bf16(a, b, accv, 0, 0, 0);
        }
#pragma unroll
        for (int r = 0; r < 4; r++)
            h2[(size_t)(rowbase + lk * 4 + r) * NCLS + lr] = accv[r];
        float s_a = a_s2[lr], d_a = a_d2[lr];
#pragma unroll
        for (int r = 0; r < 4; r++){
            float ps = accv[r] * s_a, pd = accv[r] * d_a;
#pragma unroll
            for (int off = 1; off < 16; off <<= 1){
                ps += __shfl_xor(ps, off);
                pd += __shfl_xor(pd, off);
            }
            if (lr == 0){
                al2s[rowbase + lk * 4 + r] = ps;
                al2d[rowbase + lk * 4 + r] = pd;
            }
        }
    }
}

// ---------------- layer-2: fused softmax + aggregation -> out [N][16] fp32 ----------------
__global__ __launch_bounds__(256) void agg2(const float* __restrict__ h2,
        const float* __restrict__ al2s, const float* __restrict__ al2d,
        const int* __restrict__ offsets, const int* __restrict__ esrc,
        const float* __restrict__ b2, float* __restrict__ out){
    int d = blockIdx.x * 4 + (threadIdx.x >> 6);
    int lane = threadIdx.x & 63;
    if (d >= N_NODES) return;
    int off = offsets[d], deg = offsets[d + 1] - off;
    float ald = al2d[d];
    float a0 = lrelu(al2s[d] + ald);
    float m = a0;
    for (int base = 0; base < deg; base += 64){
        int e = base + lane;
        float a = (e < deg) ? lrelu(al2s[esrc[off + e]] + ald) : -1e30f;
#pragma unroll
        for (int o = 1; o < 64; o <<= 1) a = fmaxf(a, __shfl_xor(a, o));
        m = fmaxf(m, a);
    }
    float dsum = __expf(a0 - m);
    for (int base = 0; base < deg; base += 64){
        int e = base + lane;
        float w = (e < deg) ? __expf(lrelu(al2s[esrc[off + e]] + ald) - m) : 0.f;
#pragma unroll
        for (int o = 1; o < 64; o <<= 1) w += __shfl_xor(w, o);
        dsum += w;
    }
    int sg = lane >> 4, col = lane & 15;
    float acc = (sg == 0) ? __expf(a0 - m) * h2[(size_t)d * NCLS + col] : 0.f;
    for (int i = sg; i < deg; i += 4){
        int s = esrc[off + i];
        float w = __expf(lrelu(al2s[s] + ald) - m);
        acc += w * h2[(size_t)s * NCLS + col];
    }
    acc += __shfl_xor(acc, 16);
    acc += __shfl_xor(acc, 32);
    if (lane < NCLS) out[(size_t)d * NCLS + lane] = acc / dsum + b2[lane];
}

extern "C" void kernel_launch(void* const* d_in, const int* in_sizes, int n_in,
                              void* d_out, int out_size, void* d_ws, size_t ws_size,
                              hipStream_t stream){
    const float* x   = (const float*)d_in[0];
    const int*   ei  = (const int*)d_in[1];
    const int*   src = ei;
    const int*   dst = ei + NEDGE;
    const float* W1  = (const float*)d_in[2];
    const float* as1 = (const float*)d_in[3];
    const float* ad1 = (const float*)d_in[4];
    const float* b1  = (const float*)d_in[5];
    const float* W2  = (const float*)d_in[6];
    const float* as2 = (const float*)d_in[7];
    const float* ad2 = (const float*)d_in[8];
    const float* b2  = (const float*)d_in[9];
    float* out = (float*)d_out;

    char* p = (char*)d_ws;
    auto carve = [&](size_t bytes) -> char* {
        char* r = p; p += (bytes + 255) & ~(size_t)255; return r;
    };
    unsigned short* xb   = (unsigned short*)carve((size_t)N_NODES * F_INK * 2);
    unsigned short* w1t  = (unsigned short*)carve((size_t)HH * F_INK * 2);
    unsigned short* w2t  = (unsigned short*)carve((size_t)HH * NCLS * 2);
    unsigned short* h1b  = (unsigned short*)carve((size_t)N_NODES * HH * 2);
    float* al1s  = (float*)carve((size_t)N_NODES * HEADS * 4);
    float* al1d  = (float*)carve((size_t)N_NODES * HEADS * 4);
    int* counts  = (int*)carve((size_t)N_NODES * 4);
    int* erank   = (int*)carve((size_t)NEDGE * 4);
    int* offsets = (int*)carve((size_t)(N_NODES + 1) * 4);
    int* blocksums = (int*)carve((size_t)NBLK_SCAN * 4);
    int* blockbase = (int*)carve((size_t)NBLK_SCAN * 4);
    int* esrc    = (int*)carve((size_t)NEDGE * 4);
    float* ew    = (float*)carve((size_t)NEDGE * HEADS * 4);
    float* wselfr= (float*)carve((size_t)N_NODES * HEADS * 4);
    float* dinv  = (float*)carve((size_t)N_NODES * HEADS * 4);
    float* h2    = (float*)carve((size_t)N_NODES * NCLS * 4);
    float* al2s  = (float*)carve((size_t)N_NODES * 4);
    float* al2d  = (float*)carve((size_t)N_NODES * 4);
    if ((size_t)(p - (char*)d_ws) > ws_size) return;  // workspace too small

    hipMemsetAsync(counts, 0, N_NODES * 4, stream);

    cvt_f32_bf16<<<2048, 256, 0, stream>>>(x, xb, N_NODES * F_INK / 4);
    cvt_weights<<<(F_INK * HH + HH * NCLS + 255) / 256, 256, 0, stream>>>(W1, w1t, W2, w2t);
    count_edges<<<(NEDGE + 255) / 256, 256, 0, stream>>>(dst, counts, erank);
    scan_part<<<NBLK_SCAN, 256, 0, stream>>>(counts, blocksums);
    scan_top<<<1, 256, 0, stream>>>(blocksums, blockbase, offsets);
    scan_write<<<NBLK_SCAN, 256, 0, stream>>>(counts, blockbase, offsets);
    scatter_edges<<<(NEDGE + 255) / 256, 256, 0, stream>>>(src, dst, offsets, erank, esrc);
    gemm1<<<8 * 128, 256, 0, stream>>>(xb, w1t, as1, ad1, h1b, al1s, al1d);
    softmax1<<<(N_NODES + 3) / 4, 256, 0, stream>>>(al1s, al1d, offsets, esrc, ew, wselfr, dinv);
    agg1f<<<N_NODES / 16, 256, 0, stream>>>(h1b, ew, wselfr, dinv, offsets, esrc, b1,
                                            w2t, as2, ad2, h2, al2s, al2d);
    agg2<<<(N_NODES + 3) / 4, 256, 0, stream>>>(h2, al2s, al2d, offsets, esrc, b2, out);
}

// Round 16
// 221.639 us; speedup vs baseline: 1.3522x; 1.0595x over previous
//
#include <hip/hip_runtime.h>
#include <hip/hip_bf16.h>
#include <math.h>

#define N_NODES 50000
#define F_INK   256
#define HEADS   8
#define HID     64
#define HH      512     // HEADS*HID
#define NCLS    16
#define NEDGE   400000
#define NEG_SLOPE 0.2f

#define BCOLS 64
#define KPAD  264       // 256 + 8 bf16 pad (quad-bank spread); 64*264*2 = 33 KB
#define NBLK_SCAN ((N_NODES + 255) / 256)   // 196
// LDS x2 tile (agg1f): 16 rows; row = 8 g-blocks of (64 data + 8 pad) + 8 row-pad = 584 shorts
#define X2ROW 584
#define X2GB  72
// prep partition
#define PREP_X_BLKS 12500                   // 3,200,000 float4 items (N*F_IN/4), exact
#define PREP_W_BLKS 544                     // 131072 + 8192 = 139264 items, exact
// gemm1+scatter partition
#define G1_BLKS 1024                        // 8 panels * 128 row-groups
#define SCAT_BLKS ((NEDGE + 255) / 256)     // 1563

typedef __attribute__((ext_vector_type(8))) short short8;
typedef __attribute__((ext_vector_type(4))) short sh4;
typedef __attribute__((ext_vector_type(4))) float float4v;

__device__ __forceinline__ float bf2f(unsigned short u){
    unsigned int x = ((unsigned int)u) << 16;
    float f; __builtin_memcpy(&f, &x, 4); return f;
}
__device__ __forceinline__ unsigned short f2bf(float f){
    unsigned int x; __builtin_memcpy(&x, &f, 4);
    unsigned int r = x + 0x7FFFu + ((x >> 16) & 1u);   // RNE
    return (unsigned short)(r >> 16);
}
__device__ __forceinline__ float lrelu(float a){ return a > 0.f ? a : NEG_SLOPE * a; }

__device__ __forceinline__ void fma8(float* acc, float w, short8 v){
    unsigned int u[4]; __builtin_memcpy(u, &v, 16);
#pragma unroll
    for (int j = 0; j < 4; j++){
        acc[2*j]   += w * __uint_as_float(u[j] << 16);
        acc[2*j+1] += w * __uint_as_float(u[j] & 0xffff0000u);
    }
}

// ---------------- prep: cvt x -> bf16, cvt weights, count edges (one launch) ----------------
__global__ __launch_bounds__(256) void prep(const float* __restrict__ x, unsigned short* __restrict__ xb,
                                            const float* __restrict__ W1, unsigned short* __restrict__ W1T,
                                            const float* __restrict__ W2, unsigned short* __restrict__ W2T,
                                            const int* __restrict__ dst, int* __restrict__ counts,
                                            int* __restrict__ erank){
    int bid = blockIdx.x;
    if (bid < PREP_X_BLKS){
        int i = bid * 256 + threadIdx.x;        // exactly 3,200,000 items
        float4v f = *(const float4v*)(x + (size_t)i * 4);
        sh4 o;
#pragma unroll
        for (int j = 0; j < 4; j++) o[j] = (short)f2bf(f[j]);
        *(sh4*)(xb + (size_t)i * 4) = o;
    } else if (bid < PREP_X_BLKS + PREP_W_BLKS){
        int i = (bid - PREP_X_BLKS) * 256 + threadIdx.x;
        if (i < F_INK * HH){
            int k = i / HH, c = i % HH;
            W1T[c * F_INK + k] = f2bf(W1[i]);
        } else {
            int j = i - F_INK * HH;             // < 8192 by partition sizing
            int k = j / NCLS, c = j % NCLS;
            W2T[c * HH + k] = f2bf(W2[j]);
        }
    } else {
        int e = (bid - PREP_X_BLKS - PREP_W_BLKS) * 256 + threadIdx.x;
        if (e < NEDGE) erank[e] = atomicAdd(&counts[dst[e]], 1);
    }
}

// ---------------- CSR scan ----------------
__global__ __launch_bounds__(256) void scan_part(const int* __restrict__ counts,
                                                 int* __restrict__ blocksums){
    __shared__ int red[256];
    int i = blockIdx.x * 256 + threadIdx.x;
    int v = (i < N_NODES) ? counts[i] : 0;
    red[threadIdx.x] = v; __syncthreads();
    for (int off = 128; off > 0; off >>= 1){
        if (threadIdx.x < off) red[threadIdx.x] += red[threadIdx.x + off];
        __syncthreads();
    }
    if (threadIdx.x == 0) blocksums[blockIdx.x] = red[0];
}

__global__ __launch_bounds__(256) void scan_top(const int* __restrict__ blocksums,
                                                int* __restrict__ blockbase,
                                                int* __restrict__ offsets){
    __shared__ int s[256];
    int t = threadIdx.x;
    int v = (t < NBLK_SCAN) ? blocksums[t] : 0;
    s[t] = v; __syncthreads();
    int val = v;
    for (int off = 1; off < 256; off <<= 1){
        int o2 = (t >= off) ? s[t - off] : 0;
        __syncthreads();
        val += o2; s[t] = val;
        __syncthreads();
    }
    if (t < NBLK_SCAN) blockbase[t] = val - v;   // exclusive
    if (t == 255) offsets[N_NODES] = s[255];     // grand total
}

__global__ __launch_bounds__(256) void scan_write(const int* __restrict__ counts,
                                                  const int* __restrict__ blockbase,
                                                  int* __restrict__ offsets){
    __shared__ int s[256];
    int i = blockIdx.x * 256 + threadIdx.x;
    int t = threadIdx.x;
    int v = (i < N_NODES) ? counts[i] : 0;
    s[t] = v; __syncthreads();
    int val = v;
    for (int off = 1; off < 256; off <<= 1){
        int o2 = (t >= off) ? s[t - off] : 0;
        __syncthreads();
        val += o2; s[t] = val;
        __syncthreads();
    }
    if (i < N_NODES) offsets[i] = blockbase[blockIdx.x] + val - v;
}

// ---------------- GEMM1 (64-col panels, fused attn dots) + scatter (merged launch) --------
__global__ __launch_bounds__(256) void gemm1_scatter(
        const unsigned short* __restrict__ xb, const unsigned short* __restrict__ w1t,
        const float* __restrict__ a_src, const float* __restrict__ a_dst,
        unsigned short* __restrict__ h1b, float* __restrict__ al_s, float* __restrict__ al_d,
        const int* __restrict__ src, const int* __restrict__ dst,
        const int* __restrict__ offsets, const int* __restrict__ erank,
        int* __restrict__ esrc){
    __shared__ unsigned short bs[BCOLS * KPAD];   // 33 KB
    if (blockIdx.x >= G1_BLKS){
        int e = (blockIdx.x - G1_BLKS) * 256 + threadIdx.x;
        if (e < NEDGE) esrc[offsets[dst[e]] + erank[e]] = src[e];
        return;
    }
    int cb  = blockIdx.x & 7;          // col panel == head
    int rg  = blockIdx.x >> 3;         // 0..127
    const int nrg = G1_BLKS >> 3;      // 128
    {   // stage B panel once
        int kc = threadIdx.x & 31;
        int c0 = threadIdx.x >> 5;
#pragma unroll
        for (int it = 0; it < 8; it++){
            int col = it * 8 + c0;
            short8 v = *(const short8*)(w1t + (size_t)(cb * BCOLS + col) * F_INK + kc * 8);
            *(short8*)(&bs[col * KPAD + kc * 8]) = v;
        }
    }
    __syncthreads();
    int w    = threadIdx.x >> 6;
    int lane = threadIdx.x & 63;
    int lr = lane & 15, lk = lane >> 4;
    float a_s[4], a_d[4];
#pragma unroll
    for (int ct = 0; ct < 4; ct++){
        a_s[ct] = a_src[cb * HID + ct * 16 + lr];
        a_d[ct] = a_dst[cb * HID + ct * 16 + lr];
    }
    const int nchunk = (N_NODES + 127) / 128;     // 391
    for (int ch = rg; ch < nchunk; ch += nrg){
        int rb0 = ch * 128 + w * 32;
        if (rb0 >= N_NODES) continue;
        bool t1 = (rb0 + 16 < N_NODES);
        short8 a0[8], a1[8];
#pragma unroll
        for (int ks = 0; ks < 8; ks++)
            a0[ks] = *(const short8*)(xb + (size_t)(rb0 + lr) * F_INK + ks * 32 + lk * 8);
        if (t1){
#pragma unroll
            for (int ks = 0; ks < 8; ks++)
                a1[ks] = *(const short8*)(xb + (size_t)(rb0 + 16 + lr) * F_INK + ks * 32 + lk * 8);
        }
        float ds0[4] = {0.f,0.f,0.f,0.f}, dd0[4] = {0.f,0.f,0.f,0.f};
        float ds1[4] = {0.f,0.f,0.f,0.f}, dd1[4] = {0.f,0.f,0.f,0.f};
#pragma unroll
        for (int ct = 0; ct < 4; ct++){
            float4v acc0 = {0.f, 0.f, 0.f, 0.f};
            float4v acc1 = {0.f, 0.f, 0.f, 0.f};
#pragma unroll
            for (int ks = 0; ks < 8; ks++){
                short8 b = *(const short8*)(&bs[(ct * 16 + lr) * KPAD + ks * 32 + lk * 8]);
                acc0 = __builtin_amdgcn_mfma_f32_16x16x32_bf16(a0[ks], b, acc0, 0, 0, 0);
                if (t1) acc1 = __builtin_amdgcn_mfma_f32_16x16x32_bf16(a1[ks], b, acc1, 0, 0, 0);
            }
#pragma unroll
            for (int r = 0; r < 4; r++){
                h1b[(size_t)(rb0 + lk * 4 + r) * HH + cb * BCOLS + ct * 16 + lr] = f2bf(acc0[r]);
                ds0[r] += acc0[r] * a_s[ct];
                dd0[r] += acc0[r] * a_d[ct];
            }
            if (t1){
#pragma unroll
                for (int r = 0; r < 4; r++){
                    h1b[(size_t)(rb0 + 16 + lk * 4 + r) * HH + cb * BCOLS + ct * 16 + lr] = f2bf(acc1[r]);
                    ds1[r] += acc1[r] * a_s[ct];
                    dd1[r] += acc1[r] * a_d[ct];
                }
            }
        }
#pragma unroll
        for (int r = 0; r < 4; r++){
#pragma unroll
            for (int o = 1; o < 16; o <<= 1){
                ds0[r] += __shfl_xor(ds0[r], o);
                dd0[r] += __shfl_xor(dd0[r], o);
                ds1[r] += __shfl_xor(ds1[r], o);
                dd1[r] += __shfl_xor(dd1[r], o);
            }
        }
        if (lr == 0){
#pragma unroll
            for (int r = 0; r < 4; r++){
                al_s[(rb0 + lk * 4 + r) * HEADS + cb] = ds0[r];
                al_d[(rb0 + lk * 4 + r) * HEADS + cb] = dd0[r];
            }
            if (t1){
#pragma unroll
                for (int r = 0; r < 4; r++){
                    al_s[(rb0 + 16 + lk * 4 + r) * HEADS + cb] = ds1[r];
                    al_d[(rb0 + 16 + lk * 4 + r) * HEADS + cb] = dd1[r];
                }
            }
        }
    }
}

// ---------------- layer-1 softmax: raw weights ew, wselfr, dinv ----------------
__global__ __launch_bounds__(256) void softmax1(
        const float* __restrict__ al_s, const float* __restrict__ al_d,
        const int* __restrict__ offsets, const int* __restrict__ esrc,
        float* __restrict__ ew, float* __restrict__ wselfr, float* __restrict__ dinv){
    int d = blockIdx.x * 4 + (threadIdx.x >> 6);
    int lane = threadIdx.x & 63;
    if (d >= N_NODES) return;
    int h = lane & 7, i = lane >> 3;
    int off = offsets[d], deg = offsets[d + 1] - off;
    float ald = al_d[d * HEADS + h];
    float aself = lrelu(al_s[d * HEADS + h] + ald);
    float m = aself;
    for (int base = 0; base < deg; base += 8){
        int e = base + i;
        float a = -1e30f;
        if (e < deg) a = lrelu(al_s[esrc[off + e] * HEADS + h] + ald);
        a = fmaxf(a, __shfl_xor(a, 8));
        a = fmaxf(a, __shfl_xor(a, 16));
        a = fmaxf(a, __shfl_xor(a, 32));
        m = fmaxf(m, a);
    }
    float denom = __expf(aself - m);
    for (int base = 0; base < deg; base += 8){
        int e = base + i;
        float w = 0.f;
        if (e < deg){
            w = __expf(lrelu(al_s[esrc[off + e] * HEADS + h] + ald) - m);
            ew[(size_t)(off + e) * HEADS + h] = w;    // unnormalized
        }
        float ws = w;
        ws += __shfl_xor(ws, 8);
        ws += __shfl_xor(ws, 16);
        ws += __shfl_xor(ws, 32);
        denom += ws;
    }
    if (i == 0){
        wselfr[d * HEADS + h] = __expf(aself - m);
        dinv[d * HEADS + h]   = 1.f / denom;
    }
}

// ---------------- layer-1 aggregation + fused layer-2 GEMM ----------------
__global__ __launch_bounds__(256) void agg1f(const unsigned short* __restrict__ h1b,
        const float* __restrict__ ew, const float* __restrict__ wselfr,
        const float* __restrict__ dinv,
        const int* __restrict__ offsets, const int* __restrict__ esrc,
        const float* __restrict__ b1,
        const unsigned short* __restrict__ w2t,
        const float* __restrict__ a_s2, const float* __restrict__ a_d2,
        float* __restrict__ h2, float* __restrict__ al2s, float* __restrict__ al2d){
    __shared__ unsigned short x2l[16 * X2ROW];    // 18.7 KB
    int w = threadIdx.x >> 6;
    int lane = threadIdx.x & 63;
    int g = lane >> 3, i = lane & 7;
    int cb = g * HID + i * 8;
#pragma unroll
    for (int q = 0; q < 4; q++){
        int row = w * 4 + q;
        int d = blockIdx.x * 16 + row;
        int off = offsets[d], deg = offsets[d + 1] - off;
        float acc[8];
        {   // self edge
            float w0 = wselfr[d * HEADS + g];
            short8 v = *(const short8*)(h1b + (size_t)d * HH + cb);
            unsigned int u[4]; __builtin_memcpy(u, &v, 16);
#pragma unroll
            for (int j = 0; j < 4; j++){
                acc[2*j]   = w0 * __uint_as_float(u[j] << 16);
                acc[2*j+1] = w0 * __uint_as_float(u[j] & 0xffff0000u);
            }
        }
        int e = 0;
        for (; e + 4 <= deg; e += 4){
            int s0 = __builtin_amdgcn_readfirstlane(esrc[off + e]);
            int s1 = __builtin_amdgcn_readfirstlane(esrc[off + e + 1]);
            int s2 = __builtin_amdgcn_readfirstlane(esrc[off + e + 2]);
            int s3 = __builtin_amdgcn_readfirstlane(esrc[off + e + 3]);
            float w0 = ew[(size_t)(off + e)     * HEADS + g];
            float w1 = ew[(size_t)(off + e + 1) * HEADS + g];
            float w2 = ew[(size_t)(off + e + 2) * HEADS + g];
            float w3 = ew[(size_t)(off + e + 3) * HEADS + g];
            short8 v0 = *(const short8*)(h1b + (size_t)s0 * HH + cb);
            short8 v1 = *(const short8*)(h1b + (size_t)s1 * HH + cb);
            short8 v2 = *(const short8*)(h1b + (size_t)s2 * HH + cb);
            short8 v3 = *(const short8*)(h1b + (size_t)s3 * HH + cb);
            fma8(acc, w0, v0); fma8(acc, w1, v1);
            fma8(acc, w2, v2); fma8(acc, w3, v3);
        }
        for (; e < deg; e++){
            int s0 = __builtin_amdgcn_readfirstlane(esrc[off + e]);
            float w0 = ew[(size_t)(off + e) * HEADS + g];
            short8 v0 = *(const short8*)(h1b + (size_t)s0 * HH + cb);
            fma8(acc, w0, v0);
        }
        float di = dinv[d * HEADS + g];
        unsigned short o8[8];
#pragma unroll
        for (int j = 0; j < 8; j++){
            float v = acc[j] * di + b1[cb + j];
            v = v > 0.f ? v : __expf(v) - 1.f;   // elu
            o8[j] = f2bf(v);
        }
        short8 ov; __builtin_memcpy(&ov, o8, 16);
        *(short8*)(&x2l[row * X2ROW + g * X2GB + i * 8]) = ov;
    }
    __syncthreads();
    if (w == 0){
        int rowbase = blockIdx.x * 16;
        int lr = lane & 15, lk = lane >> 4;
        float4v accv = {0.f, 0.f, 0.f, 0.f};
#pragma unroll
        for (int ks = 0; ks < 16; ks++){
            int c0 = ks * 32 + lk * 8;
            int gg = c0 >> 6, wc = c0 & 63;
            short8 a = *(const short8*)(&x2l[lr * X2ROW + gg * X2GB + wc]);
            short8 b = *(const short8*)(w2t + (size_t)lr * HH + ks * 32 + lk * 8);
            accv = __builtin_amdgcn_mfma_f32_16x16x32_bf16(a, b, accv, 0, 0, 0);
        }
#pragma unroll
        for (int r = 0; r < 4; r++)
            h2[(size_t)(rowbase + lk * 4 + r) * NCLS + lr] = accv[r];
        float s_a = a_s2[lr], d_a = a_d2[lr];
#pragma unroll
        for (int r = 0; r < 4; r++){
            float ps = accv[r] * s_a, pd = accv[r] * d_a;
#pragma unroll
            for (int off = 1; off < 16; off <<= 1){
                ps += __shfl_xor(ps, off);
                pd += __shfl_xor(pd, off);
            }
            if (lr == 0){
                al2s[rowbase + lk * 4 + r] = ps;
                al2d[rowbase + lk * 4 + r] = pd;
            }
        }
    }
}

// ---------------- layer-2: fused softmax + aggregation -> out [N][16] fp32 ----------------
// fast path deg<=64: logits in registers, single gather.
__global__ __launch_bounds__(256) void agg2(const float* __restrict__ h2,
        const float* __restrict__ al2s, const float* __restrict__ al2d,
        const int* __restrict__ offsets, const int* __restrict__ esrc,
        const float* __restrict__ b2, float* __restrict__ out){
    int d = blockIdx.x * 4 + (threadIdx.x >> 6);
    int lane = threadIdx.x & 63;
    if (d >= N_NODES) return;
    int off = offsets[d], deg = offsets[d + 1] - off;
    float ald = al2d[d];
    float a0 = lrelu(al2s[d] + ald);
    int sg = lane >> 4, col = lane & 15;
    float m, dsum, acc;
    if (deg <= 64){
        float ae = -1e30f;
        if (lane < deg) ae = lrelu(al2s[esrc[off + lane]] + ald);
        float t = fmaxf(ae, a0);
#pragma unroll
        for (int o = 1; o < 64; o <<= 1) t = fmaxf(t, __shfl_xor(t, o));
        m = t;
        float ws = (lane < deg) ? __expf(ae - m) : 0.f;
#pragma unroll
        for (int o = 1; o < 64; o <<= 1) ws += __shfl_xor(ws, o);
        dsum = ws + __expf(a0 - m);
        acc = (sg == 0) ? __expf(a0 - m) * h2[(size_t)d * NCLS + col] : 0.f;
        for (int i = sg; i < deg; i += 4){
            int s = esrc[off + i];
            float ai = __shfl(ae, i);
            acc += __expf(ai - m) * h2[(size_t)s * NCLS + col];
        }
    } else {
        m = a0;
        for (int base = 0; base < deg; base += 64){
            int e = base + lane;
            float a = (e < deg) ? lrelu(al2s[esrc[off + e]] + ald) : -1e30f;
#pragma unroll
            for (int o = 1; o < 64; o <<= 1) a = fmaxf(a, __shfl_xor(a, o));
            m = fmaxf(m, a);
        }
        dsum = __expf(a0 - m);
        for (int base = 0; base < deg; base += 64){
            int e = base + lane;
            float w = (e < deg) ? __expf(lrelu(al2s[esrc[off + e]] + ald) - m) : 0.f;
#pragma unroll
            for (int o = 1; o < 64; o <<= 1) w += __shfl_xor(w, o);
            dsum += w;
        }
        acc = (sg == 0) ? __expf(a0 - m) * h2[(size_t)d * NCLS + col] : 0.f;
        for (int i = sg; i < deg; i += 4){
            int s = esrc[off + i];
            float w = __expf(lrelu(al2s[s] + ald) - m);
            acc += w * h2[(size_t)s * NCLS + col];
        }
    }
    acc += __shfl_xor(acc, 16);
    acc += __shfl_xor(acc, 32);
    if (lane < NCLS) out[(size_t)d * NCLS + lane] = acc / dsum + b2[lane];
}

extern "C" void kernel_launch(void* const* d_in, const int* in_sizes, int n_in,
                              void* d_out, int out_size, void* d_ws, size_t ws_size,
                              hipStream_t stream){
    const float* x   = (const float*)d_in[0];
    const int*   ei  = (const int*)d_in[1];
    const int*   src = ei;
    const int*   dst = ei + NEDGE;
    const float* W1  = (const float*)d_in[2];
    const float* as1 = (const float*)d_in[3];
    const float* ad1 = (const float*)d_in[4];
    const float* b1  = (const float*)d_in[5];
    const float* W2  = (const float*)d_in[6];
    const float* as2 = (const float*)d_in[7];
    const float* ad2 = (const float*)d_in[8];
    const float* b2  = (const float*)d_in[9];
    float* out = (float*)d_out;

    char* p = (char*)d_ws;
    auto carve = [&](size_t bytes) -> char* {
        char* r = p; p += (bytes + 255) & ~(size_t)255; return r;
    };
    unsigned short* xb   = (unsigned short*)carve((size_t)N_NODES * F_INK * 2);
    unsigned short* w1t  = (unsigned short*)carve((size_t)HH * F_INK * 2);
    unsigned short* w2t  = (unsigned short*)carve((size_t)HH * NCLS * 2);
    unsigned short* h1b  = (unsigned short*)carve((size_t)N_NODES * HH * 2);
    float* al1s  = (float*)carve((size_t)N_NODES * HEADS * 4);
    float* al1d  = (float*)carve((size_t)N_NODES * HEADS * 4);
    int* counts  = (int*)carve((size_t)N_NODES * 4);
    int* erank   = (int*)carve((size_t)NEDGE * 4);
    int* offsets = (int*)carve((size_t)(N_NODES + 1) * 4);
    int* blocksums = (int*)carve((size_t)NBLK_SCAN * 4);
    int* blockbase = (int*)carve((size_t)NBLK_SCAN * 4);
    int* esrc    = (int*)carve((size_t)NEDGE * 4);
    float* ew    = (float*)carve((size_t)NEDGE * HEADS * 4);
    float* wselfr= (float*)carve((size_t)N_NODES * HEADS * 4);
    float* dinv  = (float*)carve((size_t)N_NODES * HEADS * 4);
    float* h2    = (float*)carve((size_t)N_NODES * NCLS * 4);
    float* al2s  = (float*)carve((size_t)N_NODES * 4);
    float* al2d  = (float*)carve((size_t)N_NODES * 4);
    if ((size_t)(p - (char*)d_ws) > ws_size) return;  // workspace too small

    hipMemsetAsync(counts, 0, N_NODES * 4, stream);

    prep<<<PREP_X_BLKS + PREP_W_BLKS + SCAT_BLKS, 256, 0, stream>>>(
        x, xb, W1, w1t, W2, w2t, dst, counts, erank);
    scan_part<<<NBLK_SCAN, 256, 0, stream>>>(counts, blocksums);
    scan_top<<<1, 256, 0, stream>>>(blocksums, blockbase, offsets);
    scan_write<<<NBLK_SCAN, 256, 0, stream>>>(counts, blockbase, offsets);
    gemm1_scatter<<<G1_BLKS + SCAT_BLKS, 256, 0, stream>>>(
        xb, w1t, as1, ad1, h1b, al1s, al1d, src, dst, offsets, erank, esrc);
    softmax1<<<(N_NODES + 3) / 4, 256, 0, stream>>>(al1s, al1d, offsets, esrc, ew, wselfr, dinv);
    agg1f<<<N_NODES / 16, 256, 0, stream>>>(h1b, ew, wselfr, dinv, offsets, esrc, b1,
                                            w2t, as2, ad2, h2, al2s, al2d);
    agg2<<<(N_NODES + 3) / 4, 256, 0, stream>>>(h2, al2s, al2d, offsets, esrc, b2, out);
}

// Round 18
// 210.002 us; speedup vs baseline: 1.4271x; 1.0554x over previous
//
#include <hip/hip_runtime.h>
#include <hip/hip_bf16.h>
#include <math.h>

#define N_NODES 50000
#define F_INK   256
#define HEADS   8
#define HID     64
#define HH      512     // HEADS*HID
#define NCLS    16
#define NEDGE   400000
#define NEG_SLOPE 0.2f

#define BCOLS 64
#define KPAD  264       // 256 + 8 bf16 pad (quad-bank spread); 64*264*2 = 33 KB
#define NBLK_SCAN ((N_NODES + 255) / 256)   // 196
// LDS x2 tile (agg1f): 16 rows; row = 8 g-blocks of (64 data + 8 pad) + 8 row-pad = 584 shorts
#define X2ROW 584
#define X2GB  72
// prep partition
#define PREP_X_BLKS 12500                   // 3,200,000 float4 items (N*F_IN/4), exact
#define PREP_W_BLKS 544                     // 131072 + 8192 = 139264 items, exact
// gemm1+scatter partition
#define G1_BLKS 1024                        // 8 panels * 128 row-groups
#define SCAT_BLKS ((NEDGE + 255) / 256)     // 1563

typedef __attribute__((ext_vector_type(8))) short short8;
typedef __attribute__((ext_vector_type(4))) short sh4;
typedef __attribute__((ext_vector_type(4))) float float4v;

__device__ __forceinline__ float bf2f(unsigned short u){
    unsigned int x = ((unsigned int)u) << 16;
    float f; __builtin_memcpy(&f, &x, 4); return f;
}
__device__ __forceinline__ unsigned short f2bf(float f){
    unsigned int x; __builtin_memcpy(&x, &f, 4);
    unsigned int r = x + 0x7FFFu + ((x >> 16) & 1u);   // RNE
    return (unsigned short)(r >> 16);
}
__device__ __forceinline__ float lrelu(float a){ return a > 0.f ? a : NEG_SLOPE * a; }

__device__ __forceinline__ void fma8(float* acc, float w, short8 v){
    unsigned int u[4]; __builtin_memcpy(u, &v, 16);
#pragma unroll
    for (int j = 0; j < 4; j++){
        acc[2*j]   += w * __uint_as_float(u[j] << 16);
        acc[2*j+1] += w * __uint_as_float(u[j] & 0xffff0000u);
    }
}

// ---------------- prep: cvt x -> bf16, cvt weights, count edges (one launch) ----------------
__global__ __launch_bounds__(256) void prep(const float* __restrict__ x, unsigned short* __restrict__ xb,
                                            const float* __restrict__ W1, unsigned short* __restrict__ W1T,
                                            const float* __restrict__ W2, unsigned short* __restrict__ W2T,
                                            const int* __restrict__ dst, int* __restrict__ counts,
                                            int* __restrict__ erank){
    int bid = blockIdx.x;
    if (bid < PREP_X_BLKS){
        int i = bid * 256 + threadIdx.x;        // exactly 3,200,000 items
        float4v f = *(const float4v*)(x + (size_t)i * 4);
        sh4 o;
#pragma unroll
        for (int j = 0; j < 4; j++) o[j] = (short)f2bf(f[j]);
        *(sh4*)(xb + (size_t)i * 4) = o;
    } else if (bid < PREP_X_BLKS + PREP_W_BLKS){
        int i = (bid - PREP_X_BLKS) * 256 + threadIdx.x;
        if (i < F_INK * HH){
            int k = i / HH, c = i % HH;
            W1T[c * F_INK + k] = f2bf(W1[i]);
        } else {
            int j = i - F_INK * HH;             // < 8192 by partition sizing
            int k = j / NCLS, c = j % NCLS;
            W2T[c * HH + k] = f2bf(W2[j]);
        }
    } else {
        int e = (bid - PREP_X_BLKS - PREP_W_BLKS) * 256 + threadIdx.x;
        if (e < NEDGE) erank[e] = atomicAdd(&counts[dst[e]], 1);
    }
}

// ---------------- CSR scan ----------------
__global__ __launch_bounds__(256) void scan_part(const int* __restrict__ counts,
                                                 int* __restrict__ blocksums){
    __shared__ int red[256];
    int i = blockIdx.x * 256 + threadIdx.x;
    int v = (i < N_NODES) ? counts[i] : 0;
    red[threadIdx.x] = v; __syncthreads();
    for (int off = 128; off > 0; off >>= 1){
        if (threadIdx.x < off) red[threadIdx.x] += red[threadIdx.x + off];
        __syncthreads();
    }
    if (threadIdx.x == 0) blocksums[blockIdx.x] = red[0];
}

__global__ __launch_bounds__(256) void scan_top(const int* __restrict__ blocksums,
                                                int* __restrict__ blockbase,
                                                int* __restrict__ offsets){
    __shared__ int s[256];
    int t = threadIdx.x;
    int v = (t < NBLK_SCAN) ? blocksums[t] : 0;
    s[t] = v; __syncthreads();
    int val = v;
    for (int off = 1; off < 256; off <<= 1){
        int o2 = (t >= off) ? s[t - off] : 0;
        __syncthreads();
        val += o2; s[t] = val;
        __syncthreads();
    }
    if (t < NBLK_SCAN) blockbase[t] = val - v;   // exclusive
    if (t == 255) offsets[N_NODES] = s[255];     // grand total
}

__global__ __launch_bounds__(256) void scan_write(const int* __restrict__ counts,
                                                  const int* __restrict__ blockbase,
                                                  int* __restrict__ offsets){
    __shared__ int s[256];
    int i = blockIdx.x * 256 + threadIdx.x;
    int t = threadIdx.x;
    int v = (i < N_NODES) ? counts[i] : 0;
    s[t] = v; __syncthreads();
    int val = v;
    for (int off = 1; off < 256; off <<= 1){
        int o2 = (t >= off) ? s[t - off] : 0;
        __syncthreads();
        val += o2; s[t] = val;
        __syncthreads();
    }
    if (i < N_NODES) offsets[i] = blockbase[blockIdx.x] + val - v;
}

// ---------------- GEMM1 (64-col panels, fused attn dots) + scatter (merged launch) --------
// XCD-locality: panel index is the SLOW block dim so the 8 blocks sharing a row-group's
// A-tile have bid == rg (mod 8) -> same XCD -> A staged into that XCD's L2 once.
__global__ __launch_bounds__(256) void gemm1_scatter(
        const unsigned short* __restrict__ xb, const unsigned short* __restrict__ w1t,
        const float* __restrict__ a_src, const float* __restrict__ a_dst,
        unsigned short* __restrict__ h1b, float* __restrict__ al_s, float* __restrict__ al_d,
        const int* __restrict__ src, const int* __restrict__ dst,
        const int* __restrict__ offsets, const int* __restrict__ erank,
        int* __restrict__ esrc){
    __shared__ unsigned short bs[BCOLS * KPAD];   // 33 KB
    if (blockIdx.x >= G1_BLKS){
        int e = (blockIdx.x - G1_BLKS) * 256 + threadIdx.x;
        if (e < NEDGE) esrc[offsets[dst[e]] + erank[e]] = src[e];
        return;
    }
    int cb  = blockIdx.x >> 7;         // col panel == head (slow index)
    int rg  = blockIdx.x & 127;        // row-group (fast index -> XCD affinity)
    const int nrg = G1_BLKS >> 3;      // 128
    {   // stage B panel once
        int kc = threadIdx.x & 31;
        int c0 = threadIdx.x >> 5;
#pragma unroll
        for (int it = 0; it < 8; it++){
            int col = it * 8 + c0;
            short8 v = *(const short8*)(w1t + (size_t)(cb * BCOLS + col) * F_INK + kc * 8);
            *(short8*)(&bs[col * KPAD + kc * 8]) = v;
        }
    }
    __syncthreads();
    int w    = threadIdx.x >> 6;
    int lane = threadIdx.x & 63;
    int lr = lane & 15, lk = lane >> 4;
    float a_s[4], a_d[4];
#pragma unroll
    for (int ct = 0; ct < 4; ct++){
        a_s[ct] = a_src[cb * HID + ct * 16 + lr];
        a_d[ct] = a_dst[cb * HID + ct * 16 + lr];
    }
    const int nchunk = (N_NODES + 127) / 128;     // 391
    for (int ch = rg; ch < nchunk; ch += nrg){
        int rb0 = ch * 128 + w * 32;
        if (rb0 >= N_NODES) continue;
        bool t1 = (rb0 + 16 < N_NODES);
        short8 a0[8], a1[8];
#pragma unroll
        for (int ks = 0; ks < 8; ks++)
            a0[ks] = *(const short8*)(xb + (size_t)(rb0 + lr) * F_INK + ks * 32 + lk * 8);
        if (t1){
#pragma unroll
            for (int ks = 0; ks < 8; ks++)
                a1[ks] = *(const short8*)(xb + (size_t)(rb0 + 16 + lr) * F_INK + ks * 32 + lk * 8);
        }
        float ds0[4] = {0.f,0.f,0.f,0.f}, dd0[4] = {0.f,0.f,0.f,0.f};
        float ds1[4] = {0.f,0.f,0.f,0.f}, dd1[4] = {0.f,0.f,0.f,0.f};
#pragma unroll
        for (int ct = 0; ct < 4; ct++){
            float4v acc0 = {0.f, 0.f, 0.f, 0.f};
            float4v acc1 = {0.f, 0.f, 0.f, 0.f};
#pragma unroll
            for (int ks = 0; ks < 8; ks++){
                short8 b = *(const short8*)(&bs[(ct * 16 + lr) * KPAD + ks * 32 + lk * 8]);
                acc0 = __builtin_amdgcn_mfma_f32_16x16x32_bf16(a0[ks], b, acc0, 0, 0, 0);
                if (t1) acc1 = __builtin_amdgcn_mfma_f32_16x16x32_bf16(a1[ks], b, acc1, 0, 0, 0);
            }
#pragma unroll
            for (int r = 0; r < 4; r++){
                h1b[(size_t)(rb0 + lk * 4 + r) * HH + cb * BCOLS + ct * 16 + lr] = f2bf(acc0[r]);
                ds0[r] += acc0[r] * a_s[ct];
                dd0[r] += acc0[r] * a_d[ct];
            }
            if (t1){
#pragma unroll
                for (int r = 0; r < 4; r++){
                    h1b[(size_t)(rb0 + 16 + lk * 4 + r) * HH + cb * BCOLS + ct * 16 + lr] = f2bf(acc1[r]);
                    ds1[r] += acc1[r] * a_s[ct];
                    dd1[r] += acc1[r] * a_d[ct];
                }
            }
        }
#pragma unroll
        for (int r = 0; r < 4; r++){
#pragma unroll
            for (int o = 1; o < 16; o <<= 1){
                ds0[r] += __shfl_xor(ds0[r], o);
                dd0[r] += __shfl_xor(dd0[r], o);
                ds1[r] += __shfl_xor(ds1[r], o);
                dd1[r] += __shfl_xor(dd1[r], o);
            }
        }
        if (lr == 0){
#pragma unroll
            for (int r = 0; r < 4; r++){
                al_s[(rb0 + lk * 4 + r) * HEADS + cb] = ds0[r];
                al_d[(rb0 + lk * 4 + r) * HEADS + cb] = dd0[r];
            }
            if (t1){
#pragma unroll
                for (int r = 0; r < 4; r++){
                    al_s[(rb0 + 16 + lk * 4 + r) * HEADS + cb] = ds1[r];
                    al_d[(rb0 + 16 + lk * 4 + r) * HEADS + cb] = dd1[r];
                }
            }
        }
    }
}

// ---------------- layer-1 softmax: raw weights ew, wselfr, dinv ----------------
__global__ __launch_bounds__(256) void softmax1(
        const float* __restrict__ al_s, const float* __restrict__ al_d,
        const int* __restrict__ offsets, const int* __restrict__ esrc,
        float* __restrict__ ew, float* __restrict__ wselfr, float* __restrict__ dinv){
    int d = blockIdx.x * 4 + (threadIdx.x >> 6);
    int lane = threadIdx.x & 63;
    if (d >= N_NODES) return;
    int h = lane & 7, i = lane >> 3;
    int off = offsets[d], deg = offsets[d + 1] - off;
    float ald = al_d[d * HEADS + h];
    float aself = lrelu(al_s[d * HEADS + h] + ald);
    float m = aself;
    for (int base = 0; base < deg; base += 8){
        int e = base + i;
        float a = -1e30f;
        if (e < deg) a = lrelu(al_s[esrc[off + e] * HEADS + h] + ald);
        a = fmaxf(a, __shfl_xor(a, 8));
        a = fmaxf(a, __shfl_xor(a, 16));
        a = fmaxf(a, __shfl_xor(a, 32));
        m = fmaxf(m, a);
    }
    float denom = __expf(aself - m);
    for (int base = 0; base < deg; base += 8){
        int e = base + i;
        float w = 0.f;
        if (e < deg){
            w = __expf(lrelu(al_s[esrc[off + e] * HEADS + h] + ald) - m);
            ew[(size_t)(off + e) * HEADS + h] = w;    // unnormalized
        }
        float ws = w;
        ws += __shfl_xor(ws, 8);
        ws += __shfl_xor(ws, 16);
        ws += __shfl_xor(ws, 32);
        denom += ws;
    }
    if (i == 0){
        wselfr[d * HEADS + h] = __expf(aself - m);
        dinv[d * HEADS + h]   = 1.f / denom;
    }
}

// ---------------- layer-1 aggregation + fused layer-2 GEMM ----------------
__global__ __launch_bounds__(256) void agg1f(const unsigned short* __restrict__ h1b,
        const float* __restrict__ ew, const float* __restrict__ wselfr,
        const float* __restrict__ dinv,
        const int* __restrict__ offsets, const int* __restrict__ esrc,
        const float* __restrict__ b1,
        const unsigned short* __restrict__ w2t,
        const float* __restrict__ a_s2, const float* __restrict__ a_d2,
        float* __restrict__ h2, float* __restrict__ al2s, float* __restrict__ al2d){
    __shared__ unsigned short x2l[16 * X2ROW];    // 18.7 KB
    int w = threadIdx.x >> 6;
    int lane = threadIdx.x & 63;
    int g = lane >> 3, i = lane & 7;
    int cb = g * HID + i * 8;
#pragma unroll
    for (int q = 0; q < 4; q++){
        int row = w * 4 + q;
        int d = blockIdx.x * 16 + row;
        int off = offsets[d], deg = offsets[d + 1] - off;
        float acc[8];
        {   // self edge
            float w0 = wselfr[d * HEADS + g];
            short8 v = *(const short8*)(h1b + (size_t)d * HH + cb);
            unsigned int u[4]; __builtin_memcpy(u, &v, 16);
#pragma unroll
            for (int j = 0; j < 4; j++){
                acc[2*j]   = w0 * __uint_as_float(u[j] << 16);
                acc[2*j+1] = w0 * __uint_as_float(u[j] & 0xffff0000u);
            }
        }
        int e = 0;
        for (; e + 4 <= deg; e += 4){
            int s0 = __builtin_amdgcn_readfirstlane(esrc[off + e]);
            int s1 = __builtin_amdgcn_readfirstlane(esrc[off + e + 1]);
            int s2 = __builtin_amdgcn_readfirstlane(esrc[off + e + 2]);
            int s3 = __builtin_amdgcn_readfirstlane(esrc[off + e + 3]);
            float w0 = ew[(size_t)(off + e)     * HEADS + g];
            float w1 = ew[(size_t)(off + e + 1) * HEADS + g];
            float w2 = ew[(size_t)(off + e + 2) * HEADS + g];
            float w3 = ew[(size_t)(off + e + 3) * HEADS + g];
            short8 v0 = *(const short8*)(h1b + (size_t)s0 * HH + cb);
            short8 v1 = *(const short8*)(h1b + (size_t)s1 * HH + cb);
            short8 v2 = *(const short8*)(h1b + (size_t)s2 * HH + cb);
            short8 v3 = *(const short8*)(h1b + (size_t)s3 * HH + cb);
            fma8(acc, w0, v0); fma8(acc, w1, v1);
            fma8(acc, w2, v2); fma8(acc, w3, v3);
        }
        for (; e < deg; e++){
            int s0 = __builtin_amdgcn_readfirstlane(esrc[off + e]);
            float w0 = ew[(size_t)(off + e) * HEADS + g];
            short8 v0 = *(const short8*)(h1b + (size_t)s0 * HH + cb);
            fma8(acc, w0, v0);
        }
        float di = dinv[d * HEADS + g];
        unsigned short o8[8];
#pragma unroll
        for (int j = 0; j < 8; j++){
            float v = acc[j] * di + b1[cb + j];
            v = v > 0.f ? v : __expf(v) - 1.f;   // elu
            o8[j] = f2bf(v);
        }
        short8 ov; __builtin_memcpy(&ov, o8, 16);
        *(short8*)(&x2l[row * X2ROW + g * X2GB + i * 8]) = ov;
    }
    __syncthreads();
    if (w == 0){
        int rowbase = blockIdx.x * 16;
        int lr = lane & 15, lk = lane >> 4;
        float4v accv = {0.f, 0.f, 0.f, 0.f};
#pragma unroll
        for (int ks = 0; ks < 16; ks++){
            int c0 = ks * 32 + lk * 8;
            int gg = c0 >> 6, wc = c0 & 63;
            short8 a = *(const short8*)(&x2l[lr * X2ROW + gg * X2GB + wc]);
            short8 b = *(const short8*)(w2t + (size_t)lr * HH + ks * 32 + lk * 8);
            accv = __builtin_amdgcn_mfma_f32_16x16x32_bf16(a, b, accv, 0, 0, 0);
        }
#pragma unroll
        for (int r = 0; r < 4; r++)
            h2[(size_t)(rowbase + lk * 4 + r) * NCLS + lr] = accv[r];
        float s_a = a_s2[lr], d_a = a_d2[lr];
#pragma unroll
        for (int r = 0; r < 4; r++){
            float ps = accv[r] * s_a, pd = accv[r] * d_a;
#pragma unroll
            for (int off = 1; off < 16; off <<= 1){
                ps += __shfl_xor(ps, off);
                pd += __shfl_xor(pd, off);
            }
            if (lr == 0){
                al2s[rowbase + lk * 4 + r] = ps;
                al2d[rowbase + lk * 4 + r] = pd;
            }
        }
    }
}

// ---------------- layer-2: fused softmax + aggregation -> out [N][16] fp32 ----------------
__global__ __launch_bounds__(256) void agg2(const float* __restrict__ h2,
        const float* __restrict__ al2s, const float* __restrict__ al2d,
        const int* __restrict__ offsets, const int* __restrict__ esrc,
        const float* __restrict__ b2, float* __restrict__ out){
    int d = blockIdx.x * 4 + (threadIdx.x >> 6);
    int lane = threadIdx.x & 63;
    if (d >= N_NODES) return;
    int off = offsets[d], deg = offsets[d + 1] - off;
    float ald = al2d[d];
    float a0 = lrelu(al2s[d] + ald);
    int sg = lane >> 4, col = lane & 15;
    float m, dsum, acc;
    if (deg <= 64){
        float ae = -1e30f;
        if (lane < deg) ae = lrelu(al2s[esrc[off + lane]] + ald);
        float t = fmaxf(ae, a0);
#pragma unroll
        for (int o = 1; o < 64; o <<= 1) t = fmaxf(t, __shfl_xor(t, o));
        m = t;
        float ws = (lane < deg) ? __expf(ae - m) : 0.f;
#pragma unroll
        for (int o = 1; o < 64; o <<= 1) ws += __shfl_xor(ws, o);
        dsum = ws + __expf(a0 - m);
        acc = (sg == 0) ? __expf(a0 - m) * h2[(size_t)d * NCLS + col] : 0.f;
        for (int i = sg; i < deg; i += 4){
            int s = esrc[off + i];
            float ai = __shfl(ae, i);
            acc += __expf(ai - m) * h2[(size_t)s * NCLS + col];
        }
    } else {
        m = a0;
        for (int base = 0; base < deg; base += 64){
            int e = base + lane;
            float a = (e < deg) ? lrelu(al2s[esrc[off + e]] + ald) : -1e30f;
#pragma unroll
            for (int o = 1; o < 64; o <<= 1) a = fmaxf(a, __shfl_xor(a, o));
            m = fmaxf(m, a);
        }
        dsum = __expf(a0 - m);
        for (int base = 0; base < deg; base += 64){
            int e = base + lane;
            float w = (e < deg) ? __expf(lrelu(al2s[esrc[off + e]] + ald) - m) : 0.f;
#pragma unroll
            for (int o = 1; o < 64; o <<= 1) w += __shfl_xor(w, o);
            dsum += w;
        }
        acc = (sg == 0) ? __expf(a0 - m) * h2[(size_t)d * NCLS + col] : 0.f;
        for (int i = sg; i < deg; i += 4){
            int s = esrc[off + i];
            float w = __expf(lrelu(al2s[s] + ald) - m);
            acc += w * h2[(size_t)s * NCLS + col];
        }
    }
    acc += __shfl_xor(acc, 16);
    acc += __shfl_xor(acc, 32);
    if (lane < NCLS) out[(size_t)d * NCLS + lane] = acc / dsum + b2[lane];
}

extern "C" void kernel_launch(void* const* d_in, const int* in_sizes, int n_in,
                              void* d_out, int out_size, void* d_ws, size_t ws_size,
                              hipStream_t stream){
    const float* x   = (const float*)d_in[0];
    const int*   ei  = (const int*)d_in[1];
    const int*   src = ei;
    const int*   dst = ei + NEDGE;
    const float* W1  = (const float*)d_in[2];
    const float* as1 = (const float*)d_in[3];
    const float* ad1 = (const float*)d_in[4];
    const float* b1  = (const float*)d_in[5];
    const float* W2  = (const float*)d_in[6];
    const float* as2 = (const float*)d_in[7];
    const float* ad2 = (const float*)d_in[8];
    const float* b2  = (const float*)d_in[9];
    float* out = (float*)d_out;

    char* p = (char*)d_ws;
    auto carve = [&](size_t bytes) -> char* {
        char* r = p; p += (bytes + 255) & ~(size_t)255; return r;
    };
    unsigned short* xb   = (unsigned short*)carve((size_t)N_NODES * F_INK * 2);
    unsigned short* w1t  = (unsigned short*)carve((size_t)HH * F_INK * 2);
    unsigned short* w2t  = (unsigned short*)carve((size_t)HH * NCLS * 2);
    unsigned short* h1b  = (unsigned short*)carve((size_t)N_NODES * HH * 2);
    float* al1s  = (float*)carve((size_t)N_NODES * HEADS * 4);
    float* al1d  = (float*)carve((size_t)N_NODES * HEADS * 4);
    int* counts  = (int*)carve((size_t)N_NODES * 4);
    int* erank   = (int*)carve((size_t)NEDGE * 4);
    int* offsets = (int*)carve((size_t)(N_NODES + 1) * 4);
    int* blocksums = (int*)carve((size_t)NBLK_SCAN * 4);
    int* blockbase = (int*)carve((size_t)NBLK_SCAN * 4);
    int* esrc    = (int*)carve((size_t)NEDGE * 4);
    float* ew    = (float*)carve((size_t)NEDGE * HEADS * 4);
    float* wselfr= (float*)carve((size_t)N_NODES * HEADS * 4);
    float* dinv  = (float*)carve((size_t)N_NODES * HEADS * 4);
    float* h2    = (float*)carve((size_t)N_NODES * NCLS * 4);
    float* al2s  = (float*)carve((size_t)N_NODES * 4);
    float* al2d  = (float*)carve((size_t)N_NODES * 4);
    if ((size_t)(p - (char*)d_ws) > ws_size) return;  // workspace too small

    hipMemsetAsync(counts, 0, N_NODES * 4, stream);

    prep<<<PREP_X_BLKS + PREP_W_BLKS + SCAT_BLKS, 256, 0, stream>>>(
        x, xb, W1, w1t, W2, w2t, dst, counts, erank);
    scan_part<<<NBLK_SCAN, 256, 0, stream>>>(counts, blocksums);
    scan_top<<<1, 256, 0, stream>>>(blocksums, blockbase, offsets);
    scan_write<<<NBLK_SCAN, 256, 0, stream>>>(counts, blockbase, offsets);
    gemm1_scatter<<<G1_BLKS + SCAT_BLKS, 256, 0, stream>>>(
        xb, w1t, as1, ad1, h1b, al1s, al1d, src, dst, offsets, erank, esrc);
    softmax1<<<(N_NODES + 3) / 4, 256, 0, stream>>>(al1s, al1d, offsets, esrc, ew, wselfr, dinv);
    agg1f<<<N_NODES / 16, 256, 0, stream>>>(h1b, ew, wselfr, dinv, offsets, esrc, b1,
                                            w2t, as2, ad2, h2, al2s, al2d);
    agg2<<<(N_NODES + 3) / 4, 256, 0, stream>>>(h2, al2s, al2d, offsets, esrc, b2, out);
}

// Round 21
// 209.716 us; speedup vs baseline: 1.4291x; 1.0014x over previous
//
#include <hip/hip_runtime.h>
#include <hip/hip_bf16.h>
#include <math.h>

#define N_NODES 50000
#define F_INK   256
#define HEADS   8
#define HID     64
#define HH      512     // HEADS*HID
#define NCLS    16
#define NEDGE   400000
#define NEG_SLOPE 0.2f

#define BCOLS 64
#define KPAD  264       // 256 + 8 bf16 pad (quad-bank spread); 64*264*2 = 33 KB
#define NBLK_SCAN ((N_NODES + 255) / 256)   // 196
// LDS x2 tile (agg1f): 16 rows; row = 8 g-blocks of (64 data + 8 pad) + 8 row-pad = 584 shorts
#define X2ROW 584
#define X2GB  72
// prep partition
#define PREP_X_BLKS 12500                   // 3,200,000 float4 items (N*F_IN/4), exact
#define PREP_W_BLKS 544                     // 131072 + 8192 = 139264 items, exact
// gemm1+scatter partition
#define G1_BLKS 1024                        // 8 panels * 128 row-groups
#define SCAT_BLKS ((NEDGE + 255) / 256)     // 1563

typedef __attribute__((ext_vector_type(8))) short short8;
typedef __attribute__((ext_vector_type(4))) short sh4;
typedef __attribute__((ext_vector_type(4))) float float4v;

__device__ __forceinline__ float bf2f(unsigned short u){
    unsigned int x = ((unsigned int)u) << 16;
    float f; __builtin_memcpy(&f, &x, 4); return f;
}
__device__ __forceinline__ unsigned short f2bf(float f){
    unsigned int x; __builtin_memcpy(&x, &f, 4);
    unsigned int r = x + 0x7FFFu + ((x >> 16) & 1u);   // RNE
    return (unsigned short)(r >> 16);
}
__device__ __forceinline__ float lrelu(float a){ return a > 0.f ? a : NEG_SLOPE * a; }

__device__ __forceinline__ void fma8(float* acc, float w, short8 v){
    unsigned int u[4]; __builtin_memcpy(u, &v, 16);
#pragma unroll
    for (int j = 0; j < 4; j++){
        acc[2*j]   += w * __uint_as_float(u[j] << 16);
        acc[2*j+1] += w * __uint_as_float(u[j] & 0xffff0000u);
    }
}

// ---------------- prep: cvt x -> bf16, cvt weights, count edges (one launch) ----------------
__global__ __launch_bounds__(256) void prep(const float* __restrict__ x, unsigned short* __restrict__ xb,
                                            const float* __restrict__ W1, unsigned short* __restrict__ W1T,
                                            const float* __restrict__ W2, unsigned short* __restrict__ W2T,
                                            const int* __restrict__ dst, int* __restrict__ counts,
                                            int* __restrict__ erank){
    int bid = blockIdx.x;
    if (bid < PREP_X_BLKS){
        int i = bid * 256 + threadIdx.x;        // exactly 3,200,000 items
        float4v f = *(const float4v*)(x + (size_t)i * 4);
        sh4 o;
#pragma unroll
        for (int j = 0; j < 4; j++) o[j] = (short)f2bf(f[j]);
        *(sh4*)(xb + (size_t)i * 4) = o;
    } else if (bid < PREP_X_BLKS + PREP_W_BLKS){
        int i = (bid - PREP_X_BLKS) * 256 + threadIdx.x;
        if (i < F_INK * HH){
            int k = i / HH, c = i % HH;
            W1T[c * F_INK + k] = f2bf(W1[i]);
        } else {
            int j = i - F_INK * HH;             // < 8192 by partition sizing
            int k = j / NCLS, c = j % NCLS;
            W2T[c * HH + k] = f2bf(W2[j]);
        }
    } else {
        int e = (bid - PREP_X_BLKS - PREP_W_BLKS) * 256 + threadIdx.x;
        if (e < NEDGE) erank[e] = atomicAdd(&counts[dst[e]], 1);
    }
}

// ---------------- CSR scan ----------------
__global__ __launch_bounds__(256) void scan_part(const int* __restrict__ counts,
                                                 int* __restrict__ blocksums){
    __shared__ int red[256];
    int i = blockIdx.x * 256 + threadIdx.x;
    int v = (i < N_NODES) ? counts[i] : 0;
    red[threadIdx.x] = v; __syncthreads();
    for (int off = 128; off > 0; off >>= 1){
        if (threadIdx.x < off) red[threadIdx.x] += red[threadIdx.x + off];
        __syncthreads();
    }
    if (threadIdx.x == 0) blocksums[blockIdx.x] = red[0];
}

__global__ __launch_bounds__(256) void scan_top(const int* __restrict__ blocksums,
                                                int* __restrict__ blockbase,
                                                int* __restrict__ offsets){
    __shared__ int s[256];
    int t = threadIdx.x;
    int v = (t < NBLK_SCAN) ? blocksums[t] : 0;
    s[t] = v; __syncthreads();
    int val = v;
    for (int off = 1; off < 256; off <<= 1){
        int o2 = (t >= off) ? s[t - off] : 0;
        __syncthreads();
        val += o2; s[t] = val;
        __syncthreads();
    }
    if (t < NBLK_SCAN) blockbase[t] = val - v;   // exclusive
    if (t == 255) offsets[N_NODES] = s[255];     // grand total
}

__global__ __launch_bounds__(256) void scan_write(const int* __restrict__ counts,
                                                  const int* __restrict__ blockbase,
                                                  int* __restrict__ offsets){
    __shared__ int s[256];
    int i = blockIdx.x * 256 + threadIdx.x;
    int t = threadIdx.x;
    int v = (i < N_NODES) ? counts[i] : 0;
    s[t] = v; __syncthreads();
    int val = v;
    for (int off = 1; off < 256; off <<= 1){
        int o2 = (t >= off) ? s[t - off] : 0;
        __syncthreads();
        val += o2; s[t] = val;
        __syncthreads();
    }
    if (i < N_NODES) offsets[i] = blockbase[blockIdx.x] + val - v;
}

// ---------------- GEMM1 (64-col panels, fused attn dots) + scatter (merged launch) --------
// XCD-locality: panel index is the SLOW block dim so the 8 blocks sharing a row-group's
// A-tile have bid == rg (mod 8) -> same XCD -> A staged into that XCD's L2 once.
__global__ __launch_bounds__(256) void gemm1_scatter(
        const unsigned short* __restrict__ xb, const unsigned short* __restrict__ w1t,
        const float* __restrict__ a_src, const float* __restrict__ a_dst,
        unsigned short* __restrict__ h1b, float* __restrict__ al_s, float* __restrict__ al_d,
        const int* __restrict__ src, const int* __restrict__ dst,
        const int* __restrict__ offsets, const int* __restrict__ erank,
        int* __restrict__ esrc){
    __shared__ unsigned short bs[BCOLS * KPAD];   // 33 KB
    if (blockIdx.x >= G1_BLKS){
        int e = (blockIdx.x - G1_BLKS) * 256 + threadIdx.x;
        if (e < NEDGE) esrc[offsets[dst[e]] + erank[e]] = src[e];
        return;
    }
    int cb  = blockIdx.x >> 7;         // col panel == head (slow index)
    int rg  = blockIdx.x & 127;        // row-group (fast index -> XCD affinity)
    const int nrg = G1_BLKS >> 3;      // 128
    {   // stage B panel once
        int kc = threadIdx.x & 31;
        int c0 = threadIdx.x >> 5;
#pragma unroll
        for (int it = 0; it < 8; it++){
            int col = it * 8 + c0;
            short8 v = *(const short8*)(w1t + (size_t)(cb * BCOLS + col) * F_INK + kc * 8);
            *(short8*)(&bs[col * KPAD + kc * 8]) = v;
        }
    }
    __syncthreads();
    int w    = threadIdx.x >> 6;
    int lane = threadIdx.x & 63;
    int lr = lane & 15, lk = lane >> 4;
    float a_s[4], a_d[4];
#pragma unroll
    for (int ct = 0; ct < 4; ct++){
        a_s[ct] = a_src[cb * HID + ct * 16 + lr];
        a_d[ct] = a_dst[cb * HID + ct * 16 + lr];
    }
    const int nchunk = (N_NODES + 127) / 128;     // 391
    for (int ch = rg; ch < nchunk; ch += nrg){
        int rb0 = ch * 128 + w * 32;
        if (rb0 >= N_NODES) continue;
        bool t1 = (rb0 + 16 < N_NODES);
        short8 a0[8], a1[8];
#pragma unroll
        for (int ks = 0; ks < 8; ks++)
            a0[ks] = *(const short8*)(xb + (size_t)(rb0 + lr) * F_INK + ks * 32 + lk * 8);
        if (t1){
#pragma unroll
            for (int ks = 0; ks < 8; ks++)
                a1[ks] = *(const short8*)(xb + (size_t)(rb0 + 16 + lr) * F_INK + ks * 32 + lk * 8);
        }
        float ds0[4] = {0.f,0.f,0.f,0.f}, dd0[4] = {0.f,0.f,0.f,0.f};
        float ds1[4] = {0.f,0.f,0.f,0.f}, dd1[4] = {0.f,0.f,0.f,0.f};
#pragma unroll
        for (int ct = 0; ct < 4; ct++){
            float4v acc0 = {0.f, 0.f, 0.f, 0.f};
            float4v acc1 = {0.f, 0.f, 0.f, 0.f};
#pragma unroll
            for (int ks = 0; ks < 8; ks++){
                short8 b = *(const short8*)(&bs[(ct * 16 + lr) * KPAD + ks * 32 + lk * 8]);
                acc0 = __builtin_amdgcn_mfma_f32_16x16x32_bf16(a0[ks], b, acc0, 0, 0, 0);
                if (t1) acc1 = __builtin_amdgcn_mfma_f32_16x16x32_bf16(a1[ks], b, acc1, 0, 0, 0);
            }
#pragma unroll
            for (int r = 0; r < 4; r++){
                h1b[(size_t)(rb0 + lk * 4 + r) * HH + cb * BCOLS + ct * 16 + lr] = f2bf(acc0[r]);
                ds0[r] += acc0[r] * a_s[ct];
                dd0[r] += acc0[r] * a_d[ct];
            }
            if (t1){
#pragma unroll
                for (int r = 0; r < 4; r++){
                    h1b[(size_t)(rb0 + 16 + lk * 4 + r) * HH + cb * BCOLS + ct * 16 + lr] = f2bf(acc1[r]);
                    ds1[r] += acc1[r] * a_s[ct];
                    dd1[r] += acc1[r] * a_d[ct];
                }
            }
        }
#pragma unroll
        for (int r = 0; r < 4; r++){
#pragma unroll
            for (int o = 1; o < 16; o <<= 1){
                ds0[r] += __shfl_xor(ds0[r], o);
                dd0[r] += __shfl_xor(dd0[r], o);
                ds1[r] += __shfl_xor(ds1[r], o);
                dd1[r] += __shfl_xor(dd1[r], o);
            }
        }
        if (lr == 0){
#pragma unroll
            for (int r = 0; r < 4; r++){
                al_s[(rb0 + lk * 4 + r) * HEADS + cb] = ds0[r];
                al_d[(rb0 + lk * 4 + r) * HEADS + cb] = dd0[r];
            }
            if (t1){
#pragma unroll
                for (int r = 0; r < 4; r++){
                    al_s[(rb0 + 16 + lk * 4 + r) * HEADS + cb] = ds1[r];
                    al_d[(rb0 + 16 + lk * 4 + r) * HEADS + cb] = dd1[r];
                }
            }
        }
    }
}

// ---------------- layer-1 softmax: raw weights ew, wselfr, dinv ----------------
__global__ __launch_bounds__(256) void softmax1(
        const float* __restrict__ al_s, const float* __restrict__ al_d,
        const int* __restrict__ offsets, const int* __restrict__ esrc,
        float* __restrict__ ew, float* __restrict__ wselfr, float* __restrict__ dinv){
    int d = blockIdx.x * 4 + (threadIdx.x >> 6);
    int lane = threadIdx.x & 63;
    if (d >= N_NODES) return;
    int h = lane & 7, i = lane >> 3;
    int off = offsets[d], deg = offsets[d + 1] - off;
    float ald = al_d[d * HEADS + h];
    float aself = lrelu(al_s[d * HEADS + h] + ald);
    float m = aself;
    for (int base = 0; base < deg; base += 8){
        int e = base + i;
        float a = -1e30f;
        if (e < deg) a = lrelu(al_s[esrc[off + e] * HEADS + h] + ald);
        a = fmaxf(a, __shfl_xor(a, 8));
        a = fmaxf(a, __shfl_xor(a, 16));
        a = fmaxf(a, __shfl_xor(a, 32));
        m = fmaxf(m, a);
    }
    float denom = __expf(aself - m);
    for (int base = 0; base < deg; base += 8){
        int e = base + i;
        float w = 0.f;
        if (e < deg){
            w = __expf(lrelu(al_s[esrc[off + e] * HEADS + h] + ald) - m);
            ew[(size_t)(off + e) * HEADS + h] = w;    // unnormalized
        }
        float ws = w;
        ws += __shfl_xor(ws, 8);
        ws += __shfl_xor(ws, 16);
        ws += __shfl_xor(ws, 32);
        denom += ws;
    }
    if (i == 0){
        wselfr[d * HEADS + h] = __expf(aself - m);
        dinv[d * HEADS + h]   = 1.f / denom;
    }
}

// ---------------- layer-1 aggregation + fused layer-2 GEMM ----------------
__global__ __launch_bounds__(256) void agg1f(const unsigned short* __restrict__ h1b,
        const float* __restrict__ ew, const float* __restrict__ wselfr,
        const float* __restrict__ dinv,
        const int* __restrict__ offsets, const int* __restrict__ esrc,
        const float* __restrict__ b1,
        const unsigned short* __restrict__ w2t,
        const float* __restrict__ a_s2, const float* __restrict__ a_d2,
        float* __restrict__ h2, float* __restrict__ al2s, float* __restrict__ al2d){
    __shared__ unsigned short x2l[16 * X2ROW];    // 18.7 KB
    int w = threadIdx.x >> 6;
    int lane = threadIdx.x & 63;
    int g = lane >> 3, i = lane & 7;
    int cb = g * HID + i * 8;
#pragma unroll
    for (int q = 0; q < 4; q++){
        int row = w * 4 + q;
        int d = blockIdx.x * 16 + row;
        int off = offsets[d], deg = offsets[d + 1] - off;
        float acc[8];
        {   // self edge
            float w0 = wselfr[d * HEADS + g];
            short8 v = *(const short8*)(h1b + (size_t)d * HH + cb);
            unsigned int u[4]; __builtin_memcpy(u, &v, 16);
#pragma unroll
            for (int j = 0; j < 4; j++){
                acc[2*j]   = w0 * __uint_as_float(u[j] << 16);
                acc[2*j+1] = w0 * __uint_as_float(u[j] & 0xffff0000u);
            }
        }
        int e = 0;
        for (; e + 4 <= deg; e += 4){
            int s0 = __builtin_amdgcn_readfirstlane(esrc[off + e]);
            int s1 = __builtin_amdgcn_readfirstlane(esrc[off + e + 1]);
            int s2 = __builtin_amdgcn_readfirstlane(esrc[off + e + 2]);
            int s3 = __builtin_amdgcn_readfirstlane(esrc[off + e + 3]);
            float w0 = ew[(size_t)(off + e)     * HEADS + g];
            float w1 = ew[(size_t)(off + e + 1) * HEADS + g];
            float w2 = ew[(size_t)(off + e + 2) * HEADS + g];
            float w3 = ew[(size_t)(off + e + 3) * HEADS + g];
            short8 v0 = *(const short8*)(h1b + (size_t)s0 * HH + cb);
            short8 v1 = *(const short8*)(h1b + (size_t)s1 * HH + cb);
            short8 v2 = *(const short8*)(h1b + (size_t)s2 * HH + cb);
            short8 v3 = *(const short8*)(h1b + (size_t)s3 * HH + cb);
            fma8(acc, w0, v0); fma8(acc, w1, v1);
            fma8(acc, w2, v2); fma8(acc, w3, v3);
        }
        for (; e < deg; e++){
            int s0 = __builtin_amdgcn_readfirstlane(esrc[off + e]);
            float w0 = ew[(size_t)(off + e) * HEADS + g];
            short8 v0 = *(const short8*)(h1b + (size_t)s0 * HH + cb);
            fma8(acc, w0, v0);
        }
        float di = dinv[d * HEADS + g];
        unsigned short o8[8];
#pragma unroll
        for (int j = 0; j < 8; j++){
            float v = acc[j] * di + b1[cb + j];
            v = v > 0.f ? v : __expf(v) - 1.f;   // elu
            o8[j] = f2bf(v);
        }
        short8 ov; __builtin_memcpy(&ov, o8, 16);
        *(short8*)(&x2l[row * X2ROW + g * X2GB + i * 8]) = ov;
    }
    __syncthreads();
    if (w == 0){
        int rowbase = blockIdx.x * 16;
        int lr = lane & 15, lk = lane >> 4;
        float4v accv = {0.f, 0.f, 0.f, 0.f};
#pragma unroll
        for (int ks = 0; ks < 16; ks++){
            int c0 = ks * 32 + lk * 8;
            int gg = c0 >> 6, wc = c0 & 63;
            short8 a = *(const short8*)(&x2l[lr * X2ROW + gg * X2GB + wc]);
            short8 b = *(const short8*)(w2t + (size_t)lr * HH + ks * 32 + lk * 8);
            accv = __builtin_amdgcn_mfma_f32_16x16x32_bf16(a, b, accv, 0, 0, 0);
        }
#pragma unroll
        for (int r = 0; r < 4; r++)
            h2[(size_t)(rowbase + lk * 4 + r) * NCLS + lr] = accv[r];
        float s_a = a_s2[lr], d_a = a_d2[lr];
#pragma unroll
        for (int r = 0; r < 4; r++){
            float ps = accv[r] * s_a, pd = accv[r] * d_a;
#pragma unroll
            for (int off = 1; off < 16; off <<= 1){
                ps += __shfl_xor(ps, off);
                pd += __shfl_xor(pd, off);
            }
            if (lr == 0){
                al2s[rowbase + lk * 4 + r] = ps;
                al2d[rowbase + lk * 4 + r] = pd;
            }
        }
    }
}

// ---------------- layer-2: fused softmax + aggregation -> out [N][16] fp32 ----------------
__global__ __launch_bounds__(256) void agg2(const float* __restrict__ h2,
        const float* __restrict__ al2s, const float* __restrict__ al2d,
        const int* __restrict__ offsets, const int* __restrict__ esrc,
        const float* __restrict__ b2, float* __restrict__ out){
    int d = blockIdx.x * 4 + (threadIdx.x >> 6);
    int lane = threadIdx.x & 63;
    if (d >= N_NODES) return;
    int off = offsets[d], deg = offsets[d + 1] - off;
    float ald = al2d[d];
    float a0 = lrelu(al2s[d] + ald);
    int sg = lane >> 4, col = lane & 15;
    float m, dsum, acc;
    if (deg <= 64){
        float ae = -1e30f;
        if (lane < deg) ae = lrelu(al2s[esrc[off + lane]] + ald);
        float t = fmaxf(ae, a0);
#pragma unroll
        for (int o = 1; o < 64; o <<= 1) t = fmaxf(t, __shfl_xor(t, o));
        m = t;
        float ws = (lane < deg) ? __expf(ae - m) : 0.f;
#pragma unroll
        for (int o = 1; o < 64; o <<= 1) ws += __shfl_xor(ws, o);
        dsum = ws + __expf(a0 - m);
        acc = (sg == 0) ? __expf(a0 - m) * h2[(size_t)d * NCLS + col] : 0.f;
        for (int i = sg; i < deg; i += 4){
            int s = esrc[off + i];
            float ai = __shfl(ae, i);
            acc += __expf(ai - m) * h2[(size_t)s * NCLS + col];
        }
    } else {
        m = a0;
        for (int base = 0; base < deg; base += 64){
            int e = base + lane;
            float a = (e < deg) ? lrelu(al2s[esrc[off + e]] + ald) : -1e30f;
#pragma unroll
            for (int o = 1; o < 64; o <<= 1) a = fmaxf(a, __shfl_xor(a, o));
            m = fmaxf(m, a);
        }
        dsum = __expf(a0 - m);
        for (int base = 0; base < deg; base += 64){
            int e = base + lane;
            float w = (e < deg) ? __expf(lrelu(al2s[esrc[off + e]] + ald) - m) : 0.f;
#pragma unroll
            for (int o = 1; o < 64; o <<= 1) w += __shfl_xor(w, o);
            dsum += w;
        }
        acc = (sg == 0) ? __expf(a0 - m) * h2[(size_t)d * NCLS + col] : 0.f;
        for (int i = sg; i < deg; i += 4){
            int s = esrc[off + i];
            float w = __expf(lrelu(al2s[s] + ald) - m);
            acc += w * h2[(size_t)s * NCLS + col];
        }
    }
    acc += __shfl_xor(acc, 16);
    acc += __shfl_xor(acc, 32);
    if (lane < NCLS) out[(size_t)d * NCLS + lane] = acc / dsum + b2[lane];
}

extern "C" void kernel_launch(void* const* d_in, const int* in_sizes, int n_in,
                              void* d_out, int out_size, void* d_ws, size_t ws_size,
                              hipStream_t stream){
    const float* x   = (const float*)d_in[0];
    const int*   ei  = (const int*)d_in[1];
    const int*   src = ei;
    const int*   dst = ei + NEDGE;
    const float* W1  = (const float*)d_in[2];
    const float* as1 = (const float*)d_in[3];
    const float* ad1 = (const float*)d_in[4];
    const float* b1  = (const float*)d_in[5];
    const float* W2  = (const float*)d_in[6];
    const float* as2 = (const float*)d_in[7];
    const float* ad2 = (const float*)d_in[8];
    const float* b2  = (const float*)d_in[9];
    float* out = (float*)d_out;

    char* p = (char*)d_ws;
    auto carve = [&](size_t bytes) -> char* {
        char* r = p; p += (bytes + 255) & ~(size_t)255; return r;
    };
    unsigned short* xb   = (unsigned short*)carve((size_t)N_NODES * F_INK * 2);
    unsigned short* w1t  = (unsigned short*)carve((size_t)HH * F_INK * 2);
    unsigned short* w2t  = (unsigned short*)carve((size_t)HH * NCLS * 2);
    unsigned short* h1b  = (unsigned short*)carve((size_t)N_NODES * HH * 2);
    float* al1s  = (float*)carve((size_t)N_NODES * HEADS * 4);
    float* al1d  = (float*)carve((size_t)N_NODES * HEADS * 4);
    int* counts  = (int*)carve((size_t)N_NODES * 4);
    int* erank   = (int*)carve((size_t)NEDGE * 4);
    int* offsets = (int*)carve((size_t)(N_NODES + 1) * 4);
    int* blocksums = (int*)carve((size_t)NBLK_SCAN * 4);
    int* blockbase = (int*)carve((size_t)NBLK_SCAN * 4);
    int* esrc    = (int*)carve((size_t)NEDGE * 4);
    float* ew    = (float*)carve((size_t)NEDGE * HEADS * 4);
    float* wselfr= (float*)carve((size_t)N_NODES * HEADS * 4);
    float* dinv  = (float*)carve((size_t)N_NODES * HEADS * 4);
    float* h2    = (float*)carve((size_t)N_NODES * NCLS * 4);
    float* al2s  = (float*)carve((size_t)N_NODES * 4);
    float* al2d  = (float*)carve((size_t)N_NODES * 4);
    if ((size_t)(p - (char*)d_ws) > ws_size) return;  // workspace too small

    hipMemsetAsync(counts, 0, N_NODES * 4, stream);

    prep<<<PREP_X_BLKS + PREP_W_BLKS + SCAT_BLKS, 256, 0, stream>>>(
        x, xb, W1, w1t, W2, w2t, dst, counts, erank);
    scan_part<<<NBLK_SCAN, 256, 0, stream>>>(counts, blocksums);
    scan_top<<<1, 256, 0, stream>>>(blocksums, blockbase, offsets);
    scan_write<<<NBLK_SCAN, 256, 0, stream>>>(counts, blockbase, offsets);
    gemm1_scatter<<<G1_BLKS + SCAT_BLKS, 256, 0, stream>>>(
        xb, w1t, as1, ad1, h1b, al1s, al1d, src, dst, offsets, erank, esrc);
    softmax1<<<(N_NODES + 3) / 4, 256, 0, stream>>>(al1s, al1d, offsets, esrc, ew, wselfr, dinv);
    agg1f<<<N_NODES / 16, 256, 0, stream>>>(h1b, ew, wselfr, dinv, offsets, esrc, b1,
                                            w2t, as2, ad2, h2, al2s, al2d);
    agg2<<<(N_NODES + 3) / 4, 256, 0, stream>>>(h2, al2s, al2d, offsets, esrc, b2, out);
}

// Round 22
// 207.555 us; speedup vs baseline: 1.4440x; 1.0104x over previous
//
#include <hip/hip_runtime.h>
#include <hip/hip_bf16.h>
#include <math.h>

#define N_NODES 50000
#define F_INK   256
#define HEADS   8
#define HID     64
#define HH      512     // HEADS*HID
#define NCLS    16
#define NEDGE   400000
#define NEG_SLOPE 0.2f

#define BCOLS 64
#define KPAD  264       // 256 + 8 bf16 pad (quad-bank spread); 64*264*2 = 33 KB
#define NBLK_SCAN ((N_NODES + 255) / 256)   // 196
// LDS x2 tile (agg1f): 16 rows; row = 8 g-blocks of (64 data + 8 pad) + 8 row-pad = 584 shorts
#define X2ROW 584
#define X2GB  72
// prep partition
#define PREP_X_BLKS 12500                   // 3,200,000 float4 items (N*F_IN/4), exact
#define PREP_W_BLKS 544                     // 131072 + 8192 = 139264 items, exact
// gemm1+scatter partition
#define G1_BLKS 1024                        // 8 panels * 128 row-groups
#define SCAT_BLKS ((NEDGE + 255) / 256)     // 1563

typedef __attribute__((ext_vector_type(8))) short short8;
typedef __attribute__((ext_vector_type(4))) short sh4;
typedef __attribute__((ext_vector_type(4))) float float4v;

__device__ __forceinline__ float bf2f(unsigned short u){
    unsigned int x = ((unsigned int)u) << 16;
    float f; __builtin_memcpy(&f, &x, 4); return f;
}
__device__ __forceinline__ unsigned short f2bf(float f){
    unsigned int x; __builtin_memcpy(&x, &f, 4);
    unsigned int r = x + 0x7FFFu + ((x >> 16) & 1u);   // RNE
    return (unsigned short)(r >> 16);
}
__device__ __forceinline__ float lrelu(float a){ return a > 0.f ? a : NEG_SLOPE * a; }

__device__ __forceinline__ void fma8(float* acc, float w, short8 v){
    unsigned int u[4]; __builtin_memcpy(u, &v, 16);
#pragma unroll
    for (int j = 0; j < 4; j++){
        acc[2*j]   += w * __uint_as_float(u[j] << 16);
        acc[2*j+1] += w * __uint_as_float(u[j] & 0xffff0000u);
    }
}

// ---------------- prep: cvt x -> bf16, cvt weights, count edges (one launch) ----------------
__global__ __launch_bounds__(256) void prep(const float* __restrict__ x, unsigned short* __restrict__ xb,
                                            const float* __restrict__ W1, unsigned short* __restrict__ W1T,
                                            const float* __restrict__ W2, unsigned short* __restrict__ W2T,
                                            const int* __restrict__ dst, int* __restrict__ counts,
                                            int* __restrict__ erank, int* __restrict__ cursor){
    int bid = blockIdx.x;
    if (bid == 0 && threadIdx.x == 0) *cursor = 0;   // zero scan cursor for scan1
    if (bid < PREP_X_BLKS){
        int i = bid * 256 + threadIdx.x;        // exactly 3,200,000 items
        float4v f = *(const float4v*)(x + (size_t)i * 4);
        sh4 o;
#pragma unroll
        for (int j = 0; j < 4; j++) o[j] = (short)f2bf(f[j]);
        *(sh4*)(xb + (size_t)i * 4) = o;
    } else if (bid < PREP_X_BLKS + PREP_W_BLKS){
        int i = (bid - PREP_X_BLKS) * 256 + threadIdx.x;
        if (i < F_INK * HH){
            int k = i / HH, c = i % HH;
            W1T[c * F_INK + k] = f2bf(W1[i]);
        } else {
            int j = i - F_INK * HH;             // < 8192 by partition sizing
            int k = j / NCLS, c = j % NCLS;
            W2T[c * HH + k] = f2bf(W2[j]);
        }
    } else {
        int e = (bid - PREP_X_BLKS - PREP_W_BLKS) * 256 + threadIdx.x;
        if (e < NEDGE) erank[e] = atomicAdd(&counts[dst[e]], 1);
    }
}

// ---------------- CSR base assignment: single launch, order-free disjoint ranges ----------
// In-block Hillis scan of 256 counts; one atomicAdd per block grabs the block base.
// offsets[d] need not be monotone: consumers use offsets[d] + counts[d] as an opaque range.
__global__ __launch_bounds__(256) void scan1(const int* __restrict__ counts,
                                             int* __restrict__ cursor,
                                             int* __restrict__ offsets){
    __shared__ int s[256];
    __shared__ int base;
    int i = blockIdx.x * 256 + threadIdx.x;
    int t = threadIdx.x;
    int v = (i < N_NODES) ? counts[i] : 0;
    s[t] = v; __syncthreads();
    int val = v;
    for (int off = 1; off < 256; off <<= 1){
        int o2 = (t >= off) ? s[t - off] : 0;
        __syncthreads();
        val += o2; s[t] = val;
        __syncthreads();
    }
    if (t == 255) base = atomicAdd(cursor, val);   // val@255 = block total
    __syncthreads();
    if (i < N_NODES) offsets[i] = base + val - v;  // exclusive prefix + block base
}

// ---------------- GEMM1 (64-col panels, fused attn dots) + scatter (merged launch) --------
// XCD-locality: panel index is the SLOW block dim so the 8 blocks sharing a row-group's
// A-tile have bid == rg (mod 8) -> same XCD -> A staged into that XCD's L2 once.
__global__ __launch_bounds__(256) void gemm1_scatter(
        const unsigned short* __restrict__ xb, const unsigned short* __restrict__ w1t,
        const float* __restrict__ a_src, const float* __restrict__ a_dst,
        unsigned short* __restrict__ h1b, float* __restrict__ al_s, float* __restrict__ al_d,
        const int* __restrict__ src, const int* __restrict__ dst,
        const int* __restrict__ offsets, const int* __restrict__ erank,
        int* __restrict__ esrc){
    __shared__ unsigned short bs[BCOLS * KPAD];   // 33 KB
    if (blockIdx.x >= G1_BLKS){
        int e = (blockIdx.x - G1_BLKS) * 256 + threadIdx.x;
        if (e < NEDGE) esrc[offsets[dst[e]] + erank[e]] = src[e];
        return;
    }
    int cb  = blockIdx.x >> 7;         // col panel == head (slow index)
    int rg  = blockIdx.x & 127;        // row-group (fast index -> XCD affinity)
    const int nrg = G1_BLKS >> 3;      // 128
    {   // stage B panel once
        int kc = threadIdx.x & 31;
        int c0 = threadIdx.x >> 5;
#pragma unroll
        for (int it = 0; it < 8; it++){
            int col = it * 8 + c0;
            short8 v = *(const short8*)(w1t + (size_t)(cb * BCOLS + col) * F_INK + kc * 8);
            *(short8*)(&bs[col * KPAD + kc * 8]) = v;
        }
    }
    __syncthreads();
    int w    = threadIdx.x >> 6;
    int lane = threadIdx.x & 63;
    int lr = lane & 15, lk = lane >> 4;
    float a_s[4], a_d[4];
#pragma unroll
    for (int ct = 0; ct < 4; ct++){
        a_s[ct] = a_src[cb * HID + ct * 16 + lr];
        a_d[ct] = a_dst[cb * HID + ct * 16 + lr];
    }
    const int nchunk = (N_NODES + 127) / 128;     // 391
    for (int ch = rg; ch < nchunk; ch += nrg){
        int rb0 = ch * 128 + w * 32;
        if (rb0 >= N_NODES) continue;
        bool t1 = (rb0 + 16 < N_NODES);
        short8 a0[8], a1[8];
#pragma unroll
        for (int ks = 0; ks < 8; ks++)
            a0[ks] = *(const short8*)(xb + (size_t)(rb0 + lr) * F_INK + ks * 32 + lk * 8);
        if (t1){
#pragma unroll
            for (int ks = 0; ks < 8; ks++)
                a1[ks] = *(const short8*)(xb + (size_t)(rb0 + 16 + lr) * F_INK + ks * 32 + lk * 8);
        }
        float ds0[4] = {0.f,0.f,0.f,0.f}, dd0[4] = {0.f,0.f,0.f,0.f};
        float ds1[4] = {0.f,0.f,0.f,0.f}, dd1[4] = {0.f,0.f,0.f,0.f};
#pragma unroll
        for (int ct = 0; ct < 4; ct++){
            float4v acc0 = {0.f, 0.f, 0.f, 0.f};
            float4v acc1 = {0.f, 0.f, 0.f, 0.f};
#pragma unroll
            for (int ks = 0; ks < 8; ks++){
                short8 b = *(const short8*)(&bs[(ct * 16 + lr) * KPAD + ks * 32 + lk * 8]);
                acc0 = __builtin_amdgcn_mfma_f32_16x16x32_bf16(a0[ks], b, acc0, 0, 0, 0);
                if (t1) acc1 = __builtin_amdgcn_mfma_f32_16x16x32_bf16(a1[ks], b, acc1, 0, 0, 0);
            }
#pragma unroll
            for (int r = 0; r < 4; r++){
                h1b[(size_t)(rb0 + lk * 4 + r) * HH + cb * BCOLS + ct * 16 + lr] = f2bf(acc0[r]);
                ds0[r] += acc0[r] * a_s[ct];
                dd0[r] += acc0[r] * a_d[ct];
            }
            if (t1){
#pragma unroll
                for (int r = 0; r < 4; r++){
                    h1b[(size_t)(rb0 + 16 + lk * 4 + r) * HH + cb * BCOLS + ct * 16 + lr] = f2bf(acc1[r]);
                    ds1[r] += acc1[r] * a_s[ct];
                    dd1[r] += acc1[r] * a_d[ct];
                }
            }
        }
#pragma unroll
        for (int r = 0; r < 4; r++){
#pragma unroll
            for (int o = 1; o < 16; o <<= 1){
                ds0[r] += __shfl_xor(ds0[r], o);
                dd0[r] += __shfl_xor(dd0[r], o);
                ds1[r] += __shfl_xor(ds1[r], o);
                dd1[r] += __shfl_xor(dd1[r], o);
            }
        }
        if (lr == 0){
#pragma unroll
            for (int r = 0; r < 4; r++){
                al_s[(rb0 + lk * 4 + r) * HEADS + cb] = ds0[r];
                al_d[(rb0 + lk * 4 + r) * HEADS + cb] = dd0[r];
            }
            if (t1){
#pragma unroll
                for (int r = 0; r < 4; r++){
                    al_s[(rb0 + 16 + lk * 4 + r) * HEADS + cb] = ds1[r];
                    al_d[(rb0 + 16 + lk * 4 + r) * HEADS + cb] = dd1[r];
                }
            }
        }
    }
}

// ---------------- layer-1 softmax: raw weights ew, wselfr, dinv ----------------
__global__ __launch_bounds__(256) void softmax1(
        const float* __restrict__ al_s, const float* __restrict__ al_d,
        const int* __restrict__ offsets, const int* __restrict__ counts,
        const int* __restrict__ esrc,
        float* __restrict__ ew, float* __restrict__ wselfr, float* __restrict__ dinv){
    int d = blockIdx.x * 4 + (threadIdx.x >> 6);
    int lane = threadIdx.x & 63;
    if (d >= N_NODES) return;
    int h = lane & 7, i = lane >> 3;
    int off = offsets[d], deg = counts[d];
    float ald = al_d[d * HEADS + h];
    float aself = lrelu(al_s[d * HEADS + h] + ald);
    float m = aself;
    for (int base = 0; base < deg; base += 8){
        int e = base + i;
        float a = -1e30f;
        if (e < deg) a = lrelu(al_s[esrc[off + e] * HEADS + h] + ald);
        a = fmaxf(a, __shfl_xor(a, 8));
        a = fmaxf(a, __shfl_xor(a, 16));
        a = fmaxf(a, __shfl_xor(a, 32));
        m = fmaxf(m, a);
    }
    float denom = __expf(aself - m);
    for (int base = 0; base < deg; base += 8){
        int e = base + i;
        float w = 0.f;
        if (e < deg){
            w = __expf(lrelu(al_s[esrc[off + e] * HEADS + h] + ald) - m);
            ew[(size_t)(off + e) * HEADS + h] = w;    // unnormalized
        }
        float ws = w;
        ws += __shfl_xor(ws, 8);
        ws += __shfl_xor(ws, 16);
        ws += __shfl_xor(ws, 32);
        denom += ws;
    }
    if (i == 0){
        wselfr[d * HEADS + h] = __expf(aself - m);
        dinv[d * HEADS + h]   = 1.f / denom;
    }
}

// ---------------- layer-1 aggregation + fused layer-2 GEMM ----------------
__global__ __launch_bounds__(256) void agg1f(const unsigned short* __restrict__ h1b,
        const float* __restrict__ ew, const float* __restrict__ wselfr,
        const float* __restrict__ dinv,
        const int* __restrict__ offsets, const int* __restrict__ counts,
        const int* __restrict__ esrc,
        const float* __restrict__ b1,
        const unsigned short* __restrict__ w2t,
        const float* __restrict__ a_s2, const float* __restrict__ a_d2,
        float* __restrict__ h2, float* __restrict__ al2s, float* __restrict__ al2d){
    __shared__ unsigned short x2l[16 * X2ROW];    // 18.7 KB
    int w = threadIdx.x >> 6;
    int lane = threadIdx.x & 63;
    int g = lane >> 3, i = lane & 7;
    int cb = g * HID + i * 8;
#pragma unroll
    for (int q = 0; q < 4; q++){
        int row = w * 4 + q;
        int d = blockIdx.x * 16 + row;
        int off = offsets[d], deg = counts[d];
        float acc[8];
        {   // self edge
            float w0 = wselfr[d * HEADS + g];
            short8 v = *(const short8*)(h1b + (size_t)d * HH + cb);
            unsigned int u[4]; __builtin_memcpy(u, &v, 16);
#pragma unroll
            for (int j = 0; j < 4; j++){
                acc[2*j]   = w0 * __uint_as_float(u[j] << 16);
                acc[2*j+1] = w0 * __uint_as_float(u[j] & 0xffff0000u);
            }
        }
        int e = 0;
        for (; e + 4 <= deg; e += 4){
            int s0 = __builtin_amdgcn_readfirstlane(esrc[off + e]);
            int s1 = __builtin_amdgcn_readfirstlane(esrc[off + e + 1]);
            int s2 = __builtin_amdgcn_readfirstlane(esrc[off + e + 2]);
            int s3 = __builtin_amdgcn_readfirstlane(esrc[off + e + 3]);
            float w0 = ew[(size_t)(off + e)     * HEADS + g];
            float w1 = ew[(size_t)(off + e + 1) * HEADS + g];
            float w2 = ew[(size_t)(off + e + 2) * HEADS + g];
            float w3 = ew[(size_t)(off + e + 3) * HEADS + g];
            short8 v0 = *(const short8*)(h1b + (size_t)s0 * HH + cb);
            short8 v1 = *(const short8*)(h1b + (size_t)s1 * HH + cb);
            short8 v2 = *(const short8*)(h1b + (size_t)s2 * HH + cb);
            short8 v3 = *(const short8*)(h1b + (size_t)s3 * HH + cb);
            fma8(acc, w0, v0); fma8(acc, w1, v1);
            fma8(acc, w2, v2); fma8(acc, w3, v3);
        }
        for (; e < deg; e++){
            int s0 = __builtin_amdgcn_readfirstlane(esrc[off + e]);
            float w0 = ew[(size_t)(off + e) * HEADS + g];
            short8 v0 = *(const short8*)(h1b + (size_t)s0 * HH + cb);
            fma8(acc, w0, v0);
        }
        float di = dinv[d * HEADS + g];
        unsigned short o8[8];
#pragma unroll
        for (int j = 0; j < 8; j++){
            float v = acc[j] * di + b1[cb + j];
            v = v > 0.f ? v : __expf(v) - 1.f;   // elu
            o8[j] = f2bf(v);
        }
        short8 ov; __builtin_memcpy(&ov, o8, 16);
        *(short8*)(&x2l[row * X2ROW + g * X2GB + i * 8]) = ov;
    }
    __syncthreads();
    if (w == 0){
        int rowbase = blockIdx.x * 16;
        int lr = lane & 15, lk = lane >> 4;
        float4v accv = {0.f, 0.f, 0.f, 0.f};
#pragma unroll
        for (int ks = 0; ks < 16; ks++){
            int c0 = ks * 32 + lk * 8;
            int gg = c0 >> 6, wc = c0 & 63;
            short8 a = *(const short8*)(&x2l[lr * X2ROW + gg * X2GB + wc]);
            short8 b = *(const short8*)(w2t + (size_t)lr * HH + ks * 32 + lk * 8);
            accv = __builtin_amdgcn_mfma_f32_16x16x32_bf16(a, b, accv, 0, 0, 0);
        }
#pragma unroll
        for (int r = 0; r < 4; r++)
            h2[(size_t)(rowbase + lk * 4 + r) * NCLS + lr] = accv[r];
        float s_a = a_s2[lr], d_a = a_d2[lr];
#pragma unroll
        for (int r = 0; r < 4; r++){
            float ps = accv[r] * s_a, pd = accv[r] * d_a;
#pragma unroll
            for (int off = 1; off < 16; off <<= 1){
                ps += __shfl_xor(ps, off);
                pd += __shfl_xor(pd, off);
            }
            if (lr == 0){
                al2s[rowbase + lk * 4 + r] = ps;
                al2d[rowbase + lk * 4 + r] = pd;
            }
        }
    }
}

// ---------------- layer-2: fused softmax + aggregation -> out [N][16] fp32 ----------------
__global__ __launch_bounds__(256) void agg2(const float* __restrict__ h2,
        const float* __restrict__ al2s, const float* __restrict__ al2d,
        const int* __restrict__ offsets, const int* __restrict__ counts,
        const int* __restrict__ esrc,
        const float* __restrict__ b2, float* __restrict__ out){
    int d = blockIdx.x * 4 + (threadIdx.x >> 6);
    int lane = threadIdx.x & 63;
    if (d >= N_NODES) return;
    int off = offsets[d], deg = counts[d];
    float ald = al2d[d];
    float a0 = lrelu(al2s[d] + ald);
    int sg = lane >> 4, col = lane & 15;
    float m, dsum, acc;
    if (deg <= 64){
        float ae = -1e30f;
        if (lane < deg) ae = lrelu(al2s[esrc[off + lane]] + ald);
        float t = fmaxf(ae, a0);
#pragma unroll
        for (int o = 1; o < 64; o <<= 1) t = fmaxf(t, __shfl_xor(t, o));
        m = t;
        float ws = (lane < deg) ? __expf(ae - m) : 0.f;
#pragma unroll
        for (int o = 1; o < 64; o <<= 1) ws += __shfl_xor(ws, o);
        dsum = ws + __expf(a0 - m);
        acc = (sg == 0) ? __expf(a0 - m) * h2[(size_t)d * NCLS + col] : 0.f;
        for (int i = sg; i < deg; i += 4){
            int s = esrc[off + i];
            float ai = __shfl(ae, i);
            acc += __expf(ai - m) * h2[(size_t)s * NCLS + col];
        }
    } else {
        m = a0;
        for (int base = 0; base < deg; base += 64){
            int e = base + lane;
            float a = (e < deg) ? lrelu(al2s[esrc[off + e]] + ald) : -1e30f;
#pragma unroll
            for (int o = 1; o < 64; o <<= 1) a = fmaxf(a, __shfl_xor(a, o));
            m = fmaxf(m, a);
        }
        dsum = __expf(a0 - m);
        for (int base = 0; base < deg; base += 64){
            int e = base + lane;
            float w = (e < deg) ? __expf(lrelu(al2s[esrc[off + e]] + ald) - m) : 0.f;
#pragma unroll
            for (int o = 1; o < 64; o <<= 1) w += __shfl_xor(w, o);
            dsum += w;
        }
        acc = (sg == 0) ? __expf(a0 - m) * h2[(size_t)d * NCLS + col] : 0.f;
        for (int i = sg; i < deg; i += 4){
            int s = esrc[off + i];
            float w = __expf(lrelu(al2s[s] + ald) - m);
            acc += w * h2[(size_t)s * NCLS + col];
        }
    }
    acc += __shfl_xor(acc, 16);
    acc += __shfl_xor(acc, 32);
    if (lane < NCLS) out[(size_t)d * NCLS + lane] = acc / dsum + b2[lane];
}

extern "C" void kernel_launch(void* const* d_in, const int* in_sizes, int n_in,
                              void* d_out, int out_size, void* d_ws, size_t ws_size,
                              hipStream_t stream){
    const float* x   = (const float*)d_in[0];
    const int*   ei  = (const int*)d_in[1];
    const int*   src = ei;
    const int*   dst = ei + NEDGE;
    const float* W1  = (const float*)d_in[2];
    const float* as1 = (const float*)d_in[3];
    const float* ad1 = (const float*)d_in[4];
    const float* b1  = (const float*)d_in[5];
    const float* W2  = (const float*)d_in[6];
    const float* as2 = (const float*)d_in[7];
    const float* ad2 = (const float*)d_in[8];
    const float* b2  = (const float*)d_in[9];
    float* out = (float*)d_out;

    char* p = (char*)d_ws;
    auto carve = [&](size_t bytes) -> char* {
        char* r = p; p += (bytes + 255) & ~(size_t)255; return r;
    };
    unsigned short* xb   = (unsigned short*)carve((size_t)N_NODES * F_INK * 2);
    unsigned short* w1t  = (unsigned short*)carve((size_t)HH * F_INK * 2);
    unsigned short* w2t  = (unsigned short*)carve((size_t)HH * NCLS * 2);
    unsigned short* h1b  = (unsigned short*)carve((size_t)N_NODES * HH * 2);
    float* al1s  = (float*)carve((size_t)N_NODES * HEADS * 4);
    float* al1d  = (float*)carve((size_t)N_NODES * HEADS * 4);
    int* counts  = (int*)carve((size_t)N_NODES * 4);
    int* erank   = (int*)carve((size_t)NEDGE * 4);
    int* offsets = (int*)carve((size_t)N_NODES * 4);
    int* cursor  = (int*)carve(4);
    int* esrc    = (int*)carve((size_t)NEDGE * 4);
    float* ew    = (float*)carve((size_t)NEDGE * HEADS * 4);
    float* wselfr= (float*)carve((size_t)N_NODES * HEADS * 4);
    float* dinv  = (float*)carve((size_t)N_NODES * HEADS * 4);
    float* h2    = (float*)carve((size_t)N_NODES * NCLS * 4);
    float* al2s  = (float*)carve((size_t)N_NODES * 4);
    float* al2d  = (float*)carve((size_t)N_NODES * 4);
    if ((size_t)(p - (char*)d_ws) > ws_size) return;  // workspace too small

    hipMemsetAsync(counts, 0, N_NODES * 4, stream);

    prep<<<PREP_X_BLKS + PREP_W_BLKS + SCAT_BLKS, 256, 0, stream>>>(
        x, xb, W1, w1t, W2, w2t, dst, counts, erank, cursor);
    scan1<<<NBLK_SCAN, 256, 0, stream>>>(counts, cursor, offsets);
    gemm1_scatter<<<G1_BLKS + SCAT_BLKS, 256, 0, stream>>>(
        xb, w1t, as1, ad1, h1b, al1s, al1d, src, dst, offsets, erank, esrc);
    softmax1<<<(N_NODES + 3) / 4, 256, 0, stream>>>(al1s, al1d, offsets, counts, esrc,
                                                    ew, wselfr, dinv);
    agg1f<<<N_NODES / 16, 256, 0, stream>>>(h1b, ew, wselfr, dinv, offsets, counts, esrc, b1,
                                            w2t, as2, ad2, h2, al2s, al2d);
    agg2<<<(N_NODES + 3) / 4, 256, 0, stream>>>(h2, al2s, al2d, offsets, counts, esrc, b2, out);
}

// Round 23
// 207.449 us; speedup vs baseline: 1.4447x; 1.0005x over previous
//
#include <hip/hip_runtime.h>
#include <hip/hip_bf16.h>
#include <math.h>

#define N_NODES 50000
#define F_INK   256
#define HEADS   8
#define HID     64
#define HH      512     // HEADS*HID
#define NCLS    16
#define NEDGE   400000
#define NEG_SLOPE 0.2f

#define BCOLS 64
#define KPAD  264       // 256 + 8 bf16 pad (quad-bank spread); 64*264*2 = 33 KB
#define NBLK_SCAN ((N_NODES + 255) / 256)   // 196
// LDS x2 tile (agg1f): 16 rows; row = 8 g-blocks of (64 data + 8 pad) + 8 row-pad = 584 shorts
#define X2ROW 584
#define X2GB  72
// prep partition
#define PREP_X_BLKS 12500                   // 3,200,000 float4 items (N*F_IN/4), exact
#define PREP_W_BLKS 544                     // 131072 + 8192 = 139264 items, exact
// gemm1+scatter partition
#define G1_BLKS 1024                        // 8 panels * 128 row-groups
#define SCAT_BLKS ((NEDGE + 255) / 256)     // 1563

typedef __attribute__((ext_vector_type(8))) short short8;
typedef __attribute__((ext_vector_type(4))) short sh4;
typedef __attribute__((ext_vector_type(4))) float float4v;

__device__ __forceinline__ float bf2f(unsigned short u){
    unsigned int x = ((unsigned int)u) << 16;
    float f; __builtin_memcpy(&f, &x, 4); return f;
}
__device__ __forceinline__ unsigned short f2bf(float f){
    unsigned int x; __builtin_memcpy(&x, &f, 4);
    unsigned int r = x + 0x7FFFu + ((x >> 16) & 1u);   // RNE
    return (unsigned short)(r >> 16);
}
__device__ __forceinline__ float lrelu(float a){ return a > 0.f ? a : NEG_SLOPE * a; }

__device__ __forceinline__ void fma8(float* acc, float w, short8 v){
    unsigned int u[4]; __builtin_memcpy(u, &v, 16);
#pragma unroll
    for (int j = 0; j < 4; j++){
        acc[2*j]   += w * __uint_as_float(u[j] << 16);
        acc[2*j+1] += w * __uint_as_float(u[j] & 0xffff0000u);
    }
}

// ---------------- prep: cvt x -> bf16, cvt weights, count edges (one launch) ----------------
__global__ __launch_bounds__(256) void prep(const float* __restrict__ x, unsigned short* __restrict__ xb,
                                            const float* __restrict__ W1, unsigned short* __restrict__ W1T,
                                            const float* __restrict__ W2, unsigned short* __restrict__ W2T,
                                            const int* __restrict__ dst, int* __restrict__ counts,
                                            int* __restrict__ erank, int* __restrict__ cursor){
    int bid = blockIdx.x;
    if (bid == 0 && threadIdx.x == 0) *cursor = 0;   // zero scan cursor for scan1
    if (bid < PREP_X_BLKS){
        int i = bid * 256 + threadIdx.x;        // exactly 3,200,000 items
        float4v f = *(const float4v*)(x + (size_t)i * 4);
        sh4 o;
#pragma unroll
        for (int j = 0; j < 4; j++) o[j] = (short)f2bf(f[j]);
        *(sh4*)(xb + (size_t)i * 4) = o;
    } else if (bid < PREP_X_BLKS + PREP_W_BLKS){
        int i = (bid - PREP_X_BLKS) * 256 + threadIdx.x;
        if (i < F_INK * HH){
            int k = i / HH, c = i % HH;
            W1T[c * F_INK + k] = f2bf(W1[i]);
        } else {
            int j = i - F_INK * HH;             // < 8192 by partition sizing
            int k = j / NCLS, c = j % NCLS;
            W2T[c * HH + k] = f2bf(W2[j]);
        }
    } else {
        int e = (bid - PREP_X_BLKS - PREP_W_BLKS) * 256 + threadIdx.x;
        if (e < NEDGE) erank[e] = atomicAdd(&counts[dst[e]], 1);
    }
}

// ---------------- CSR base assignment: single launch, order-free disjoint ranges ----------
__global__ __launch_bounds__(256) void scan1(const int* __restrict__ counts,
                                             int* __restrict__ cursor,
                                             int* __restrict__ offsets){
    __shared__ int s[256];
    __shared__ int base;
    int i = blockIdx.x * 256 + threadIdx.x;
    int t = threadIdx.x;
    int v = (i < N_NODES) ? counts[i] : 0;
    s[t] = v; __syncthreads();
    int val = v;
    for (int off = 1; off < 256; off <<= 1){
        int o2 = (t >= off) ? s[t - off] : 0;
        __syncthreads();
        val += o2; s[t] = val;
        __syncthreads();
    }
    if (t == 255) base = atomicAdd(cursor, val);   // val@255 = block total
    __syncthreads();
    if (i < N_NODES) offsets[i] = base + val - v;  // exclusive prefix + block base
}

// ---------------- GEMM1 (64-col panels, fused attn dots) + scatter (merged launch) --------
// XCD-locality: panel index is the SLOW block dim so the 8 blocks sharing a row-group's
// A-tile have bid == rg (mod 8) -> same XCD -> A staged into that XCD's L2 once.
__global__ __launch_bounds__(256) void gemm1_scatter(
        const unsigned short* __restrict__ xb, const unsigned short* __restrict__ w1t,
        const float* __restrict__ a_src, const float* __restrict__ a_dst,
        unsigned short* __restrict__ h1b, float* __restrict__ al_s, float* __restrict__ al_d,
        const int* __restrict__ src, const int* __restrict__ dst,
        const int* __restrict__ offsets, const int* __restrict__ erank,
        int* __restrict__ esrc){
    __shared__ unsigned short bs[BCOLS * KPAD];   // 33 KB
    if (blockIdx.x >= G1_BLKS){
        int e = (blockIdx.x - G1_BLKS) * 256 + threadIdx.x;
        if (e < NEDGE) esrc[offsets[dst[e]] + erank[e]] = src[e];
        return;
    }
    int cb  = blockIdx.x >> 7;         // col panel == head (slow index)
    int rg  = blockIdx.x & 127;        // row-group (fast index -> XCD affinity)
    const int nrg = G1_BLKS >> 3;      // 128
    {   // stage B panel once
        int kc = threadIdx.x & 31;
        int c0 = threadIdx.x >> 5;
#pragma unroll
        for (int it = 0; it < 8; it++){
            int col = it * 8 + c0;
            short8 v = *(const short8*)(w1t + (size_t)(cb * BCOLS + col) * F_INK + kc * 8);
            *(short8*)(&bs[col * KPAD + kc * 8]) = v;
        }
    }
    __syncthreads();
    int w    = threadIdx.x >> 6;
    int lane = threadIdx.x & 63;
    int lr = lane & 15, lk = lane >> 4;
    float a_s[4], a_d[4];
#pragma unroll
    for (int ct = 0; ct < 4; ct++){
        a_s[ct] = a_src[cb * HID + ct * 16 + lr];
        a_d[ct] = a_dst[cb * HID + ct * 16 + lr];
    }
    const int nchunk = (N_NODES + 127) / 128;     // 391
    for (int ch = rg; ch < nchunk; ch += nrg){
        int rb0 = ch * 128 + w * 32;
        if (rb0 >= N_NODES) continue;
        bool t1 = (rb0 + 16 < N_NODES);
        short8 a0[8], a1[8];
#pragma unroll
        for (int ks = 0; ks < 8; ks++)
            a0[ks] = *(const short8*)(xb + (size_t)(rb0 + lr) * F_INK + ks * 32 + lk * 8);
        if (t1){
#pragma unroll
            for (int ks = 0; ks < 8; ks++)
                a1[ks] = *(const short8*)(xb + (size_t)(rb0 + 16 + lr) * F_INK + ks * 32 + lk * 8);
        }
        float ds0[4] = {0.f,0.f,0.f,0.f}, dd0[4] = {0.f,0.f,0.f,0.f};
        float ds1[4] = {0.f,0.f,0.f,0.f}, dd1[4] = {0.f,0.f,0.f,0.f};
#pragma unroll
        for (int ct = 0; ct < 4; ct++){
            float4v acc0 = {0.f, 0.f, 0.f, 0.f};
            float4v acc1 = {0.f, 0.f, 0.f, 0.f};
#pragma unroll
            for (int ks = 0; ks < 8; ks++){
                short8 b = *(const short8*)(&bs[(ct * 16 + lr) * KPAD + ks * 32 + lk * 8]);
                acc0 = __builtin_amdgcn_mfma_f32_16x16x32_bf16(a0[ks], b, acc0, 0, 0, 0);
                if (t1) acc1 = __builtin_amdgcn_mfma_f32_16x16x32_bf16(a1[ks], b, acc1, 0, 0, 0);
            }
#pragma unroll
            for (int r = 0; r < 4; r++){
                h1b[(size_t)(rb0 + lk * 4 + r) * HH + cb * BCOLS + ct * 16 + lr] = f2bf(acc0[r]);
                ds0[r] += acc0[r] * a_s[ct];
                dd0[r] += acc0[r] * a_d[ct];
            }
            if (t1){
#pragma unroll
                for (int r = 0; r < 4; r++){
                    h1b[(size_t)(rb0 + 16 + lk * 4 + r) * HH + cb * BCOLS + ct * 16 + lr] = f2bf(acc1[r]);
                    ds1[r] += acc1[r] * a_s[ct];
                    dd1[r] += acc1[r] * a_d[ct];
                }
            }
        }
#pragma unroll
        for (int r = 0; r < 4; r++){
#pragma unroll
            for (int o = 1; o < 16; o <<= 1){
                ds0[r] += __shfl_xor(ds0[r], o);
                dd0[r] += __shfl_xor(dd0[r], o);
                ds1[r] += __shfl_xor(ds1[r], o);
                dd1[r] += __shfl_xor(dd1[r], o);
            }
        }
        if (lr == 0){
#pragma unroll
            for (int r = 0; r < 4; r++){
                al_s[(rb0 + lk * 4 + r) * HEADS + cb] = ds0[r];
                al_d[(rb0 + lk * 4 + r) * HEADS + cb] = dd0[r];
            }
            if (t1){
#pragma unroll
                for (int r = 0; r < 4; r++){
                    al_s[(rb0 + 16 + lk * 4 + r) * HEADS + cb] = ds1[r];
                    al_d[(rb0 + 16 + lk * 4 + r) * HEADS + cb] = dd1[r];
                }
            }
        }
    }
}

// ---------------- layer-1 softmax: raw weights ew (bf16), wselfr, dinv ----------------
__global__ __launch_bounds__(256) void softmax1(
        const float* __restrict__ al_s, const float* __restrict__ al_d,
        const int* __restrict__ offsets, const int* __restrict__ counts,
        const int* __restrict__ esrc,
        unsigned short* __restrict__ ew, float* __restrict__ wselfr, float* __restrict__ dinv){
    int d = blockIdx.x * 4 + (threadIdx.x >> 6);
    int lane = threadIdx.x & 63;
    if (d >= N_NODES) return;
    int h = lane & 7, i = lane >> 3;
    int off = offsets[d], deg = counts[d];
    float ald = al_d[d * HEADS + h];
    float aself = lrelu(al_s[d * HEADS + h] + ald);
    float m = aself;
    for (int base = 0; base < deg; base += 8){
        int e = base + i;
        float a = -1e30f;
        if (e < deg) a = lrelu(al_s[esrc[off + e] * HEADS + h] + ald);
        a = fmaxf(a, __shfl_xor(a, 8));
        a = fmaxf(a, __shfl_xor(a, 16));
        a = fmaxf(a, __shfl_xor(a, 32));
        m = fmaxf(m, a);
    }
    float denom = __expf(aself - m);
    for (int base = 0; base < deg; base += 8){
        int e = base + i;
        float w = 0.f;
        if (e < deg){
            w = __expf(lrelu(al_s[esrc[off + e] * HEADS + h] + ald) - m);
            ew[(size_t)(off + e) * HEADS + h] = f2bf(w);   // unnormalized, bf16
        }
        float ws = w;
        ws += __shfl_xor(ws, 8);
        ws += __shfl_xor(ws, 16);
        ws += __shfl_xor(ws, 32);
        denom += ws;
    }
    if (i == 0){
        wselfr[d * HEADS + h] = __expf(aself - m);
        dinv[d * HEADS + h]   = 1.f / denom;
    }
}

// ---------------- layer-1 aggregation + fused layer-2 GEMM ----------------
__global__ __launch_bounds__(256) void agg1f(const unsigned short* __restrict__ h1b,
        const unsigned short* __restrict__ ew, const float* __restrict__ wselfr,
        const float* __restrict__ dinv,
        const int* __restrict__ offsets, const int* __restrict__ counts,
        const int* __restrict__ esrc,
        const float* __restrict__ b1,
        const unsigned short* __restrict__ w2t,
        const float* __restrict__ a_s2, const float* __restrict__ a_d2,
        float* __restrict__ h2, float* __restrict__ al2s, float* __restrict__ al2d){
    __shared__ unsigned short x2l[16 * X2ROW];    // 18.7 KB
    int w = threadIdx.x >> 6;
    int lane = threadIdx.x & 63;
    int g = lane >> 3, i = lane & 7;
    int cb = g * HID + i * 8;
#pragma unroll
    for (int q = 0; q < 4; q++){
        int row = w * 4 + q;
        int d = blockIdx.x * 16 + row;
        int off = offsets[d], deg = counts[d];
        float acc[8];
        {   // self edge
            float w0 = wselfr[d * HEADS + g];
            short8 v = *(const short8*)(h1b + (size_t)d * HH + cb);
            unsigned int u[4]; __builtin_memcpy(u, &v, 16);
#pragma unroll
            for (int j = 0; j < 4; j++){
                acc[2*j]   = w0 * __uint_as_float(u[j] << 16);
                acc[2*j+1] = w0 * __uint_as_float(u[j] & 0xffff0000u);
            }
        }
        int e = 0;
        for (; e + 4 <= deg; e += 4){
            int s0 = __builtin_amdgcn_readfirstlane(esrc[off + e]);
            int s1 = __builtin_amdgcn_readfirstlane(esrc[off + e + 1]);
            int s2 = __builtin_amdgcn_readfirstlane(esrc[off + e + 2]);
            int s3 = __builtin_amdgcn_readfirstlane(esrc[off + e + 3]);
            float w0 = bf2f(ew[(size_t)(off + e)     * HEADS + g]);
            float w1 = bf2f(ew[(size_t)(off + e + 1) * HEADS + g]);
            float w2 = bf2f(ew[(size_t)(off + e + 2) * HEADS + g]);
            float w3 = bf2f(ew[(size_t)(off + e + 3) * HEADS + g]);
            short8 v0 = *(const short8*)(h1b + (size_t)s0 * HH + cb);
            short8 v1 = *(const short8*)(h1b + (size_t)s1 * HH + cb);
            short8 v2 = *(const short8*)(h1b + (size_t)s2 * HH + cb);
            short8 v3 = *(const short8*)(h1b + (size_t)s3 * HH + cb);
            fma8(acc, w0, v0); fma8(acc, w1, v1);
            fma8(acc, w2, v2); fma8(acc, w3, v3);
        }
        for (; e < deg; e++){
            int s0 = __builtin_amdgcn_readfirstlane(esrc[off + e]);
            float w0 = bf2f(ew[(size_t)(off + e) * HEADS + g]);
            short8 v0 = *(const short8*)(h1b + (size_t)s0 * HH + cb);
            fma8(acc, w0, v0);
        }
        float di = dinv[d * HEADS + g];
        unsigned short o8[8];
#pragma unroll
        for (int j = 0; j < 8; j++){
            float v = acc[j] * di + b1[cb + j];
            v = v > 0.f ? v : __expf(v) - 1.f;   // elu
            o8[j] = f2bf(v);
        }
        short8 ov; __builtin_memcpy(&ov, o8, 16);
        *(short8*)(&x2l[row * X2ROW + g * X2GB + i * 8]) = ov;
    }
    __syncthreads();
    if (w == 0){
        int rowbase = blockIdx.x * 16;
        int lr = lane & 15, lk = lane >> 4;
        float4v accv = {0.f, 0.f, 0.f, 0.f};
#pragma unroll
        for (int ks = 0; ks < 16; ks++){
            int c0 = ks * 32 + lk * 8;
            int gg = c0 >> 6, wc = c0 & 63;
            short8 a = *(const short8*)(&x2l[lr * X2ROW + gg * X2GB + wc]);
            short8 b = *(const short8*)(w2t + (size_t)lr * HH + ks * 32 + lk * 8);
            accv = __builtin_amdgcn_mfma_f32_16x16x32_bf16(a, b, accv, 0, 0, 0);
        }
#pragma unroll
        for (int r = 0; r < 4; r++)
            h2[(size_t)(rowbase + lk * 4 + r) * NCLS + lr] = accv[r];
        float s_a = a_s2[lr], d_a = a_d2[lr];
#pragma unroll
        for (int r = 0; r < 4; r++){
            float ps = accv[r] * s_a, pd = accv[r] * d_a;
#pragma unroll
            for (int off = 1; off < 16; off <<= 1){
                ps += __shfl_xor(ps, off);
                pd += __shfl_xor(pd, off);
            }
            if (lr == 0){
                al2s[rowbase + lk * 4 + r] = ps;
                al2d[rowbase + lk * 4 + r] = pd;
            }
        }
    }
}

// ---------------- layer-2: fused softmax + aggregation -> out [N][16] fp32 ----------------
__global__ __launch_bounds__(256) void agg2(const float* __restrict__ h2,
        const float* __restrict__ al2s, const float* __restrict__ al2d,
        const int* __restrict__ offsets, const int* __restrict__ counts,
        const int* __restrict__ esrc,
        const float* __restrict__ b2, float* __restrict__ out){
    int d = blockIdx.x * 4 + (threadIdx.x >> 6);
    int lane = threadIdx.x & 63;
    if (d >= N_NODES) return;
    int off = offsets[d], deg = counts[d];
    float ald = al2d[d];
    float a0 = lrelu(al2s[d] + ald);
    int sg = lane >> 4, col = lane & 15;
    float m, dsum, acc;
    if (deg <= 64){
        float ae = -1e30f;
        if (lane < deg) ae = lrelu(al2s[esrc[off + lane]] + ald);
        float t = fmaxf(ae, a0);
#pragma unroll
        for (int o = 1; o < 64; o <<= 1) t = fmaxf(t, __shfl_xor(t, o));
        m = t;
        float ws = (lane < deg) ? __expf(ae - m) : 0.f;
#pragma unroll
        for (int o = 1; o < 64; o <<= 1) ws += __shfl_xor(ws, o);
        dsum = ws + __expf(a0 - m);
        acc = (sg == 0) ? __expf(a0 - m) * h2[(size_t)d * NCLS + col] : 0.f;
        for (int i = sg; i < deg; i += 4){
            int s = esrc[off + i];
            float ai = __shfl(ae, i);
            acc += __expf(ai - m) * h2[(size_t)s * NCLS + col];
        }
    } else {
        m = a0;
        for (int base = 0; base < deg; base += 64){
            int e = base + lane;
            float a = (e < deg) ? lrelu(al2s[esrc[off + e]] + ald) : -1e30f;
#pragma unroll
            for (int o = 1; o < 64; o <<= 1) a = fmaxf(a, __shfl_xor(a, o));
            m = fmaxf(m, a);
        }
        dsum = __expf(a0 - m);
        for (int base = 0; base < deg; base += 64){
            int e = base + lane;
            float w = (e < deg) ? __expf(lrelu(al2s[esrc[off + e]] + ald) - m) : 0.f;
#pragma unroll
            for (int o = 1; o < 64; o <<= 1) w += __shfl_xor(w, o);
            dsum += w;
        }
        acc = (sg == 0) ? __expf(a0 - m) * h2[(size_t)d * NCLS + col] : 0.f;
        for (int i = sg; i < deg; i += 4){
            int s = esrc[off + i];
            float w = __expf(lrelu(al2s[s] + ald) - m);
            acc += w * h2[(size_t)s * NCLS + col];
        }
    }
    acc += __shfl_xor(acc, 16);
    acc += __shfl_xor(acc, 32);
    if (lane < NCLS) out[(size_t)d * NCLS + lane] = acc / dsum + b2[lane];
}

extern "C" void kernel_launch(void* const* d_in, const int* in_sizes, int n_in,
                              void* d_out, int out_size, void* d_ws, size_t ws_size,
                              hipStream_t stream){
    const float* x   = (const float*)d_in[0];
    const int*   ei  = (const int*)d_in[1];
    const int*   src = ei;
    const int*   dst = ei + NEDGE;
    const float* W1  = (const float*)d_in[2];
    const float* as1 = (const float*)d_in[3];
    const float* ad1 = (const float*)d_in[4];
    const float* b1  = (const float*)d_in[5];
    const float* W2  = (const float*)d_in[6];
    const float* as2 = (const float*)d_in[7];
    const float* ad2 = (const float*)d_in[8];
    const float* b2  = (const float*)d_in[9];
    float* out = (float*)d_out;

    char* p = (char*)d_ws;
    auto carve = [&](size_t bytes) -> char* {
        char* r = p; p += (bytes + 255) & ~(size_t)255; return r;
    };
    unsigned short* xb   = (unsigned short*)carve((size_t)N_NODES * F_INK * 2);
    unsigned short* w1t  = (unsigned short*)carve((size_t)HH * F_INK * 2);
    unsigned short* w2t  = (unsigned short*)carve((size_t)HH * NCLS * 2);
    unsigned short* h1b  = (unsigned short*)carve((size_t)N_NODES * HH * 2);
    float* al1s  = (float*)carve((size_t)N_NODES * HEADS * 4);
    float* al1d  = (float*)carve((size_t)N_NODES * HEADS * 4);
    int* counts  = (int*)carve((size_t)N_NODES * 4);
    int* erank   = (int*)carve((size_t)NEDGE * 4);
    int* offsets = (int*)carve((size_t)N_NODES * 4);
    int* cursor  = (int*)carve(4);
    int* esrc    = (int*)carve((size_t)NEDGE * 4);
    unsigned short* ew = (unsigned short*)carve((size_t)NEDGE * HEADS * 2);
    float* wselfr= (float*)carve((size_t)N_NODES * HEADS * 4);
    float* dinv  = (float*)carve((size_t)N_NODES * HEADS * 4);
    float* h2    = (float*)carve((size_t)N_NODES * NCLS * 4);
    float* al2s  = (float*)carve((size_t)N_NODES * 4);
    float* al2d  = (float*)carve((size_t)N_NODES * 4);
    if ((size_t)(p - (char*)d_ws) > ws_size) return;  // workspace too small

    hipMemsetAsync(counts, 0, N_NODES * 4, stream);

    prep<<<PREP_X_BLKS + PREP_W_BLKS + SCAT_BLKS, 256, 0, stream>>>(
        x, xb, W1, w1t, W2, w2t, dst, counts, erank, cursor);
    scan1<<<NBLK_SCAN, 256, 0, stream>>>(counts, cursor, offsets);
    gemm1_scatter<<<G1_BLKS + SCAT_BLKS, 256, 0, stream>>>(
        xb, w1t, as1, ad1, h1b, al1s, al1d, src, dst, offsets, erank, esrc);
    softmax1<<<(N_NODES + 3) / 4, 256, 0, stream>>>(al1s, al1d, offsets, counts, esrc,
                                                    ew, wselfr, dinv);
    agg1f<<<N_NODES / 16, 256, 0, stream>>>(h1b, ew, wselfr, dinv, offsets, counts, esrc, b1,
                                            w2t, as2, ad2, h2, al2s, al2d);
    agg2<<<(N_NODES + 3) / 4, 256, 0, stream>>>(h2, al2s, al2d, offsets, counts, esrc, b2, out);
}